// Round 10
// baseline (369.068 us; speedup 1.0000x reference)
//
#include <hip/hip_runtime.h>
#include <math.h>
#include <limits.h>
#include <stdint.h>

#define QMAXF 127.0f
#define BN_EPS 1e-5f
#define NCOPIES 64

typedef int v4i __attribute__((ext_vector_type(4)));
typedef float f32x4 __attribute__((ext_vector_type(4)));
typedef _Float16 f16x8 __attribute__((ext_vector_type(8)));

// ---------- helpers ----------
__device__ __forceinline__ int f2ord(float f){
    int i = __float_as_int(f);
    return i ^ ((i >> 31) & 0x7fffffff);
}
__device__ __forceinline__ float ord2f(int i){
    return __int_as_float(i ^ ((i >> 31) & 0x7fffffff));
}
__device__ __forceinline__ float scale_from_ord(int om){
    return fmaxf(ord2f(om) / QMAXF, 1e-8f);
}
// fake-quant forward: clip(round(x/s))*s  (round = half-to-even, matches jnp.round)
__device__ __forceinline__ float fq_apply(float x, float s){
    float q = rintf(x / s);
    q = fminf(fmaxf(q, -QMAXF), QMAXF);
    return q * s;
}
// return clipped integer level as float
__device__ __forceinline__ float quant_k(float x, float s){
    float q = rintf(x / s);
    return fminf(fmaxf(q, -QMAXF), QMAXF);
}

// ---------- K0: init stat buffers ----------
__global__ void k_init_stats(int* s1, int* s2, int* sf, int* so, int* wsmax){
    int t = blockIdx.x*blockDim.x + threadIdx.x;
    if (t < 2048){ int j = t & 31; s1[t] = (j < 16) ? INT_MAX : INT_MIN; }
    else if (t < 6144){ int u = t - 2048; int j = u & 63; s2[u] = (j < 32) ? INT_MAX : INT_MIN; }
    else if (t < 6272){ int u = t - 6144; sf[u] = ((u & 1) == 0) ? INT_MAX : INT_MIN; }
    else if (t < 6400){ int u = t - 6272; so[u] = ((u & 1) == 0) ? INT_MAX : INT_MIN; }
    else if (t < 6404){ wsmax[t - 6400] = INT_MIN; }
}

// ---------- K1a: per-tensor |w| max ----------
__global__ __launch_bounds__(256) void k_wscales(
    const float* __restrict__ w1, const float* __restrict__ w2,
    const float* __restrict__ fw1, const float* __restrict__ fw2,
    int* __restrict__ wsmax)
{
    __shared__ float red[256];
    int t = threadIdx.x, blk = blockIdx.x;
    const float* src; int n, base, which;
    if (blk < 64){ src = fw1; base = blk*3136; n = 3136; which = 2; }
    else if (blk == 64){ src = w1;  base = 0; n = 144;  which = 0; }
    else if (blk == 65){ src = w2;  base = 0; n = 4608; which = 1; }
    else { src = fw2; base = 0; n = 1280; which = 3; }
    float m = 0.f;
    for (int i = t; i < n; i += 256) m = fmaxf(m, fabsf(src[base + i]));
    red[t] = m; __syncthreads();
    for (int off = 128; off; off >>= 1){
        if (t < off) red[t] = fmaxf(red[t], red[t+off]);
        __syncthreads();
    }
    if (t == 0) atomicMax(&wsmax[which], f2ord(red[0]));
}

// ---------- K1b: pack/quantize weights ----------
__global__ __launch_bounds__(256) void k_pack_weights(
    const float* __restrict__ w1, const float* __restrict__ w2,
    const float* __restrict__ fw1, const float* __restrict__ fw2,
    const int* __restrict__ wsmax,
    _Float16* __restrict__ wpk1h, int8_t* __restrict__ wpk2,
    int8_t* __restrict__ bpk1, float* __restrict__ qfw2,
    float* __restrict__ wscales)
{
    int blk = blockIdx.x, t = threadIdx.x;
    if (blk < 784){
        float s = scale_from_ord(wsmax[2]);
        int i = blk*256 + t;                      // 200704 exact
        int o = i / 1568, k = i - o*1568;
        int c = k / 49, r = k - c*49;
        int kp = r*32 + c;
        int kchunk = kp >> 6, rem = kp & 63, hi = rem >> 4, j = rem & 15;
        int code = (int)quant_k(fw1[i], s);
        bpk1[(o>>4)*25600 + (kchunk*4 + hi)*256 + (o&15)*16 + j] = (int8_t)code;
    } else if (blk == 784){
        float s0 = scale_from_ord(wsmax[0]), s3 = scale_from_ord(wsmax[3]);
        for (int i = t; i < 512; i += 256){
            int grp = i >> 3, j = i & 7;
            int hi = grp >> 4, col = grp & 15;
            int k = hi*8 + j;
            _Float16 val = (_Float16)0.f;
            if (k < 9) val = (_Float16)quant_k(w1[col*9 + k], s0);  // integer code, exact
            wpk1h[i] = val;
        }
        for (int i = t; i < 1280; i += 256) qfw2[i] = fq_apply(fw2[i], s3);
        for (int i = t; i < 4096; i += 256){
            int o = i >> 5, rem = (i & 31) + 32;  // kp 1568..1599 -> chunk24
            int hi = rem >> 4, j = rem & 15;
            bpk1[(o>>4)*25600 + (24*4 + hi)*256 + (o&15)*16 + j] = 0;
        }
        if (t < 4) wscales[t] = scale_from_ord(wsmax[t]);
    } else {
        float s1 = scale_from_ord(wsmax[1]);
        for (int i = t; i < 6144; i += 256) wpk2[i] = 0;
        __syncthreads();
        for (int i = t; i < 4608; i += 256){
            int co = i / 144, rr = i - co*144, ci = rr / 9, pix = rr - ci*9;
            wpk2[(co >> 4)*3072 + pix*256 + (co & 15)*16 + ci] = (int8_t)(int)quant_k(w2[i], s1);
        }
    }
}

// ---------- K1c: pad + hi/lo f16 split of x -> xp[b][30][30] (hi<<16 | lo) ----------
__global__ __launch_bounds__(256) void k_prep_x(
    const float* __restrict__ x, uint32_t* __restrict__ xp)
{
    int i = blockIdx.x*256 + threadIdx.x;   // 7,372,800 = 8192*900 exact
    int b = i / 900, r = i - b*900;
    int yy = r / 30, xx = r - yy*30;
    float val = 0.f;
    if (yy >= 1 && yy <= 28 && xx >= 1 && xx <= 28)
        val = x[(size_t)b*784 + (yy-1)*28 + (xx-1)];
    _Float16 h  = (_Float16)val;
    _Float16 lo = (_Float16)(val - (float)h);
    xp[i] = ((uint32_t)__builtin_bit_cast(unsigned short, h) << 16)
          |  (uint32_t)__builtin_bit_cast(unsigned short, lo);
}

// ---------- conv1 A-fragment from packed padded image ----------
// tap k -> load xpb[(y+ky)*30 + xx+kx] (imm offsets off one base), unpack hi/lo.
__device__ __forceinline__ void conv1_frag_p(const uint32_t* __restrict__ xpb,
                                             int y, int xx, int hi,
                                             f16x8& ahi, f16x8& alo)
{
    const uint32_t* base = xpb + y*30 + xx;
    #pragma unroll
    for (int j = 0; j < 8; j++){
        int k = hi*8 + j;
        uint32_t w = 0;
        if (k < 9){
            int ky = k / 3, kx = k - ky*3;
            w = base[ky*30 + kx];
        }
        ahi[j] = __builtin_bit_cast(_Float16, (unsigned short)(w >> 16));
        alo[j] = __builtin_bit_cast(_Float16, (unsigned short)(w & 0xffffu));
    }
}

// ---------- K2: conv1 f16-split MFMA + per-channel min/max ----------
__global__ __launch_bounds__(256) void k_conv1s_mfma(
    const uint32_t* __restrict__ xp, const _Float16* __restrict__ wpk1h,
    const float* __restrict__ b1, const float* __restrict__ wscales,
    int* __restrict__ stats1 /*[64][32] ordered-int*/)
{
    int t = threadIdx.x, l = t & 63, wid = t >> 6;
    int hi = l >> 4, col = l & 15;
    f16x8 bv = *(const f16x8*)(wpk1h + (hi*16 + col)*8);
    float sb = b1[col];
    float s0 = wscales[0];
    float mn = INFINITY, mx = -INFINITY;
    #pragma unroll 1
    for (int it = 0; it < 64; it++){
        int tile = (blockIdx.x*4 + wid)*64 + it;   // 1568*4*64 = 401,408 tiles
        int p = tile*16 + (l & 15);                // A row = l&15
        int b = p / 784, r = p - b*784;
        int y = r / 28, xx = r - y*28;
        const uint32_t* xpb = xp + (size_t)b*900;
        f16x8 ahi, alo;
        conv1_frag_p(xpb, y, xx, hi, ahi, alo);
        f32x4 acc = {0.f, 0.f, 0.f, 0.f};
        acc = __builtin_amdgcn_mfma_f32_16x16x32_f16(ahi, bv, acc, 0, 0, 0);
        acc = __builtin_amdgcn_mfma_f32_16x16x32_f16(alo, bv, acc, 0, 0, 0);
        #pragma unroll
        for (int rg = 0; rg < 4; rg++){
            float v = fmaf(s0, acc[rg], sb);
            mn = fminf(mn, v); mx = fmaxf(mx, v);
        }
    }
    mn = fminf(mn, __shfl_xor(mn, 16)); mn = fminf(mn, __shfl_xor(mn, 32));
    mx = fmaxf(mx, __shfl_xor(mx, 16)); mx = fmaxf(mx, __shfl_xor(mx, 32));
    if (l < 16){
        int* base = stats1 + (blockIdx.x & (NCOPIES-1))*32;
        atomicMin(&base[l],      f2ord(mn));
        atomicMax(&base[16 + l], f2ord(mx));
    }
}

// ---------- K4: block1 f16-split MFMA + fused scale derivation ----------
// rows pool-permuted; lane's 4 C-regs = one 2x2 pool window. Prologue derives
// s1,s2,s3,bnA,bnB from stats1 in every block (deterministic); block 0 publishes.
__global__ __launch_bounds__(256) void k_block1_mfma(
    const uint32_t* __restrict__ xp, const _Float16* __restrict__ wpk1h,
    const float* __restrict__ b1, const float* __restrict__ wscales,
    const int* __restrict__ stats1,
    const float* __restrict__ g, const float* __restrict__ be,
    const float* __restrict__ m, const float* __restrict__ v,
    float* __restrict__ scales, int8_t* __restrict__ h1q)
{
    __shared__ char pbuf[4096];
    __shared__ float cmn[16], cmx[16], bnAl[16], bnBl[16], ssc[3];
    int t = threadIdx.x, l = t & 63, wid = t >> 6;
    if (t < 32){
        bool ismax = t >= 16; int c = t & 15;
        int acc = ismax ? INT_MIN : INT_MAX;
        for (int i = 0; i < NCOPIES; i++){
            int u = stats1[i*32 + t];
            acc = ismax ? max(acc, u) : min(acc, u);
        }
        if (ismax) cmx[c] = ord2f(acc); else cmn[c] = ord2f(acc);
    }
    __syncthreads();
    if (t == 0){
        float am = 0.f;
        for (int c = 0; c < 16; c++) am = fmaxf(am, fmaxf(fabsf(cmn[c]), fabsf(cmx[c])));
        float sA_ = fmaxf(am / QMAXF, 1e-8f);
        float rmax = 0.f;
        float q1x[16], q1n[16];
        for (int c = 0; c < 16; c++){
            q1x[c] = fmaxf(fq_apply(cmx[c], sA_), 0.f);
            q1n[c] = fmaxf(fq_apply(cmn[c], sA_), 0.f);
            rmax = fmaxf(rmax, q1x[c]);
        }
        float sB_ = fmaxf(rmax / QMAXF, 1e-8f);
        float am3 = 0.f;
        for (int c = 0; c < 16; c++){
            float inv = g[c] / sqrtf(v[c] + BN_EPS);
            float dd  = be[c] - m[c]*inv;
            bnAl[c] = inv; bnBl[c] = dd;
            float ha = fmaf(fq_apply(q1x[c], sB_), inv, dd);
            float hb = fmaf(fq_apply(q1n[c], sB_), inv, dd);
            am3 = fmaxf(am3, fmaxf(fabsf(ha), fabsf(hb)));
        }
        float sC_ = fmaxf(am3 / QMAXF, 1e-8f);
        ssc[0] = sA_; ssc[1] = sB_; ssc[2] = sC_;
        if (blockIdx.x == 0){ scales[0] = sA_; scales[1] = sB_; scales[2] = sC_; }
    }
    __syncthreads();
    int hi = l >> 4, col = l & 15;
    f16x8 bv = *(const f16x8*)(wpk1h + (hi*16 + col)*8);
    float sb = b1[col], sA = bnAl[col], sB = bnBl[col];
    float s0 = wscales[0];
    float s1 = ssc[0], s2 = ssc[1], s3 = ssc[2];
    #pragma unroll 1
    for (int it = 0; it < 16; it++){
        int tl = wid*16 + it;                    // tile_local 0..63
        int tile = blockIdx.x*64 + tl;           // 6272*64 = 401,408 tiles
        int grow = tile*16 + (l & 15);           // A row
        int cell = grow >> 2, sub = grow & 3;
        int b = cell / 196, rc = cell - b*196;
        int py = rc / 14, px = rc - py*14;
        int y = 2*py + (sub >> 1), xx = 2*px + (sub & 1);
        const uint32_t* xpb = xp + (size_t)b*900;
        f16x8 ahi, alo;
        conv1_frag_p(xpb, y, xx, hi, ahi, alo);
        f32x4 acc = {0.f, 0.f, 0.f, 0.f};
        acc = __builtin_amdgcn_mfma_f32_16x16x32_f16(ahi, bv, acc, 0, 0, 0);
        acc = __builtin_amdgcn_mfma_f32_16x16x32_f16(alo, bv, acc, 0, 0, 0);
        float pool = fmaxf(fmaxf(acc[0], acc[1]), fmaxf(acc[2], acc[3]));
        float conv = fmaf(s0, pool, sb);
        float h = fq_apply(conv, s1);
        h = fmaxf(h, 0.f);
        h = fq_apply(h, s2);
        h = fmaf(h, sA, sB);
        int code = (int)quant_k(h, s3);
        pbuf[(tl*4 + hi)*16 + col] = (char)code;
    }
    __syncthreads();
    ((int4*)h1q)[blockIdx.x*256 + t] = ((const int4*)pbuf)[t];
}

// ---------- conv2 MFMA tile ----------
__device__ __forceinline__ void conv2_tile_mfma(
    const int8_t* __restrict__ h1q, const v4i* __restrict__ bv,
    int tile, int l, v4i& acc0, v4i& acc1)
{
    int grow = tile*16 + (l & 15);
    int cell_g = grow >> 2;
    int b = cell_g / 49, cell = cell_g - b*49;
    int sub = grow & 3;
    int qy = cell / 7, qx = cell - qy*7;
    int y = 2*qy + (sub >> 1);
    int x = 2*qx + (sub & 1);
    size_t base = (size_t)b * 196;
    int hi = l >> 4;
    acc0 = (v4i){0,0,0,0};
    acc1 = (v4i){0,0,0,0};
    #pragma unroll
    for (int s = 0; s < 3; s++){
        int tap = 4*s + hi;
        v4i av = {0,0,0,0};
        if (tap < 9){
            int ky = tap / 3, kx = tap - ky*3;
            int yy = y + ky - 1, xc = x + kx - 1;
            if (yy >= 0 && yy < 14 && xc >= 0 && xc < 14)
                av = *(const v4i*)(h1q + (base + yy*14 + xc)*16);
        }
        acc0 = __builtin_amdgcn_mfma_i32_16x16x64_i8(av, bv[s],     acc0, 0, 0, 0);
        acc1 = __builtin_amdgcn_mfma_i32_16x16x64_i8(av, bv[3 + s], acc1, 0, 0, 0);
    }
}

// ---------- K6: conv2 int8 MFMA + per-channel code min/max ----------
__global__ __launch_bounds__(256) void k_conv2s_mfma(
    const int8_t* __restrict__ h1q, const int8_t* __restrict__ wpk2,
    int* __restrict__ stats2)
{
    __shared__ int smn[32], smx[32];
    int t = threadIdx.x, l = t & 63, wid = t >> 6;
    if (t < 32){ smn[t] = INT_MAX; smx[t] = INT_MIN; }
    __syncthreads();
    v4i bv[6];
    #pragma unroll
    for (int nt = 0; nt < 2; nt++)
        #pragma unroll
        for (int s = 0; s < 3; s++)
            bv[nt*3+s] = *(const v4i*)(wpk2 + nt*3072 + (4*s + (l>>4))*256 + (l&15)*16);
    int mn0 = INT_MAX, mx0 = INT_MIN, mn1 = INT_MAX, mx1 = INT_MIN;
    #pragma unroll 1
    for (int it = 0; it < 16; it++){            // 1568 blocks * 16 = 25088 tiles
        int tb = blockIdx.x + it*1568;
        v4i acc0, acc1;
        conv2_tile_mfma(h1q, bv, tb*4 + wid, l, acc0, acc1);
        #pragma unroll
        for (int r = 0; r < 4; r++){
            mn0 = min(mn0, acc0[r]); mx0 = max(mx0, acc0[r]);
            mn1 = min(mn1, acc1[r]); mx1 = max(mx1, acc1[r]);
        }
    }
    mn0 = min(mn0, __shfl_xor(mn0, 16)); mn0 = min(mn0, __shfl_xor(mn0, 32));
    mx0 = max(mx0, __shfl_xor(mx0, 16)); mx0 = max(mx0, __shfl_xor(mx0, 32));
    mn1 = min(mn1, __shfl_xor(mn1, 16)); mn1 = min(mn1, __shfl_xor(mn1, 32));
    mx1 = max(mx1, __shfl_xor(mx1, 16)); mx1 = max(mx1, __shfl_xor(mx1, 32));
    if (l < 16){
        atomicMin(&smn[l], mn0);      atomicMax(&smx[l], mx0);
        atomicMin(&smn[16 + l], mn1); atomicMax(&smx[16 + l], mx1);
    }
    __syncthreads();
    if (t < 32){
        int* base = stats2 + (blockIdx.x & (NCOPIES-1))*64;
        atomicMin(&base[t],      smn[t]);
        atomicMax(&base[t + 32], smx[t]);
    }
}

// ---------- K8: conv2 MFMA -> pool -> chain -> h2q + fused scale derivation ----------
__global__ __launch_bounds__(256) void k_block2_mfma(
    const int8_t* __restrict__ h1q, const int8_t* __restrict__ wpk2,
    const float* __restrict__ b2, const int* __restrict__ stats2,
    const float* __restrict__ g, const float* __restrict__ be,
    const float* __restrict__ m, const float* __restrict__ v,
    float* __restrict__ scales, const float* __restrict__ wscales,
    int8_t* __restrict__ h2q)
{
    __shared__ float sbl[32], sAl[32], sBl[32], ssc[3];
    __shared__ float cmn[32], cmx[32];
    __shared__ int pbufi[512];
    char* pbuf = (char*)pbufi;
    int t = threadIdx.x, l = t & 63, wid = t >> 6;
    float S = scales[2] * wscales[1];
    if (t < 64){
        bool ismax = t >= 32; int c = t & 31;
        int acc = ismax ? INT_MIN : INT_MAX;
        for (int i = 0; i < NCOPIES; i++){
            int u = stats2[i*64 + t];
            acc = ismax ? max(acc, u) : min(acc, u);
        }
        float val = fmaf(S, (float)acc, b2[c]);
        if (ismax) cmx[c] = val; else cmn[c] = val;
    }
    if (t < 32) sbl[t] = b2[t];
    __syncthreads();
    if (t == 0){
        float am = 0.f;
        for (int c = 0; c < 32; c++) am = fmaxf(am, fmaxf(fabsf(cmn[c]), fabsf(cmx[c])));
        float sA_ = fmaxf(am / QMAXF, 1e-8f);
        float rmax = 0.f;
        float q1x[32], q1n[32];
        for (int c = 0; c < 32; c++){
            q1x[c] = fmaxf(fq_apply(cmx[c], sA_), 0.f);
            q1n[c] = fmaxf(fq_apply(cmn[c], sA_), 0.f);
            rmax = fmaxf(rmax, q1x[c]);
        }
        float sB_ = fmaxf(rmax / QMAXF, 1e-8f);
        float am3 = 0.f;
        for (int c = 0; c < 32; c++){
            float inv = g[c] / sqrtf(v[c] + BN_EPS);
            float dd  = be[c] - m[c]*inv;
            sAl[c] = inv; sBl[c] = dd;
            float ha = fmaf(fq_apply(q1x[c], sB_), inv, dd);
            float hb = fmaf(fq_apply(q1n[c], sB_), inv, dd);
            am3 = fmaxf(am3, fmaxf(fabsf(ha), fabsf(hb)));
        }
        float sC_ = fmaxf(am3 / QMAXF, 1e-8f);
        ssc[0] = sA_; ssc[1] = sB_; ssc[2] = sC_;
        if (blockIdx.x == 0){ scales[3] = sA_; scales[4] = sB_; scales[5] = sC_; }
    }
    __syncthreads();
    float s4 = ssc[0], s5 = ssc[1], s6 = ssc[2];
    v4i bv[6];
    #pragma unroll
    for (int nt = 0; nt < 2; nt++)
        #pragma unroll
        for (int s = 0; s < 3; s++)
            bv[nt*3+s] = *(const v4i*)(wpk2 + nt*3072 + (4*s + (l>>4))*256 + (l&15)*16);
    #pragma unroll 1
    for (int it = 0; it < 4; it++){
        int tile = blockIdx.x*16 + wid*4 + it;   // grid 6272: tiles 0..100351
        v4i acc0, acc1;
        conv2_tile_mfma(h1q, bv, tile, l, acc0, acc1);
        int cell_local = wid*16 + it*4 + (l >> 4);
        #pragma unroll
        for (int nt = 0; nt < 2; nt++){
            v4i a = nt ? acc1 : acc0;
            int pool = max(max(a[0], a[1]), max(a[2], a[3]));
            int co = nt*16 + (l & 15);
            float conv = fmaf(S, (float)pool, sbl[co]);
            float h = fq_apply(conv, s4);
            h = fmaxf(h, 0.f);
            h = fq_apply(h, s5);
            h = fmaf(h, sAl[co], sBl[co]);
            pbuf[cell_local*32 + co] = (char)(int)quant_k(h, s6);
        }
    }
    __syncthreads();
    #pragma unroll
    for (int i = t; i < 512; i += 256)
        ((int*)h2q)[blockIdx.x*512 + i] = pbufi[i];
}

// ---------- K9: fc1 int8 MFMA: M=8192, N=128, K=1600 (padded) ----------
__global__ __launch_bounds__(256) void k_fc1(
    const int8_t* __restrict__ h2q, const int8_t* __restrict__ bpk1,
    const float* __restrict__ fb1, const float* __restrict__ scales,
    const float* __restrict__ wscales,
    float* __restrict__ fc1o, int* __restrict__ statsFc)
{
    __shared__ int smn, smx;
    int t = threadIdx.x, l = t & 63, wid = t >> 6;
    if (t == 0){ smn = INT_MAX; smx = INT_MIN; }
    __syncthreads();
    int wave_id = blockIdx.x*4 + wid;     // 1024 waves
    int mtile = wave_id >> 1;             // 0..511
    int half = wave_id & 1;
    int hi = l >> 4, lo = l & 15;
    const int8_t* arow = h2q + (size_t)(mtile*16 + lo)*1568;
    v4i acc[4];
    #pragma unroll
    for (int g = 0; g < 4; g++) acc[g] = (v4i){0,0,0,0};
    #pragma unroll 1
    for (int kc = 0; kc < 25; kc++){
        int koff = kc*64 + hi*16;
        v4i av = (v4i){0,0,0,0};
        if (koff < 1568) av = *(const v4i*)(arow + koff);
        #pragma unroll
        for (int g = 0; g < 4; g++){
            v4i bvv = *(const v4i*)(bpk1 + (half*4 + g)*25600 + (kc*4 + hi)*256 + lo*16);
            acc[g] = __builtin_amdgcn_mfma_i32_16x16x64_i8(av, bvv, acc[g], 0, 0, 0);
        }
    }
    float Sfc = scales[5] * wscales[2];
    float lmn = INFINITY, lmx = -INFINITY;
    #pragma unroll
    for (int g = 0; g < 4; g++){
        int o = (half*4 + g)*16 + lo;
        float bias = fb1[o];
        #pragma unroll
        for (int r = 0; r < 4; r++){
            int m = mtile*16 + hi*4 + r;
            float val = fmaf(Sfc, (float)acc[g][r], bias);
            fc1o[(size_t)m*128 + o] = val;
            lmn = fminf(lmn, val); lmx = fmaxf(lmx, val);
        }
    }
    #pragma unroll
    for (int d = 1; d < 64; d <<= 1){
        lmn = fminf(lmn, __shfl_xor(lmn, d));
        lmx = fmaxf(lmx, __shfl_xor(lmx, d));
    }
    if (l == 0){
        atomicMin(&smn, f2ord(lmn));
        atomicMax(&smx, f2ord(lmx));
    }
    __syncthreads();
    if (t == 0){
        int* base = statsFc + (blockIdx.x & (NCOPIES-1))*2;
        atomicMin(&base[0], smn); atomicMax(&base[1], smx);
    }
}

// ---------- K12: fc2 with inline h3 quantization (s7/s8 derived in prologue) ----------
__global__ __launch_bounds__(256) void k_fc2(
    const float* __restrict__ fc1o, const float* __restrict__ qfw2, const float* __restrict__ fb2,
    const int* __restrict__ statsFc, float* __restrict__ out, int* __restrict__ statsOut)
{
    __shared__ float sw[1280], sb2[10];
    __shared__ float s7s, s8s;
    __shared__ int smn, smx;
    int t = threadIdx.x;
    for (int i = t; i < 1280; i += 256) sw[i] = qfw2[i];
    if (t < 10) sb2[t] = fb2[t];
    if (t == 0){
        smn = INT_MAX; smx = INT_MIN;
        int mni = INT_MAX, mxi = INT_MIN;
        for (int i = 0; i < NCOPIES; i++){ mni = min(mni, statsFc[i*2]); mxi = max(mxi, statsFc[i*2+1]); }
        float mn = ord2f(mni), mx = ord2f(mxi);
        float am = fmaxf(fabsf(mn), fabsf(mx));
        float s7 = fmaxf(am / QMAXF, 1e-8f);
        float rmx = fmaxf(fq_apply(mx, s7), 0.f);
        s7s = s7; s8s = fmaxf(rmx / QMAXF, 1e-8f);
    }
    __syncthreads();
    float s7 = s7s, s8 = s8s;
    int b = blockIdx.x*256 + t;   // 8192 exact (32 blocks)
    float acc[10];
    #pragma unroll
    for (int j = 0; j < 10; j++) acc[j] = sb2[j];
    const float* fp = fc1o + (size_t)b*128;
    for (int k = 0; k < 128; k += 4){
        float4 f = *(const float4*)(fp + k);
        float v0 = s8 * quant_k(fmaxf(fq_apply(f.x, s7), 0.f), s8);
        float v1 = s8 * quant_k(fmaxf(fq_apply(f.y, s7), 0.f), s8);
        float v2 = s8 * quant_k(fmaxf(fq_apply(f.z, s7), 0.f), s8);
        float v3 = s8 * quant_k(fmaxf(fq_apply(f.w, s7), 0.f), s8);
        #pragma unroll
        for (int j = 0; j < 10; j++){
            float a = acc[j];
            a = fmaf(v0, sw[j*128 + k],     a);
            a = fmaf(v1, sw[j*128 + k + 1], a);
            a = fmaf(v2, sw[j*128 + k + 2], a);
            a = fmaf(v3, sw[j*128 + k + 3], a);
            acc[j] = a;
        }
    }
    float lmn = INFINITY, lmx = -INFINITY;
    #pragma unroll
    for (int j = 0; j < 10; j++){
        out[(size_t)b*10 + j] = acc[j];
        lmn = fminf(lmn, acc[j]); lmx = fmaxf(lmx, acc[j]);
    }
    atomicMin(&smn, f2ord(lmn)); atomicMax(&smx, f2ord(lmx));
    __syncthreads();
    if (t == 0){
        int* base = statsOut + (blockIdx.x & (NCOPIES-1))*2;
        atomicMin(&base[0], smn); atomicMax(&base[1], smx);
    }
}

// ---------- K14: final fake-quant of d_out (s9 derived in prologue) ----------
__global__ void k_quant_out(float* __restrict__ out, const int* __restrict__ statsOut, int n){
    __shared__ float s9s;
    if (threadIdx.x == 0){
        int mni = INT_MAX, mxi = INT_MIN;
        for (int i = 0; i < NCOPIES; i++){ mni = min(mni, statsOut[i*2]); mxi = max(mxi, statsOut[i*2+1]); }
        float am = fmaxf(fabsf(ord2f(mni)), fabsf(ord2f(mxi)));
        s9s = fmaxf(am / QMAXF, 1e-8f);
    }
    __syncthreads();
    int i = blockIdx.x*256 + threadIdx.x;
    if (i < n) out[i] = fq_apply(out[i], s9s);
}

// =================== host ===================
extern "C" void kernel_launch(void* const* d_in, const int* in_sizes, int n_in,
                              void* d_out, int out_size, void* d_ws, size_t ws_size,
                              hipStream_t stream)
{
    const float* x   = (const float*)d_in[0];
    const float* w1  = (const float*)d_in[1];
    const float* b1  = (const float*)d_in[2];
    const float* g1  = (const float*)d_in[3];
    const float* be1 = (const float*)d_in[4];
    const float* m1  = (const float*)d_in[5];
    const float* v1  = (const float*)d_in[6];
    const float* w2  = (const float*)d_in[7];
    const float* b2  = (const float*)d_in[8];
    const float* g2  = (const float*)d_in[9];
    const float* be2 = (const float*)d_in[10];
    const float* m2  = (const float*)d_in[11];
    const float* v2  = (const float*)d_in[12];
    const float* fw1 = (const float*)d_in[13];
    const float* fb1 = (const float*)d_in[14];
    const float* fw2 = (const float*)d_in[15];
    const float* fb2 = (const float*)d_in[16];
    float* out = (float*)d_out;

    char* ws = (char*)d_ws;
    size_t off = 0;
    auto alloc = [&](size_t bytes)->char*{
        char* p = ws + off;
        off = (off + bytes + 255) & ~(size_t)255;
        return p;
    };
    _Float16* wpk1h = (_Float16*)alloc(512*2);
    int8_t* wpk2  = (int8_t*)alloc(6144);
    int8_t* bpk1  = (int8_t*)alloc(204800);
    float* qfw2   = (float*)alloc(1280*4);
    float* scales = (float*)alloc(16*4);
    float* wscales= (float*)alloc(4*4);
    int* wsmax    = (int*)alloc(4*4);
    int* stats1   = (int*)alloc(64*32*4);
    int* stats2   = (int*)alloc(64*64*4);
    int* statsFc  = (int*)alloc(64*2*4);
    int* statsOut = (int*)alloc(64*2*4);
    uint32_t* xp  = (uint32_t*)alloc((size_t)8192*900*4);
    int8_t* h1q   = (int8_t*)alloc((size_t)8192*196*16);
    int8_t* h2q   = (int8_t*)alloc((size_t)8192*49*32);
    float* fc1o   = (float*)alloc((size_t)8192*128*4);
    (void)ws_size;

    k_init_stats<<<26, 256, 0, stream>>>(stats1, stats2, statsFc, statsOut, wsmax);
    k_wscales<<<67, 256, 0, stream>>>(w1, w2, fw1, fw2, wsmax);
    k_pack_weights<<<786, 256, 0, stream>>>(w1, w2, fw1, fw2, wsmax, wpk1h, wpk2, bpk1, qfw2, wscales);
    k_prep_x<<<28800, 256, 0, stream>>>(x, xp);
    k_conv1s_mfma<<<1568, 256, 0, stream>>>(xp, wpk1h, b1, wscales, stats1);
    k_block1_mfma<<<6272, 256, 0, stream>>>(xp, wpk1h, b1, wscales, stats1, g1, be1, m1, v1, scales, h1q);
    k_conv2s_mfma<<<1568, 256, 0, stream>>>(h1q, wpk2, stats2);
    k_block2_mfma<<<6272, 256, 0, stream>>>(h1q, wpk2, b2, stats2, g2, be2, m2, v2, scales, wscales, h2q);
    k_fc1<<<256, 256, 0, stream>>>(h2q, bpk1, fb1, scales, wscales, fc1o, statsFc);
    k_fc2<<<32, 256, 0, stream>>>(fc1o, qfw2, fb2, statsFc, out, statsOut);
    k_quant_out<<<320, 256, 0, stream>>>(out, statsOut, out_size);
}

// Round 11
// 250.923 us; speedup vs baseline: 1.4708x; 1.4708x over previous
//
#include <hip/hip_runtime.h>
#include <math.h>
#include <limits.h>
#include <stdint.h>

#define QMAXF 127.0f
#define BN_EPS 1e-5f
#define NCOPIES 64

typedef int v4i __attribute__((ext_vector_type(4)));
typedef float f32x4 __attribute__((ext_vector_type(4)));
typedef _Float16 f16x8 __attribute__((ext_vector_type(8)));

// ---------- helpers ----------
__device__ __forceinline__ int f2ord(float f){
    int i = __float_as_int(f);
    return i ^ ((i >> 31) & 0x7fffffff);
}
__device__ __forceinline__ float ord2f(int i){
    return __int_as_float(i ^ ((i >> 31) & 0x7fffffff));
}
__device__ __forceinline__ float scale_from_ord(int om){
    return fmaxf(ord2f(om) / QMAXF, 1e-8f);
}
// fake-quant forward: clip(round(x/s))*s  (round = half-to-even, matches jnp.round)
__device__ __forceinline__ float fq_apply(float x, float s){
    float q = rintf(x / s);
    q = fminf(fmaxf(q, -QMAXF), QMAXF);
    return q * s;
}
// return clipped integer level as float
__device__ __forceinline__ float quant_k(float x, float s){
    float q = rintf(x / s);
    return fminf(fmaxf(q, -QMAXF), QMAXF);
}

// ---------- K0: init stat buffers ----------
__global__ void k_init_stats(int* s1, int* s2, int* sf, int* so, int* wsmax){
    int t = blockIdx.x*blockDim.x + threadIdx.x;
    if (t < 2048){ int j = t & 31; s1[t] = (j < 16) ? INT_MAX : INT_MIN; }
    else if (t < 6144){ int u = t - 2048; int j = u & 63; s2[u] = (j < 32) ? INT_MAX : INT_MIN; }
    else if (t < 6272){ int u = t - 6144; sf[u] = ((u & 1) == 0) ? INT_MAX : INT_MIN; }
    else if (t < 6400){ int u = t - 6272; so[u] = ((u & 1) == 0) ? INT_MAX : INT_MIN; }
    else if (t < 6404){ wsmax[t - 6400] = INT_MIN; }
}

// ---------- K1a: per-tensor |w| max ----------
__global__ __launch_bounds__(256) void k_wscales(
    const float* __restrict__ w1, const float* __restrict__ w2,
    const float* __restrict__ fw1, const float* __restrict__ fw2,
    int* __restrict__ wsmax)
{
    __shared__ float red[256];
    int t = threadIdx.x, blk = blockIdx.x;
    const float* src; int n, base, which;
    if (blk < 64){ src = fw1; base = blk*3136; n = 3136; which = 2; }
    else if (blk == 64){ src = w1;  base = 0; n = 144;  which = 0; }
    else if (blk == 65){ src = w2;  base = 0; n = 4608; which = 1; }
    else { src = fw2; base = 0; n = 1280; which = 3; }
    float m = 0.f;
    for (int i = t; i < n; i += 256) m = fmaxf(m, fabsf(src[base + i]));
    red[t] = m; __syncthreads();
    for (int off = 128; off; off >>= 1){
        if (t < off) red[t] = fmaxf(red[t], red[t+off]);
        __syncthreads();
    }
    if (t == 0) atomicMax(&wsmax[which], f2ord(red[0]));
}

// ---------- K1b: pack/quantize weights ----------
__global__ __launch_bounds__(256) void k_pack_weights(
    const float* __restrict__ w1, const float* __restrict__ w2,
    const float* __restrict__ fw1, const float* __restrict__ fw2,
    const int* __restrict__ wsmax,
    _Float16* __restrict__ wpk1h, int8_t* __restrict__ wpk2,
    int8_t* __restrict__ bpk1, float* __restrict__ qfw2,
    float* __restrict__ wscales)
{
    int blk = blockIdx.x, t = threadIdx.x;
    if (blk < 784){
        float s = scale_from_ord(wsmax[2]);
        int i = blk*256 + t;                      // 200704 exact
        int o = i / 1568, k = i - o*1568;
        int c = k / 49, r = k - c*49;
        int kp = r*32 + c;
        int kchunk = kp >> 6, rem = kp & 63, hi = rem >> 4, j = rem & 15;
        int code = (int)quant_k(fw1[i], s);
        bpk1[(o>>4)*25600 + (kchunk*4 + hi)*256 + (o&15)*16 + j] = (int8_t)code;
    } else if (blk == 784){
        float s0 = scale_from_ord(wsmax[0]), s3 = scale_from_ord(wsmax[3]);
        for (int i = t; i < 512; i += 256){
            int grp = i >> 3, j = i & 7;
            int hi = grp >> 4, col = grp & 15;
            int k = hi*8 + j;
            _Float16 val = (_Float16)0.f;
            if (k < 9) val = (_Float16)quant_k(w1[col*9 + k], s0);  // integer code, exact
            wpk1h[i] = val;
        }
        for (int i = t; i < 1280; i += 256) qfw2[i] = fq_apply(fw2[i], s3);
        for (int i = t; i < 4096; i += 256){
            int o = i >> 5, rem = (i & 31) + 32;  // kp 1568..1599 -> chunk24
            int hi = rem >> 4, j = rem & 15;
            bpk1[(o>>4)*25600 + (24*4 + hi)*256 + (o&15)*16 + j] = 0;
        }
        if (t < 4) wscales[t] = scale_from_ord(wsmax[t]);
    } else {
        float s1 = scale_from_ord(wsmax[1]);
        for (int i = t; i < 6144; i += 256) wpk2[i] = 0;
        __syncthreads();
        for (int i = t; i < 4608; i += 256){
            int co = i / 144, rr = i - co*144, ci = rr / 9, pix = rr - ci*9;
            wpk2[(co >> 4)*3072 + pix*256 + (co & 15)*16 + ci] = (int8_t)(int)quant_k(w2[i], s1);
        }
    }
}

// ---------- K1c: pad + hi/lo f16 split of x -> xp[b][30][30] (hi<<16 | lo) ----------
__global__ __launch_bounds__(256) void k_prep_x(
    const float* __restrict__ x, uint32_t* __restrict__ xp)
{
    int i = blockIdx.x*256 + threadIdx.x;   // 7,372,800 = 8192*900 exact
    int b = i / 900, r = i - b*900;
    int yy = r / 30, xx = r - yy*30;
    float val = 0.f;
    if (yy >= 1 && yy <= 28 && xx >= 1 && xx <= 28)
        val = x[(size_t)b*784 + (yy-1)*28 + (xx-1)];
    _Float16 h  = (_Float16)val;
    _Float16 lo = (_Float16)(val - (float)h);
    xp[i] = ((uint32_t)__builtin_bit_cast(unsigned short, h) << 16)
          |  (uint32_t)__builtin_bit_cast(unsigned short, lo);
}

// ---------- conv1 fragment from precomputed per-lane tap offsets ----------
__device__ __forceinline__ void conv1_frag_o(const uint32_t* __restrict__ base,
                                             const int* toff,
                                             f16x8& ahi, f16x8& alo)
{
    #pragma unroll
    for (int j = 0; j < 8; j++){
        uint32_t w = (toff[j] >= 0) ? base[toff[j]] : 0u;
        ahi[j] = __builtin_bit_cast(_Float16, (unsigned short)(w >> 16));
        alo[j] = __builtin_bit_cast(_Float16, (unsigned short)(w & 0xffffu));
    }
}

// ---------- K2: conv1 f16-split MFMA + per-channel min/max (hoisted addressing) ----------
// tile = tile0 + it*6272 -> p += 100352 = 128 images; (y,x) fixed, b += 128.
__global__ __launch_bounds__(256) void k_conv1s_mfma(
    const uint32_t* __restrict__ xp, const _Float16* __restrict__ wpk1h,
    const float* __restrict__ b1, const float* __restrict__ wscales,
    int* __restrict__ stats1)
{
    int t = threadIdx.x, l = t & 63, wid = t >> 6;
    int hi = l >> 4, col = l & 15;
    f16x8 bv = *(const f16x8*)(wpk1h + (hi*16 + col)*8);
    float sb = b1[col];
    float s0 = wscales[0];
    int tile0 = blockIdx.x*4 + wid;                // 0..6271
    int p0 = tile0*16 + (l & 15);
    int b0 = p0 / 784, r = p0 - b0*784;
    int y = r / 28, xx = r - y*28;
    const uint32_t* base = xp + (size_t)b0*900 + (y)*30 + xx;  // window top-left (padded)
    int toff[8];
    #pragma unroll
    for (int j = 0; j < 8; j++){
        int k = hi*8 + j;
        toff[j] = (k < 9) ? ((k/3)*30 + (k - (k/3)*3)) : -1;
    }
    float mn = INFINITY, mx = -INFINITY;
    #pragma unroll 1
    for (int it = 0; it < 64; it++){
        f16x8 ahi, alo;
        conv1_frag_o(base, toff, ahi, alo);
        f32x4 acc = {0.f, 0.f, 0.f, 0.f};
        acc = __builtin_amdgcn_mfma_f32_16x16x32_f16(ahi, bv, acc, 0, 0, 0);
        acc = __builtin_amdgcn_mfma_f32_16x16x32_f16(alo, bv, acc, 0, 0, 0);
        #pragma unroll
        for (int rg = 0; rg < 4; rg++){
            float v = fmaf(s0, acc[rg], sb);
            mn = fminf(mn, v); mx = fmaxf(mx, v);
        }
        base += (size_t)128*900;
    }
    mn = fminf(mn, __shfl_xor(mn, 16)); mn = fminf(mn, __shfl_xor(mn, 32));
    mx = fmaxf(mx, __shfl_xor(mx, 16)); mx = fmaxf(mx, __shfl_xor(mx, 32));
    if (l < 16){
        int* basep = stats1 + (blockIdx.x & (NCOPIES-1))*32;
        atomicMin(&basep[l],      f2ord(mn));
        atomicMax(&basep[16 + l], f2ord(mx));
    }
}

// ---------- scales for block1 ----------
__global__ void k_scales_block(int C, const int* __restrict__ stats,
                               const float* __restrict__ g, const float* __restrict__ be,
                               const float* __restrict__ m, const float* __restrict__ v,
                               float* __restrict__ s_out, float* __restrict__ bnA, float* __restrict__ bnB)
{
    __shared__ float cmn[32], cmx[32];
    int t = threadIdx.x;
    if (t < 2*C){
        bool ismax = t >= C; int c = ismax ? t - C : t;
        int acc = ismax ? INT_MIN : INT_MAX;
        for (int i = 0; i < NCOPIES; i++){
            int u = stats[i*2*C + t];
            acc = ismax ? max(acc, u) : min(acc, u);
        }
        if (ismax) cmx[c] = ord2f(acc); else cmn[c] = ord2f(acc);
    }
    __syncthreads();
    if (t == 0){
        float am = 0.f;
        for (int c = 0; c < C; c++) am = fmaxf(am, fmaxf(fabsf(cmn[c]), fabsf(cmx[c])));
        float sA_ = fmaxf(am / QMAXF, 1e-8f);
        float rmax = 0.f;
        float q1x[32], q1n[32];
        for (int c = 0; c < C; c++){
            q1x[c] = fmaxf(fq_apply(cmx[c], sA_), 0.f);
            q1n[c] = fmaxf(fq_apply(cmn[c], sA_), 0.f);
            rmax = fmaxf(rmax, q1x[c]);
        }
        float sB_ = fmaxf(rmax / QMAXF, 1e-8f);
        float am3 = 0.f;
        for (int c = 0; c < C; c++){
            float inv = g[c] / sqrtf(v[c] + BN_EPS);
            float dd  = be[c] - m[c]*inv;
            bnA[c] = inv; bnB[c] = dd;
            float ha = fmaf(fq_apply(q1x[c], sB_), inv, dd);
            float hb = fmaf(fq_apply(q1n[c], sB_), inv, dd);
            am3 = fmaxf(am3, fmaxf(fabsf(ha), fabsf(hb)));
        }
        float sC_ = fmaxf(am3 / QMAXF, 1e-8f);
        s_out[0] = sA_; s_out[1] = sB_; s_out[2] = sC_;
    }
}

// ---------- K4: block1 f16-split MFMA, pool in C-regs, hoisted; direct byte stores ----------
// tile = tile0 + it*25088 -> cell += 100352 = 512 images; (rc,y,x) fixed, b += 512.
__global__ __launch_bounds__(256) void k_block1_mfma(
    const uint32_t* __restrict__ xp, const _Float16* __restrict__ wpk1h,
    const float* __restrict__ b1, const float* __restrict__ wscales,
    const float* __restrict__ scales,
    const float* __restrict__ bnA, const float* __restrict__ bnB,
    int8_t* __restrict__ h1q)
{
    int t = threadIdx.x, l = t & 63, wid = t >> 6;
    int hi = l >> 4, col = l & 15;
    f16x8 bv = *(const f16x8*)(wpk1h + (hi*16 + col)*8);
    float sb = b1[col], sA = bnA[col], sB = bnB[col];
    float s0 = wscales[0];
    float s1 = scales[0], s2 = scales[1], s3 = scales[2];
    int tile0 = blockIdx.x*4 + wid;                // 0..25087
    int grow = tile0*16 + (l & 15);
    int cell = grow >> 2, sub = grow & 3;
    int b0 = cell / 196, rc = cell - b0*196;
    int py = rc / 14, px = rc - py*14;
    int y = 2*py + (sub >> 1), xx = 2*px + (sub & 1);
    const uint32_t* base = xp + (size_t)b0*900 + y*30 + xx;
    int toff[8];
    #pragma unroll
    for (int j = 0; j < 8; j++){
        int k = hi*8 + j;
        toff[j] = (k < 9) ? ((k/3)*30 + (k - (k/3)*3)) : -1;
    }
    int8_t* h1o = h1q + (size_t)(tile0*4)*16 + l;  // (tile*4+hi)*16+col = tile*64 + l
    #pragma unroll 1
    for (int it = 0; it < 16; it++){
        f16x8 ahi, alo;
        conv1_frag_o(base, toff, ahi, alo);
        f32x4 acc = {0.f, 0.f, 0.f, 0.f};
        acc = __builtin_amdgcn_mfma_f32_16x16x32_f16(ahi, bv, acc, 0, 0, 0);
        acc = __builtin_amdgcn_mfma_f32_16x16x32_f16(alo, bv, acc, 0, 0, 0);
        float pool = fmaxf(fmaxf(acc[0], acc[1]), fmaxf(acc[2], acc[3]));
        float conv = fmaf(s0, pool, sb);
        float h = fq_apply(conv, s1);
        h = fmaxf(h, 0.f);
        h = fq_apply(h, s2);
        h = fmaf(h, sA, sB);
        *h1o = (int8_t)(int)quant_k(h, s3);
        base += (size_t)512*900;
        h1o  += (size_t)100352*16;
    }
}

// ---------- K6: conv2 int8 MFMA + per-channel code min/max (hoisted) ----------
// tile = tile0 + it*6272 -> cell_g += 25088 = 512 images; taps fixed, b += 512.
__global__ __launch_bounds__(256) void k_conv2s_mfma(
    const int8_t* __restrict__ h1q, const int8_t* __restrict__ wpk2,
    int* __restrict__ stats2)
{
    __shared__ int smn[32], smx[32];
    int t = threadIdx.x, l = t & 63, wid = t >> 6;
    if (t < 32){ smn[t] = INT_MAX; smx[t] = INT_MIN; }
    __syncthreads();
    int hi = l >> 4;
    v4i bv[6];
    #pragma unroll
    for (int nt = 0; nt < 2; nt++)
        #pragma unroll
        for (int s = 0; s < 3; s++)
            bv[nt*3+s] = *(const v4i*)(wpk2 + nt*3072 + (4*s + hi)*256 + (l&15)*16);
    int tile0 = blockIdx.x*4 + wid;                // 0..6271
    int grow = tile0*16 + (l & 15);
    int cell_g = grow >> 2;
    int b0 = cell_g / 49, cell = cell_g - b0*49;
    int sub = grow & 3;
    int qy = cell / 7, qx = cell - qy*7;
    int y = 2*qy + (sub >> 1), x = 2*qx + (sub & 1);
    const int8_t* ip = h1q + (size_t)b0*196*16;
    int toff[3];
    #pragma unroll
    for (int s = 0; s < 3; s++){
        int tap = 4*s + hi;
        toff[s] = -1;
        if (tap < 9){
            int ky = tap / 3, kx = tap - ky*3;
            int yy = y + ky - 1, xc = x + kx - 1;
            if (yy >= 0 && yy < 14 && xc >= 0 && xc < 14)
                toff[s] = (yy*14 + xc)*16;
        }
    }
    int mn0 = INT_MAX, mx0 = INT_MIN, mn1 = INT_MAX, mx1 = INT_MIN;
    #pragma unroll 1
    for (int it = 0; it < 16; it++){
        v4i acc0 = (v4i){0,0,0,0}, acc1 = (v4i){0,0,0,0};
        #pragma unroll
        for (int s = 0; s < 3; s++){
            v4i av = (toff[s] >= 0) ? *(const v4i*)(ip + toff[s]) : (v4i){0,0,0,0};
            acc0 = __builtin_amdgcn_mfma_i32_16x16x64_i8(av, bv[s],     acc0, 0, 0, 0);
            acc1 = __builtin_amdgcn_mfma_i32_16x16x64_i8(av, bv[3 + s], acc1, 0, 0, 0);
        }
        #pragma unroll
        for (int r = 0; r < 4; r++){
            mn0 = min(mn0, acc0[r]); mx0 = max(mx0, acc0[r]);
            mn1 = min(mn1, acc1[r]); mx1 = max(mx1, acc1[r]);
        }
        ip += (size_t)512*196*16;
    }
    mn0 = min(mn0, __shfl_xor(mn0, 16)); mn0 = min(mn0, __shfl_xor(mn0, 32));
    mx0 = max(mx0, __shfl_xor(mx0, 16)); mx0 = max(mx0, __shfl_xor(mx0, 32));
    mn1 = min(mn1, __shfl_xor(mn1, 16)); mn1 = min(mn1, __shfl_xor(mn1, 32));
    mx1 = max(mx1, __shfl_xor(mx1, 16)); mx1 = max(mx1, __shfl_xor(mx1, 32));
    if (l < 16){
        atomicMin(&smn[l], mn0);      atomicMax(&smx[l], mx0);
        atomicMin(&smn[16 + l], mn1); atomicMax(&smx[16 + l], mx1);
    }
    __syncthreads();
    if (t < 32){
        int* basep = stats2 + (blockIdx.x & (NCOPIES-1))*64;
        atomicMin(&basep[t],      smn[t]);
        atomicMax(&basep[t + 32], smx[t]);
    }
}

// ---------- scales for block2 from int code stats ----------
__global__ void k_scales2(const int* __restrict__ stats,
                          const float* __restrict__ g, const float* __restrict__ be,
                          const float* __restrict__ m, const float* __restrict__ v,
                          const float* __restrict__ b2,
                          const float* __restrict__ scales, const float* __restrict__ wscales,
                          float* __restrict__ s_out, float* __restrict__ bnA, float* __restrict__ bnB)
{
    __shared__ float cmn[32], cmx[32];
    int t = threadIdx.x;
    float S = scales[2] * wscales[1];
    if (t < 64){
        bool ismax = t >= 32; int c = t & 31;
        int acc = ismax ? INT_MIN : INT_MAX;
        for (int i = 0; i < NCOPIES; i++){
            int u = stats[i*64 + t];
            acc = ismax ? max(acc, u) : min(acc, u);
        }
        float val = fmaf(S, (float)acc, b2[c]);
        if (ismax) cmx[c] = val; else cmn[c] = val;
    }
    __syncthreads();
    if (t == 0){
        float am = 0.f;
        for (int c = 0; c < 32; c++) am = fmaxf(am, fmaxf(fabsf(cmn[c]), fabsf(cmx[c])));
        float sA_ = fmaxf(am / QMAXF, 1e-8f);
        float rmax = 0.f;
        float q1x[32], q1n[32];
        for (int c = 0; c < 32; c++){
            q1x[c] = fmaxf(fq_apply(cmx[c], sA_), 0.f);
            q1n[c] = fmaxf(fq_apply(cmn[c], sA_), 0.f);
            rmax = fmaxf(rmax, q1x[c]);
        }
        float sB_ = fmaxf(rmax / QMAXF, 1e-8f);
        float am3 = 0.f;
        for (int c = 0; c < 32; c++){
            float inv = g[c] / sqrtf(v[c] + BN_EPS);
            float dd  = be[c] - m[c]*inv;
            bnA[c] = inv; bnB[c] = dd;
            float ha = fmaf(fq_apply(q1x[c], sB_), inv, dd);
            float hb = fmaf(fq_apply(q1n[c], sB_), inv, dd);
            am3 = fmaxf(am3, fmaxf(fabsf(ha), fabsf(hb)));
        }
        float sC_ = fmaxf(am3 / QMAXF, 1e-8f);
        s_out[0] = sA_; s_out[1] = sB_; s_out[2] = sC_;
    }
}

// ---------- K8: block2 MFMA -> pool -> chain -> h2q (hoisted, direct stores) ----------
// tile = tile0 + it*25088 -> cell_g += 100352 = 2048 images; taps fixed, b += 2048.
__global__ __launch_bounds__(256) void k_block2_mfma(
    const int8_t* __restrict__ h1q, const int8_t* __restrict__ wpk2,
    const float* __restrict__ b2, const float* __restrict__ scales,
    const float* __restrict__ wscales,
    const float* __restrict__ bnA, const float* __restrict__ bnB,
    int8_t* __restrict__ h2q)
{
    int t = threadIdx.x, l = t & 63, wid = t >> 6;
    int hi = l >> 4, cl = l & 15;
    float S = scales[2] * wscales[1];
    float s4 = scales[3], s5 = scales[4], s6 = scales[5];
    float sb0 = b2[cl],      sA0 = bnA[cl],      sB0 = bnB[cl];
    float sb1 = b2[16 + cl], sA1 = bnA[16 + cl], sB1 = bnB[16 + cl];
    v4i bv[6];
    #pragma unroll
    for (int nt = 0; nt < 2; nt++)
        #pragma unroll
        for (int s = 0; s < 3; s++)
            bv[nt*3+s] = *(const v4i*)(wpk2 + nt*3072 + (4*s + hi)*256 + cl*16);
    int tile0 = blockIdx.x*4 + wid;                // 0..25087
    int grow = tile0*16 + (l & 15);
    int cell_g = grow >> 2;
    int b0 = cell_g / 49, cell = cell_g - b0*49;
    int sub = grow & 3;
    int qy = cell / 7, qx = cell - qy*7;
    int y = 2*qy + (sub >> 1), x = 2*qx + (sub & 1);
    const int8_t* ip = h1q + (size_t)b0*196*16;
    int toff[3];
    #pragma unroll
    for (int s = 0; s < 3; s++){
        int tap = 4*s + hi;
        toff[s] = -1;
        if (tap < 9){
            int ky = tap / 3, kx = tap - ky*3;
            int yy = y + ky - 1, xc = x + kx - 1;
            if (yy >= 0 && yy < 14 && xc >= 0 && xc < 14)
                toff[s] = (yy*14 + xc)*16;
        }
    }
    int8_t* h2o = h2q + (size_t)(tile0*4 + hi)*32 + cl;   // +16 for nt=1
    #pragma unroll 1
    for (int it = 0; it < 4; it++){
        v4i acc0 = (v4i){0,0,0,0}, acc1 = (v4i){0,0,0,0};
        #pragma unroll
        for (int s = 0; s < 3; s++){
            v4i av = (toff[s] >= 0) ? *(const v4i*)(ip + toff[s]) : (v4i){0,0,0,0};
            acc0 = __builtin_amdgcn_mfma_i32_16x16x64_i8(av, bv[s],     acc0, 0, 0, 0);
            acc1 = __builtin_amdgcn_mfma_i32_16x16x64_i8(av, bv[3 + s], acc1, 0, 0, 0);
        }
        int pool0 = max(max(acc0[0], acc0[1]), max(acc0[2], acc0[3]));
        int pool1 = max(max(acc1[0], acc1[1]), max(acc1[2], acc1[3]));
        float h0 = fq_apply(fmaf(S, (float)pool0, sb0), s4);
        h0 = fmaxf(h0, 0.f);
        h0 = fq_apply(h0, s5);
        h0 = fmaf(h0, sA0, sB0);
        h2o[0]  = (int8_t)(int)quant_k(h0, s6);
        float h1 = fq_apply(fmaf(S, (float)pool1, sb1), s4);
        h1 = fmaxf(h1, 0.f);
        h1 = fq_apply(h1, s5);
        h1 = fmaf(h1, sA1, sB1);
        h2o[16] = (int8_t)(int)quant_k(h1, s6);
        ip  += (size_t)2048*196*16;
        h2o += (size_t)100352*32;
    }
}

// ---------- K9: fc1 int8 MFMA, quarter-split: 2048 waves ----------
__global__ __launch_bounds__(256) void k_fc1(
    const int8_t* __restrict__ h2q, const int8_t* __restrict__ bpk1,
    const float* __restrict__ fb1, const float* __restrict__ scales,
    const float* __restrict__ wscales,
    float* __restrict__ fc1o, int* __restrict__ statsFc)
{
    __shared__ int smn, smx;
    int t = threadIdx.x, l = t & 63, wid = t >> 6;
    if (t == 0){ smn = INT_MAX; smx = INT_MIN; }
    __syncthreads();
    int wave_id = blockIdx.x*4 + wid;     // 2048 waves (512 blocks)
    int mtile = wave_id >> 2;             // 0..511
    int quarter = wave_id & 3;            // 2 o-groups each
    int hi = l >> 4, lo = l & 15;
    const int8_t* arow = h2q + (size_t)(mtile*16 + lo)*1568;
    v4i acc[2];
    #pragma unroll
    for (int g = 0; g < 2; g++) acc[g] = (v4i){0,0,0,0};
    #pragma unroll 1
    for (int kc = 0; kc < 25; kc++){
        int koff = kc*64 + hi*16;
        v4i av = (v4i){0,0,0,0};
        if (koff < 1568) av = *(const v4i*)(arow + koff);
        #pragma unroll
        for (int g = 0; g < 2; g++){
            v4i bvv = *(const v4i*)(bpk1 + (quarter*2 + g)*25600 + (kc*4 + hi)*256 + lo*16);
            acc[g] = __builtin_amdgcn_mfma_i32_16x16x64_i8(av, bvv, acc[g], 0, 0, 0);
        }
    }
    float Sfc = scales[5] * wscales[2];
    float lmn = INFINITY, lmx = -INFINITY;
    #pragma unroll
    for (int g = 0; g < 2; g++){
        int o = (quarter*2 + g)*16 + lo;
        float bias = fb1[o];
        #pragma unroll
        for (int r = 0; r < 4; r++){
            int m = mtile*16 + hi*4 + r;
            float val = fmaf(Sfc, (float)acc[g][r], bias);
            fc1o[(size_t)m*128 + o] = val;
            lmn = fminf(lmn, val); lmx = fmaxf(lmx, val);
        }
    }
    #pragma unroll
    for (int d = 1; d < 64; d <<= 1){
        lmn = fminf(lmn, __shfl_xor(lmn, d));
        lmx = fmaxf(lmx, __shfl_xor(lmx, d));
    }
    if (l == 0){
        atomicMin(&smn, f2ord(lmn));
        atomicMax(&smx, f2ord(lmx));
    }
    __syncthreads();
    if (t == 0){
        int* basep = statsFc + (blockIdx.x & (NCOPIES-1))*2;
        atomicMin(&basep[0], smn); atomicMax(&basep[1], smx);
    }
}

// ---------- K12: fc2 with inline h3 quantization ----------
__global__ __launch_bounds__(256) void k_fc2(
    const float* __restrict__ fc1o, const float* __restrict__ qfw2, const float* __restrict__ fb2,
    const int* __restrict__ statsFc, float* __restrict__ out, int* __restrict__ statsOut)
{
    __shared__ float sw[1280], sb2[10];
    __shared__ float s7s, s8s;
    __shared__ int smn, smx;
    int t = threadIdx.x;
    for (int i = t; i < 1280; i += 256) sw[i] = qfw2[i];
    if (t < 10) sb2[t] = fb2[t];
    if (t == 0){
        smn = INT_MAX; smx = INT_MIN;
        int mni = INT_MAX, mxi = INT_MIN;
        for (int i = 0; i < NCOPIES; i++){ mni = min(mni, statsFc[i*2]); mxi = max(mxi, statsFc[i*2+1]); }
        float mn = ord2f(mni), mx = ord2f(mxi);
        float am = fmaxf(fabsf(mn), fabsf(mx));
        float s7 = fmaxf(am / QMAXF, 1e-8f);
        float rmx = fmaxf(fq_apply(mx, s7), 0.f);
        s7s = s7; s8s = fmaxf(rmx / QMAXF, 1e-8f);
    }
    __syncthreads();
    float s7 = s7s, s8 = s8s;
    int b = blockIdx.x*256 + t;   // 8192 exact (32 blocks)
    float acc[10];
    #pragma unroll
    for (int j = 0; j < 10; j++) acc[j] = sb2[j];
    const float* fp = fc1o + (size_t)b*128;
    for (int k = 0; k < 128; k += 4){
        float4 f = *(const float4*)(fp + k);
        float v0 = s8 * quant_k(fmaxf(fq_apply(f.x, s7), 0.f), s8);
        float v1 = s8 * quant_k(fmaxf(fq_apply(f.y, s7), 0.f), s8);
        float v2 = s8 * quant_k(fmaxf(fq_apply(f.z, s7), 0.f), s8);
        float v3 = s8 * quant_k(fmaxf(fq_apply(f.w, s7), 0.f), s8);
        #pragma unroll
        for (int j = 0; j < 10; j++){
            float a = acc[j];
            a = fmaf(v0, sw[j*128 + k],     a);
            a = fmaf(v1, sw[j*128 + k + 1], a);
            a = fmaf(v2, sw[j*128 + k + 2], a);
            a = fmaf(v3, sw[j*128 + k + 3], a);
            acc[j] = a;
        }
    }
    float lmn = INFINITY, lmx = -INFINITY;
    #pragma unroll
    for (int j = 0; j < 10; j++){
        out[(size_t)b*10 + j] = acc[j];
        lmn = fminf(lmn, acc[j]); lmx = fmaxf(lmx, acc[j]);
    }
    atomicMin(&smn, f2ord(lmn)); atomicMax(&smx, f2ord(lmx));
    __syncthreads();
    if (t == 0){
        int* basep = statsOut + (blockIdx.x & (NCOPIES-1))*2;
        atomicMin(&basep[0], smn); atomicMax(&basep[1], smx);
    }
}

// ---------- K14: final fake-quant of d_out ----------
__global__ void k_quant_out(float* __restrict__ out, const int* __restrict__ statsOut, int n){
    __shared__ float s9s;
    if (threadIdx.x == 0){
        int mni = INT_MAX, mxi = INT_MIN;
        for (int i = 0; i < NCOPIES; i++){ mni = min(mni, statsOut[i*2]); mxi = max(mxi, statsOut[i*2+1]); }
        float am = fmaxf(fabsf(ord2f(mni)), fabsf(ord2f(mxi)));
        s9s = fmaxf(am / QMAXF, 1e-8f);
    }
    __syncthreads();
    int i = blockIdx.x*256 + threadIdx.x;
    if (i < n) out[i] = fq_apply(out[i], s9s);
}

// =================== host ===================
extern "C" void kernel_launch(void* const* d_in, const int* in_sizes, int n_in,
                              void* d_out, int out_size, void* d_ws, size_t ws_size,
                              hipStream_t stream)
{
    const float* x   = (const float*)d_in[0];
    const float* w1  = (const float*)d_in[1];
    const float* b1  = (const float*)d_in[2];
    const float* g1  = (const float*)d_in[3];
    const float* be1 = (const float*)d_in[4];
    const float* m1  = (const float*)d_in[5];
    const float* v1  = (const float*)d_in[6];
    const float* w2  = (const float*)d_in[7];
    const float* b2  = (const float*)d_in[8];
    const float* g2  = (const float*)d_in[9];
    const float* be2 = (const float*)d_in[10];
    const float* m2  = (const float*)d_in[11];
    const float* v2  = (const float*)d_in[12];
    const float* fw1 = (const float*)d_in[13];
    const float* fb1 = (const float*)d_in[14];
    const float* fw2 = (const float*)d_in[15];
    const float* fb2 = (const float*)d_in[16];
    float* out = (float*)d_out;

    char* ws = (char*)d_ws;
    size_t off = 0;
    auto alloc = [&](size_t bytes)->char*{
        char* p = ws + off;
        off = (off + bytes + 255) & ~(size_t)255;
        return p;
    };
    _Float16* wpk1h = (_Float16*)alloc(512*2);
    int8_t* wpk2  = (int8_t*)alloc(6144);
    int8_t* bpk1  = (int8_t*)alloc(204800);
    float* qfw2   = (float*)alloc(1280*4);
    float* scales = (float*)alloc(16*4);
    float* wscales= (float*)alloc(4*4);
    int* wsmax    = (int*)alloc(4*4);
    float* bn1A   = (float*)alloc(16*4);
    float* bn1B   = (float*)alloc(16*4);
    float* bn2A   = (float*)alloc(32*4);
    float* bn2B   = (float*)alloc(32*4);
    int* stats1   = (int*)alloc(64*32*4);
    int* stats2   = (int*)alloc(64*64*4);
    int* statsFc  = (int*)alloc(64*2*4);
    int* statsOut = (int*)alloc(64*2*4);
    uint32_t* xp  = (uint32_t*)alloc((size_t)8192*900*4);
    int8_t* h1q   = (int8_t*)alloc((size_t)8192*196*16);
    int8_t* h2q   = (int8_t*)alloc((size_t)8192*49*32);
    float* fc1o   = (float*)alloc((size_t)8192*128*4);
    (void)ws_size;

    k_init_stats<<<26, 256, 0, stream>>>(stats1, stats2, statsFc, statsOut, wsmax);
    k_wscales<<<67, 256, 0, stream>>>(w1, w2, fw1, fw2, wsmax);
    k_pack_weights<<<786, 256, 0, stream>>>(w1, w2, fw1, fw2, wsmax, wpk1h, wpk2, bpk1, qfw2, wscales);
    k_prep_x<<<28800, 256, 0, stream>>>(x, xp);
    k_conv1s_mfma<<<1568, 256, 0, stream>>>(xp, wpk1h, b1, wscales, stats1);
    k_scales_block<<<1, 64, 0, stream>>>(16, stats1, g1, be1, m1, v1, scales + 0, bn1A, bn1B);
    k_block1_mfma<<<6272, 256, 0, stream>>>(xp, wpk1h, b1, wscales, scales, bn1A, bn1B, h1q);
    k_conv2s_mfma<<<1568, 256, 0, stream>>>(h1q, wpk2, stats2);
    k_scales2<<<1, 64, 0, stream>>>(stats2, g2, be2, m2, v2, b2, scales, wscales, scales + 3, bn2A, bn2B);
    k_block2_mfma<<<6272, 256, 0, stream>>>(h1q, wpk2, b2, scales, wscales, bn2A, bn2B, h2q);
    k_fc1<<<512, 256, 0, stream>>>(h2q, bpk1, fb1, scales, wscales, fc1o, statsFc);
    k_fc2<<<32, 256, 0, stream>>>(fc1o, qfw2, fb2, statsFc, out, statsOut);
    k_quant_out<<<320, 256, 0, stream>>>(out, statsOut, out_size);
}

// Round 12
// 216.383 us; speedup vs baseline: 1.7056x; 1.1596x over previous
//
#include <hip/hip_runtime.h>
#include <math.h>
#include <limits.h>
#include <stdint.h>

#define QMAXF 127.0f
#define BN_EPS 1e-5f
#define NCOPIES 64

typedef int v4i __attribute__((ext_vector_type(4)));
typedef float f32x4 __attribute__((ext_vector_type(4)));
typedef _Float16 f16x8 __attribute__((ext_vector_type(8)));

// ---------- helpers ----------
__device__ __forceinline__ int f2ord(float f){
    int i = __float_as_int(f);
    return i ^ ((i >> 31) & 0x7fffffff);
}
__device__ __forceinline__ float ord2f(int i){
    return __int_as_float(i ^ ((i >> 31) & 0x7fffffff));
}
__device__ __forceinline__ float scale_from_ord(int om){
    return fmaxf(ord2f(om) / QMAXF, 1e-8f);
}
// fake-quant forward: clip(round(x/s))*s  (round = half-to-even, matches jnp.round)
__device__ __forceinline__ float fq_apply(float x, float s){
    float q = rintf(x / s);
    q = fminf(fmaxf(q, -QMAXF), QMAXF);
    return q * s;
}
// return clipped integer level as float
__device__ __forceinline__ float quant_k(float x, float s){
    float q = rintf(x / s);
    return fminf(fmaxf(q, -QMAXF), QMAXF);
}
__device__ __forceinline__ _Float16 hpart(uint32_t w){
    return __builtin_bit_cast(_Float16, (unsigned short)(w >> 16));
}
__device__ __forceinline__ _Float16 lpart(uint32_t w){
    return __builtin_bit_cast(_Float16, (unsigned short)(w & 0xffffu));
}

// ---------- K0: init stat buffers ----------
__global__ void k_init_stats(int* s1, int* s2, int* sf, int* so, int* wsmax){
    int t = blockIdx.x*blockDim.x + threadIdx.x;
    if (t < 2048){ int j = t & 31; s1[t] = (j < 16) ? INT_MAX : INT_MIN; }
    else if (t < 6144){ int u = t - 2048; int j = u & 63; s2[u] = (j < 32) ? INT_MAX : INT_MIN; }
    else if (t < 6272){ int u = t - 6144; sf[u] = ((u & 1) == 0) ? INT_MAX : INT_MIN; }
    else if (t < 6400){ int u = t - 6272; so[u] = ((u & 1) == 0) ? INT_MAX : INT_MIN; }
    else if (t < 6404){ wsmax[t - 6400] = INT_MIN; }
}

// ---------- K1a: per-tensor |w| max ----------
__global__ __launch_bounds__(256) void k_wscales(
    const float* __restrict__ w1, const float* __restrict__ w2,
    const float* __restrict__ fw1, const float* __restrict__ fw2,
    int* __restrict__ wsmax)
{
    __shared__ float red[256];
    int t = threadIdx.x, blk = blockIdx.x;
    const float* src; int n, base, which;
    if (blk < 64){ src = fw1; base = blk*3136; n = 3136; which = 2; }
    else if (blk == 64){ src = w1;  base = 0; n = 144;  which = 0; }
    else if (blk == 65){ src = w2;  base = 0; n = 4608; which = 1; }
    else { src = fw2; base = 0; n = 1280; which = 3; }
    float m = 0.f;
    for (int i = t; i < n; i += 256) m = fmaxf(m, fabsf(src[base + i]));
    red[t] = m; __syncthreads();
    for (int off = 128; off; off >>= 1){
        if (t < off) red[t] = fmaxf(red[t], red[t+off]);
        __syncthreads();
    }
    if (t == 0) atomicMax(&wsmax[which], f2ord(red[0]));
}

// ---------- K1b: pack/quantize weights ----------
// wpk1h: f16 codes, K-slot-spread: entry (hi*16+col)*8 + j = code(w1[col][hi*3+j])
// for hi<3 && j<3, else 0.
__global__ __launch_bounds__(256) void k_pack_weights(
    const float* __restrict__ w1, const float* __restrict__ w2,
    const float* __restrict__ fw1, const float* __restrict__ fw2,
    const int* __restrict__ wsmax,
    _Float16* __restrict__ wpk1h, int8_t* __restrict__ wpk2,
    int8_t* __restrict__ bpk1, float* __restrict__ qfw2,
    float* __restrict__ wscales)
{
    int blk = blockIdx.x, t = threadIdx.x;
    if (blk < 784){
        float s = scale_from_ord(wsmax[2]);
        int i = blk*256 + t;                      // 200704 exact
        int o = i / 1568, k = i - o*1568;
        int c = k / 49, r = k - c*49;
        int kp = r*32 + c;
        int kchunk = kp >> 6, rem = kp & 63, hi = rem >> 4, j = rem & 15;
        int code = (int)quant_k(fw1[i], s);
        bpk1[(o>>4)*25600 + (kchunk*4 + hi)*256 + (o&15)*16 + j] = (int8_t)code;
    } else if (blk == 784){
        float s0 = scale_from_ord(wsmax[0]), s3 = scale_from_ord(wsmax[3]);
        for (int i = t; i < 512; i += 256){
            int grp = i >> 3, j = i & 7;
            int hi = grp >> 4, col = grp & 15;
            _Float16 val = (_Float16)0.f;
            if (hi < 3 && j < 3)
                val = (_Float16)quant_k(w1[col*9 + hi*3 + j], s0);  // integer code, exact
            wpk1h[i] = val;
        }
        for (int i = t; i < 1280; i += 256) qfw2[i] = fq_apply(fw2[i], s3);
        for (int i = t; i < 4096; i += 256){
            int o = i >> 5, rem = (i & 31) + 32;  // kp 1568..1599 -> chunk24
            int hi = rem >> 4, j = rem & 15;
            bpk1[(o>>4)*25600 + (24*4 + hi)*256 + (o&15)*16 + j] = 0;
        }
        if (t < 4) wscales[t] = scale_from_ord(wsmax[t]);
    } else {
        float s1 = scale_from_ord(wsmax[1]);
        for (int i = t; i < 6144; i += 256) wpk2[i] = 0;
        __syncthreads();
        for (int i = t; i < 4608; i += 256){
            int co = i / 144, rr = i - co*144, ci = rr / 9, pix = rr - ci*9;
            wpk2[(co >> 4)*3072 + pix*256 + (co & 15)*16 + ci] = (int8_t)(int)quant_k(w2[i], s1);
        }
    }
}

// ---------- K1c: pad + hi/lo f16 split of x -> xp[b][30][30] (hi<<16 | lo) ----------
__global__ __launch_bounds__(256) void k_prep_x(
    const float* __restrict__ x, uint32_t* __restrict__ xp)
{
    int i = blockIdx.x*256 + threadIdx.x;   // 7,372,800 = 8192*900 exact
    int b = i / 900, r = i - b*900;
    int yy = r / 30, xx = r - yy*30;
    float val = 0.f;
    if (yy >= 1 && yy <= 28 && xx >= 1 && xx <= 28)
        val = x[(size_t)b*784 + (yy-1)*28 + (xx-1)];
    _Float16 h  = (_Float16)val;
    _Float16 lo = (_Float16)(val - (float)h);
    xp[i] = ((uint32_t)__builtin_bit_cast(unsigned short, h) << 16)
          |  (uint32_t)__builtin_bit_cast(unsigned short, lo);
}

// ---------- conv1 fragment: 3 contiguous dwords at row (y+hi), slots j=0..2 ----------
__device__ __forceinline__ void conv1_frag3(const uint32_t* __restrict__ base, bool valid,
                                            f16x8& ahi, f16x8& alo)
{
    uint32_t w0 = valid ? base[0] : 0u;
    uint32_t w1 = valid ? base[1] : 0u;
    uint32_t w2 = valid ? base[2] : 0u;
    _Float16 z = (_Float16)0.f;
    ahi = (f16x8){hpart(w0), hpart(w1), hpart(w2), z, z, z, z, z};
    alo = (f16x8){lpart(w0), lpart(w1), lpart(w2), z, z, z, z, z};
}

// ---------- K2: conv1 f16-split MFMA + per-channel min/max ----------
__global__ __launch_bounds__(256) void k_conv1s_mfma(
    const uint32_t* __restrict__ xp, const _Float16* __restrict__ wpk1h,
    const float* __restrict__ b1, const float* __restrict__ wscales,
    int* __restrict__ stats1)
{
    int t = threadIdx.x, l = t & 63, wid = t >> 6;
    int hi = l >> 4, col = l & 15;
    f16x8 bv = *(const f16x8*)(wpk1h + (hi*16 + col)*8);
    float sb = b1[col];
    float s0 = wscales[0];
    int tile0 = blockIdx.x*4 + wid;                // 0..6271
    int p0 = tile0*16 + (l & 15);
    int b0 = p0 / 784, r = p0 - b0*784;
    int y = r / 28, xx = r - y*28;
    int rowo = (hi < 3) ? hi : 2;
    bool valid = hi < 3;
    const uint32_t* base = xp + (size_t)b0*900 + (y + rowo)*30 + xx;
    float mn = INFINITY, mx = -INFINITY;
    #pragma unroll 1
    for (int it = 0; it < 64; it++){
        f16x8 ahi, alo;
        conv1_frag3(base, valid, ahi, alo);
        f32x4 acc = {0.f, 0.f, 0.f, 0.f};
        acc = __builtin_amdgcn_mfma_f32_16x16x32_f16(ahi, bv, acc, 0, 0, 0);
        acc = __builtin_amdgcn_mfma_f32_16x16x32_f16(alo, bv, acc, 0, 0, 0);
        #pragma unroll
        for (int rg = 0; rg < 4; rg++){
            mn = fminf(mn, acc[rg]); mx = fmaxf(mx, acc[rg]);
        }
        base += (size_t)128*900;
    }
    // affine after (monotone single op: exact)
    mn = fmaf(s0, mn, sb);
    mx = fmaf(s0, mx, sb);
    mn = fminf(mn, __shfl_xor(mn, 16)); mn = fminf(mn, __shfl_xor(mn, 32));
    mx = fmaxf(mx, __shfl_xor(mx, 16)); mx = fmaxf(mx, __shfl_xor(mx, 32));
    if (l < 16){
        int* basep = stats1 + (blockIdx.x & (NCOPIES-1))*32;
        atomicMin(&basep[l],      f2ord(mn));
        atomicMax(&basep[16 + l], f2ord(mx));
    }
}

// ---------- scales for block1 + chain LUT build ----------
__global__ __launch_bounds__(256) void k_scales_block(
    const int* __restrict__ stats,
    const float* __restrict__ g, const float* __restrict__ be,
    const float* __restrict__ m, const float* __restrict__ v,
    float* __restrict__ s_out, int8_t* __restrict__ t1buf)
{
    __shared__ float cmn[16], cmx[16], invs[16], dds[16], sss[3];
    int t = threadIdx.x;
    if (t < 32){
        bool ismax = t >= 16; int c = t & 15;
        int acc = ismax ? INT_MIN : INT_MAX;
        for (int i = 0; i < NCOPIES; i++){
            int u = stats[i*32 + t];
            acc = ismax ? max(acc, u) : min(acc, u);
        }
        if (ismax) cmx[c] = ord2f(acc); else cmn[c] = ord2f(acc);
    }
    __syncthreads();
    if (t == 0){
        float am = 0.f;
        for (int c = 0; c < 16; c++) am = fmaxf(am, fmaxf(fabsf(cmn[c]), fabsf(cmx[c])));
        float sA_ = fmaxf(am / QMAXF, 1e-8f);
        float rmax = 0.f;
        float q1x[16], q1n[16];
        for (int c = 0; c < 16; c++){
            q1x[c] = fmaxf(fq_apply(cmx[c], sA_), 0.f);
            q1n[c] = fmaxf(fq_apply(cmn[c], sA_), 0.f);
            rmax = fmaxf(rmax, q1x[c]);
        }
        float sB_ = fmaxf(rmax / QMAXF, 1e-8f);
        float am3 = 0.f;
        for (int c = 0; c < 16; c++){
            float inv = g[c] / sqrtf(v[c] + BN_EPS);
            float dd  = be[c] - m[c]*inv;
            invs[c] = inv; dds[c] = dd;
            float ha = fmaf(fq_apply(q1x[c], sB_), inv, dd);
            float hb = fmaf(fq_apply(q1n[c], sB_), inv, dd);
            am3 = fmaxf(am3, fmaxf(fabsf(ha), fabsf(hb)));
        }
        float sC_ = fmaxf(am3 / QMAXF, 1e-8f);
        sss[0] = sA_; sss[1] = sB_; sss[2] = sC_;
        s_out[0] = sA_; s_out[1] = sB_; s_out[2] = sC_;
    }
    __syncthreads();
    float s1 = sss[0], s2 = sss[1], s3 = sss[2];
    for (int e = t; e < 2048; e += 256){
        int c = e >> 7, idx = e & 127;
        float hh = (float)idx * s1;             // = q1*s1 (relu'd)
        float q2 = quant_k(hh, s2);
        float h2 = q2 * s2;
        float hb = fmaf(h2, invs[c], dds[c]);
        t1buf[e] = (int8_t)(int)quant_k(hb, s3);
    }
}

// ---------- K4: block1 MFMA -> pool -> 1 div + LUT -> h1q ----------
__global__ __launch_bounds__(256) void k_block1_mfma(
    const uint32_t* __restrict__ xp, const _Float16* __restrict__ wpk1h,
    const float* __restrict__ b1, const float* __restrict__ wscales,
    const float* __restrict__ scales, const int8_t* __restrict__ t1buf,
    int8_t* __restrict__ h1q)
{
    __shared__ int8_t T1l[16*132];
    int t = threadIdx.x, l = t & 63, wid = t >> 6;
    for (int e = t; e < 2048; e += 256)
        T1l[(e >> 7)*132 + (e & 127)] = t1buf[e];
    __syncthreads();
    int hi = l >> 4, col = l & 15;
    f16x8 bv = *(const f16x8*)(wpk1h + (hi*16 + col)*8);
    float sb = b1[col];
    float s0 = wscales[0], s1 = scales[0];
    int tile0 = blockIdx.x*4 + wid;                // 0..25087
    int grow = tile0*16 + (l & 15);
    int cell = grow >> 2, sub = grow & 3;
    int b0 = cell / 196, rc = cell - b0*196;
    int py = rc / 14, px = rc - py*14;
    int y = 2*py + (sub >> 1), xx = 2*px + (sub & 1);
    int rowo = (hi < 3) ? hi : 2;
    bool valid = hi < 3;
    const uint32_t* base = xp + (size_t)b0*900 + (y + rowo)*30 + xx;
    const int8_t* T1c = T1l + col*132;
    int8_t* h1o = h1q + (size_t)tile0*64 + l;
    #pragma unroll 1
    for (int it = 0; it < 16; it++){
        f16x8 ahi, alo;
        conv1_frag3(base, valid, ahi, alo);
        f32x4 acc = {0.f, 0.f, 0.f, 0.f};
        acc = __builtin_amdgcn_mfma_f32_16x16x32_f16(ahi, bv, acc, 0, 0, 0);
        acc = __builtin_amdgcn_mfma_f32_16x16x32_f16(alo, bv, acc, 0, 0, 0);
        float pool = fmaxf(fmaxf(acc[0], acc[1]), fmaxf(acc[2], acc[3]));
        float conv = fmaf(s0, pool, sb);
        float q = quant_k(conv, s1);
        int idx = (int)fmaxf(q, 0.f);
        *h1o = T1c[idx];
        base += (size_t)512*900;
        h1o  += (size_t)100352*16;
    }
}

// ---------- K6: conv2 int8 MFMA + per-channel code min/max (hoisted) ----------
__global__ __launch_bounds__(256) void k_conv2s_mfma(
    const int8_t* __restrict__ h1q, const int8_t* __restrict__ wpk2,
    int* __restrict__ stats2)
{
    __shared__ int smn[32], smx[32];
    int t = threadIdx.x, l = t & 63, wid = t >> 6;
    if (t < 32){ smn[t] = INT_MAX; smx[t] = INT_MIN; }
    __syncthreads();
    int hi = l >> 4;
    v4i bv[6];
    #pragma unroll
    for (int nt = 0; nt < 2; nt++)
        #pragma unroll
        for (int s = 0; s < 3; s++)
            bv[nt*3+s] = *(const v4i*)(wpk2 + nt*3072 + (4*s + hi)*256 + (l&15)*16);
    int tile0 = blockIdx.x*4 + wid;                // 0..6271
    int grow = tile0*16 + (l & 15);
    int cell_g = grow >> 2;
    int b0 = cell_g / 49, cell = cell_g - b0*49;
    int sub = grow & 3;
    int qy = cell / 7, qx = cell - qy*7;
    int y = 2*qy + (sub >> 1), x = 2*qx + (sub & 1);
    const int8_t* ip = h1q + (size_t)b0*196*16;
    int toff[3];
    #pragma unroll
    for (int s = 0; s < 3; s++){
        int tap = 4*s + hi;
        toff[s] = -1;
        if (tap < 9){
            int ky = tap / 3, kx = tap - ky*3;
            int yy = y + ky - 1, xc = x + kx - 1;
            if (yy >= 0 && yy < 14 && xc >= 0 && xc < 14)
                toff[s] = (yy*14 + xc)*16;
        }
    }
    int mn0 = INT_MAX, mx0 = INT_MIN, mn1 = INT_MAX, mx1 = INT_MIN;
    #pragma unroll 1
    for (int it = 0; it < 16; it++){
        v4i acc0 = (v4i){0,0,0,0}, acc1 = (v4i){0,0,0,0};
        #pragma unroll
        for (int s = 0; s < 3; s++){
            v4i av = (toff[s] >= 0) ? *(const v4i*)(ip + toff[s]) : (v4i){0,0,0,0};
            acc0 = __builtin_amdgcn_mfma_i32_16x16x64_i8(av, bv[s],     acc0, 0, 0, 0);
            acc1 = __builtin_amdgcn_mfma_i32_16x16x64_i8(av, bv[3 + s], acc1, 0, 0, 0);
        }
        #pragma unroll
        for (int r = 0; r < 4; r++){
            mn0 = min(mn0, acc0[r]); mx0 = max(mx0, acc0[r]);
            mn1 = min(mn1, acc1[r]); mx1 = max(mx1, acc1[r]);
        }
        ip += (size_t)512*196*16;
    }
    mn0 = min(mn0, __shfl_xor(mn0, 16)); mn0 = min(mn0, __shfl_xor(mn0, 32));
    mx0 = max(mx0, __shfl_xor(mx0, 16)); mx0 = max(mx0, __shfl_xor(mx0, 32));
    mn1 = min(mn1, __shfl_xor(mn1, 16)); mn1 = min(mn1, __shfl_xor(mn1, 32));
    mx1 = max(mx1, __shfl_xor(mx1, 16)); mx1 = max(mx1, __shfl_xor(mx1, 32));
    if (l < 16){
        atomicMin(&smn[l], mn0);      atomicMax(&smx[l], mx0);
        atomicMin(&smn[16 + l], mn1); atomicMax(&smx[16 + l], mx1);
    }
    __syncthreads();
    if (t < 32){
        int* basep = stats2 + (blockIdx.x & (NCOPIES-1))*64;
        atomicMin(&basep[t],      smn[t]);
        atomicMax(&basep[t + 32], smx[t]);
    }
}

// ---------- scales for block2 + chain LUT build ----------
__global__ __launch_bounds__(256) void k_scales2(
    const int* __restrict__ stats,
    const float* __restrict__ g, const float* __restrict__ be,
    const float* __restrict__ m, const float* __restrict__ v,
    const float* __restrict__ b2,
    const float* __restrict__ scales, const float* __restrict__ wscales,
    float* __restrict__ s_out, int8_t* __restrict__ t2buf)
{
    __shared__ float cmn[32], cmx[32], invs[32], dds[32], sss[3];
    int t = threadIdx.x;
    float S = scales[2] * wscales[1];
    if (t < 64){
        bool ismax = t >= 32; int c = t & 31;
        int acc = ismax ? INT_MIN : INT_MAX;
        for (int i = 0; i < NCOPIES; i++){
            int u = stats[i*64 + t];
            acc = ismax ? max(acc, u) : min(acc, u);
        }
        float val = fmaf(S, (float)acc, b2[c]);
        if (ismax) cmx[c] = val; else cmn[c] = val;
    }
    __syncthreads();
    if (t == 0){
        float am = 0.f;
        for (int c = 0; c < 32; c++) am = fmaxf(am, fmaxf(fabsf(cmn[c]), fabsf(cmx[c])));
        float sA_ = fmaxf(am / QMAXF, 1e-8f);
        float rmax = 0.f;
        float q1x[32], q1n[32];
        for (int c = 0; c < 32; c++){
            q1x[c] = fmaxf(fq_apply(cmx[c], sA_), 0.f);
            q1n[c] = fmaxf(fq_apply(cmn[c], sA_), 0.f);
            rmax = fmaxf(rmax, q1x[c]);
        }
        float sB_ = fmaxf(rmax / QMAXF, 1e-8f);
        float am3 = 0.f;
        for (int c = 0; c < 32; c++){
            float inv = g[c] / sqrtf(v[c] + BN_EPS);
            float dd  = be[c] - m[c]*inv;
            invs[c] = inv; dds[c] = dd;
            float ha = fmaf(fq_apply(q1x[c], sB_), inv, dd);
            float hb = fmaf(fq_apply(q1n[c], sB_), inv, dd);
            am3 = fmaxf(am3, fmaxf(fabsf(ha), fabsf(hb)));
        }
        float sC_ = fmaxf(am3 / QMAXF, 1e-8f);
        sss[0] = sA_; sss[1] = sB_; sss[2] = sC_;
        s_out[0] = sA_; s_out[1] = sB_; s_out[2] = sC_;
    }
    __syncthreads();
    float s4 = sss[0], s5 = sss[1], s6 = sss[2];
    for (int e = t; e < 4096; e += 256){
        int c = e >> 7, idx = e & 127;
        float hh = (float)idx * s4;
        float q5 = quant_k(hh, s5);
        float h2 = q5 * s5;
        float hb = fmaf(h2, invs[c], dds[c]);
        t2buf[e] = (int8_t)(int)quant_k(hb, s6);
    }
}

// ---------- K8: block2 MFMA -> pool -> 1 div + LUT -> h2q ----------
__global__ __launch_bounds__(256) void k_block2_mfma(
    const int8_t* __restrict__ h1q, const int8_t* __restrict__ wpk2,
    const float* __restrict__ b2, const float* __restrict__ scales,
    const float* __restrict__ wscales, const int8_t* __restrict__ t2buf,
    int8_t* __restrict__ h2q)
{
    __shared__ int8_t T2l[32*132];
    int t = threadIdx.x, l = t & 63, wid = t >> 6;
    for (int e = t; e < 4096; e += 256)
        T2l[(e >> 7)*132 + (e & 127)] = t2buf[e];
    __syncthreads();
    int hi = l >> 4, cl = l & 15;
    float S = scales[2] * wscales[1];
    float s4 = scales[3];
    float sb0 = b2[cl], sb1 = b2[16 + cl];
    const int8_t* T2a = T2l + cl*132;
    const int8_t* T2b = T2l + (16 + cl)*132;
    v4i bv[6];
    #pragma unroll
    for (int nt = 0; nt < 2; nt++)
        #pragma unroll
        for (int s = 0; s < 3; s++)
            bv[nt*3+s] = *(const v4i*)(wpk2 + nt*3072 + (4*s + hi)*256 + cl*16);
    int tile0 = blockIdx.x*4 + wid;                // 0..25087
    int grow = tile0*16 + (l & 15);
    int cell_g = grow >> 2;
    int b0 = cell_g / 49, cell = cell_g - b0*49;
    int sub = grow & 3;
    int qy = cell / 7, qx = cell - qy*7;
    int y = 2*qy + (sub >> 1), x = 2*qx + (sub & 1);
    const int8_t* ip = h1q + (size_t)b0*196*16;
    int toff[3];
    #pragma unroll
    for (int s = 0; s < 3; s++){
        int tap = 4*s + hi;
        toff[s] = -1;
        if (tap < 9){
            int ky = tap / 3, kx = tap - ky*3;
            int yy = y + ky - 1, xc = x + kx - 1;
            if (yy >= 0 && yy < 14 && xc >= 0 && xc < 14)
                toff[s] = (yy*14 + xc)*16;
        }
    }
    int8_t* h2o = h2q + (size_t)(tile0*4 + hi)*32 + cl;   // +16 for nt=1
    #pragma unroll 1
    for (int it = 0; it < 4; it++){
        v4i acc0 = (v4i){0,0,0,0}, acc1 = (v4i){0,0,0,0};
        #pragma unroll
        for (int s = 0; s < 3; s++){
            v4i av = (toff[s] >= 0) ? *(const v4i*)(ip + toff[s]) : (v4i){0,0,0,0};
            acc0 = __builtin_amdgcn_mfma_i32_16x16x64_i8(av, bv[s],     acc0, 0, 0, 0);
            acc1 = __builtin_amdgcn_mfma_i32_16x16x64_i8(av, bv[3 + s], acc1, 0, 0, 0);
        }
        int pool0 = max(max(acc0[0], acc0[1]), max(acc0[2], acc0[3]));
        int pool1 = max(max(acc1[0], acc1[1]), max(acc1[2], acc1[3]));
        float q0 = quant_k(fmaf(S, (float)pool0, sb0), s4);
        float q1 = quant_k(fmaf(S, (float)pool1, sb1), s4);
        h2o[0]  = T2a[(int)fmaxf(q0, 0.f)];
        h2o[16] = T2b[(int)fmaxf(q1, 0.f)];
        ip  += (size_t)2048*196*16;
        h2o += (size_t)100352*32;
    }
}

// ---------- K9: fc1 int8 MFMA, quarter-split: 2048 waves ----------
__global__ __launch_bounds__(256) void k_fc1(
    const int8_t* __restrict__ h2q, const int8_t* __restrict__ bpk1,
    const float* __restrict__ fb1, const float* __restrict__ scales,
    const float* __restrict__ wscales,
    float* __restrict__ fc1o, int* __restrict__ statsFc)
{
    __shared__ int smn, smx;
    int t = threadIdx.x, l = t & 63, wid = t >> 6;
    if (t == 0){ smn = INT_MAX; smx = INT_MIN; }
    __syncthreads();
    int wave_id = blockIdx.x*4 + wid;     // 2048 waves (512 blocks)
    int mtile = wave_id >> 2;             // 0..511
    int quarter = wave_id & 3;            // 2 o-groups each
    int hi = l >> 4, lo = l & 15;
    const int8_t* arow = h2q + (size_t)(mtile*16 + lo)*1568;
    v4i acc[2];
    #pragma unroll
    for (int g = 0; g < 2; g++) acc[g] = (v4i){0,0,0,0};
    #pragma unroll 1
    for (int kc = 0; kc < 25; kc++){
        int koff = kc*64 + hi*16;
        v4i av = (v4i){0,0,0,0};
        if (koff < 1568) av = *(const v4i*)(arow + koff);
        #pragma unroll
        for (int g = 0; g < 2; g++){
            v4i bvv = *(const v4i*)(bpk1 + (quarter*2 + g)*25600 + (kc*4 + hi)*256 + lo*16);
            acc[g] = __builtin_amdgcn_mfma_i32_16x16x64_i8(av, bvv, acc[g], 0, 0, 0);
        }
    }
    float Sfc = scales[5] * wscales[2];
    float lmn = INFINITY, lmx = -INFINITY;
    #pragma unroll
    for (int g = 0; g < 2; g++){
        int o = (quarter*2 + g)*16 + lo;
        float bias = fb1[o];
        #pragma unroll
        for (int r = 0; r < 4; r++){
            int m = mtile*16 + hi*4 + r;
            float val = fmaf(Sfc, (float)acc[g][r], bias);
            fc1o[(size_t)m*128 + o] = val;
            lmn = fminf(lmn, val); lmx = fmaxf(lmx, val);
        }
    }
    #pragma unroll
    for (int d = 1; d < 64; d <<= 1){
        lmn = fminf(lmn, __shfl_xor(lmn, d));
        lmx = fmaxf(lmx, __shfl_xor(lmx, d));
    }
    if (l == 0){
        atomicMin(&smn, f2ord(lmn));
        atomicMax(&smx, f2ord(lmx));
    }
    __syncthreads();
    if (t == 0){
        int* basep = statsFc + (blockIdx.x & (NCOPIES-1))*2;
        atomicMin(&basep[0], smn); atomicMax(&basep[1], smx);
    }
}

// ---------- K12: fc2 with LUT'd h3 quantization ----------
__global__ __launch_bounds__(256) void k_fc2(
    const float* __restrict__ fc1o, const float* __restrict__ qfw2, const float* __restrict__ fb2,
    const int* __restrict__ statsFc, float* __restrict__ out, int* __restrict__ statsOut)
{
    __shared__ float sw[1280], sb2[10], Tf[128];
    __shared__ float s7sh, s8sh;
    __shared__ int smn, smx;
    int t = threadIdx.x;
    for (int i = t; i < 1280; i += 256) sw[i] = qfw2[i];
    if (t < 10) sb2[t] = fb2[t];
    if (t == 0){
        smn = INT_MAX; smx = INT_MIN;
        int mni = INT_MAX, mxi = INT_MIN;
        for (int i = 0; i < NCOPIES; i++){ mni = min(mni, statsFc[i*2]); mxi = max(mxi, statsFc[i*2+1]); }
        float mn = ord2f(mni), mx = ord2f(mxi);
        float am = fmaxf(fabsf(mn), fabsf(mx));
        float s7 = fmaxf(am / QMAXF, 1e-8f);
        float rmx = fmaxf(fq_apply(mx, s7), 0.f);
        s7sh = s7; s8sh = fmaxf(rmx / QMAXF, 1e-8f);
    }
    __syncthreads();
    float s7 = s7sh, s8 = s8sh;
    if (t < 128) Tf[t] = s8 * quant_k((float)t * s7, s8);
    __syncthreads();
    int b = blockIdx.x*256 + t;   // 8192 exact (32 blocks)
    float acc[10];
    #pragma unroll
    for (int j = 0; j < 10; j++) acc[j] = sb2[j];
    const float* fp = fc1o + (size_t)b*128;
    for (int k = 0; k < 128; k += 4){
        float4 f = *(const float4*)(fp + k);
        float v0 = Tf[(int)fmaxf(quant_k(f.x, s7), 0.f)];
        float v1 = Tf[(int)fmaxf(quant_k(f.y, s7), 0.f)];
        float v2 = Tf[(int)fmaxf(quant_k(f.z, s7), 0.f)];
        float v3 = Tf[(int)fmaxf(quant_k(f.w, s7), 0.f)];
        #pragma unroll
        for (int j = 0; j < 10; j++){
            float a = acc[j];
            a = fmaf(v0, sw[j*128 + k],     a);
            a = fmaf(v1, sw[j*128 + k + 1], a);
            a = fmaf(v2, sw[j*128 + k + 2], a);
            a = fmaf(v3, sw[j*128 + k + 3], a);
            acc[j] = a;
        }
    }
    float lmn = INFINITY, lmx = -INFINITY;
    #pragma unroll
    for (int j = 0; j < 10; j++){
        out[(size_t)b*10 + j] = acc[j];
        lmn = fminf(lmn, acc[j]); lmx = fmaxf(lmx, acc[j]);
    }
    atomicMin(&smn, f2ord(lmn)); atomicMax(&smx, f2ord(lmx));
    __syncthreads();
    if (t == 0){
        int* basep = statsOut + (blockIdx.x & (NCOPIES-1))*2;
        atomicMin(&basep[0], smn); atomicMax(&basep[1], smx);
    }
}

// ---------- K14: final fake-quant of d_out ----------
__global__ void k_quant_out(float* __restrict__ out, const int* __restrict__ statsOut, int n){
    __shared__ float s9s;
    if (threadIdx.x == 0){
        int mni = INT_MAX, mxi = INT_MIN;
        for (int i = 0; i < NCOPIES; i++){ mni = min(mni, statsOut[i*2]); mxi = max(mxi, statsOut[i*2+1]); }
        float am = fmaxf(fabsf(ord2f(mni)), fabsf(ord2f(mxi)));
        s9s = fmaxf(am / QMAXF, 1e-8f);
    }
    __syncthreads();
    int i = blockIdx.x*256 + threadIdx.x;
    if (i < n) out[i] = fq_apply(out[i], s9s);
}

// =================== host ===================
extern "C" void kernel_launch(void* const* d_in, const int* in_sizes, int n_in,
                              void* d_out, int out_size, void* d_ws, size_t ws_size,
                              hipStream_t stream)
{
    const float* x   = (const float*)d_in[0];
    const float* w1  = (const float*)d_in[1];
    const float* b1  = (const float*)d_in[2];
    const float* g1  = (const float*)d_in[3];
    const float* be1 = (const float*)d_in[4];
    const float* m1  = (const float*)d_in[5];
    const float* v1  = (const float*)d_in[6];
    const float* w2  = (const float*)d_in[7];
    const float* b2  = (const float*)d_in[8];
    const float* g2  = (const float*)d_in[9];
    const float* be2 = (const float*)d_in[10];
    const float* m2  = (const float*)d_in[11];
    const float* v2  = (const float*)d_in[12];
    const float* fw1 = (const float*)d_in[13];
    const float* fb1 = (const float*)d_in[14];
    const float* fw2 = (const float*)d_in[15];
    const float* fb2 = (const float*)d_in[16];
    float* out = (float*)d_out;

    char* ws = (char*)d_ws;
    size_t off = 0;
    auto alloc = [&](size_t bytes)->char*{
        char* p = ws + off;
        off = (off + bytes + 255) & ~(size_t)255;
        return p;
    };
    _Float16* wpk1h = (_Float16*)alloc(512*2);
    int8_t* wpk2  = (int8_t*)alloc(6144);
    int8_t* bpk1  = (int8_t*)alloc(204800);
    float* qfw2   = (float*)alloc(1280*4);
    float* scales = (float*)alloc(16*4);
    float* wscales= (float*)alloc(4*4);
    int* wsmax    = (int*)alloc(4*4);
    int8_t* t1buf = (int8_t*)alloc(2048);
    int8_t* t2buf = (int8_t*)alloc(4096);
    int* stats1   = (int*)alloc(64*32*4);
    int* stats2   = (int*)alloc(64*64*4);
    int* statsFc  = (int*)alloc(64*2*4);
    int* statsOut = (int*)alloc(64*2*4);
    uint32_t* xp  = (uint32_t*)alloc((size_t)8192*900*4);
    int8_t* h1q   = (int8_t*)alloc((size_t)8192*196*16);
    int8_t* h2q   = (int8_t*)alloc((size_t)8192*49*32);
    float* fc1o   = (float*)alloc((size_t)8192*128*4);
    (void)ws_size;

    k_init_stats<<<26, 256, 0, stream>>>(stats1, stats2, statsFc, statsOut, wsmax);
    k_wscales<<<67, 256, 0, stream>>>(w1, w2, fw1, fw2, wsmax);
    k_pack_weights<<<786, 256, 0, stream>>>(w1, w2, fw1, fw2, wsmax, wpk1h, wpk2, bpk1, qfw2, wscales);
    k_prep_x<<<28800, 256, 0, stream>>>(x, xp);
    k_conv1s_mfma<<<1568, 256, 0, stream>>>(xp, wpk1h, b1, wscales, stats1);
    k_scales_block<<<1, 256, 0, stream>>>(stats1, g1, be1, m1, v1, scales + 0, t1buf);
    k_block1_mfma<<<6272, 256, 0, stream>>>(xp, wpk1h, b1, wscales, scales, t1buf, h1q);
    k_conv2s_mfma<<<1568, 256, 0, stream>>>(h1q, wpk2, stats2);
    k_scales2<<<1, 256, 0, stream>>>(stats2, g2, be2, m2, v2, b2, scales, wscales, scales + 3, t2buf);
    k_block2_mfma<<<6272, 256, 0, stream>>>(h1q, wpk2, b2, scales, wscales, t2buf, h2q);
    k_fc1<<<512, 256, 0, stream>>>(h2q, bpk1, fb1, scales, wscales, fc1o, statsFc);
    k_fc2<<<32, 256, 0, stream>>>(fc1o, qfw2, fb2, statsFc, out, statsOut);
    k_quant_out<<<320, 256, 0, stream>>>(out, statsOut, out_size);
}

// Round 13
// 197.843 us; speedup vs baseline: 1.8655x; 1.0937x over previous
//
#include <hip/hip_runtime.h>
#include <math.h>
#include <limits.h>
#include <stdint.h>

#define QMAXF 127.0f
#define BN_EPS 1e-5f
#define NCOPIES 64

typedef int v4i __attribute__((ext_vector_type(4)));
typedef float f32x4 __attribute__((ext_vector_type(4)));
typedef _Float16 f16x8 __attribute__((ext_vector_type(8)));

// ---------- helpers ----------
__device__ __forceinline__ int f2ord(float f){
    int i = __float_as_int(f);
    return i ^ ((i >> 31) & 0x7fffffff);
}
__device__ __forceinline__ float ord2f(int i){
    return __int_as_float(i ^ ((i >> 31) & 0x7fffffff));
}
__device__ __forceinline__ float scale_of(float m){
    return fmaxf(m / QMAXF, 1e-8f);
}
// fake-quant forward: clip(round(x/s))*s  (round = half-to-even, matches jnp.round)
__device__ __forceinline__ float fq_apply(float x, float s){
    float q = rintf(x / s);
    q = fminf(fmaxf(q, -QMAXF), QMAXF);
    return q * s;
}
// return clipped integer level as float
__device__ __forceinline__ float quant_k(float x, float s){
    float q = rintf(x / s);
    return fminf(fmaxf(q, -QMAXF), QMAXF);
}
__device__ __forceinline__ _Float16 hpart(uint32_t w){
    return __builtin_bit_cast(_Float16, (unsigned short)(w >> 16));
}
__device__ __forceinline__ _Float16 lpart(uint32_t w){
    return __builtin_bit_cast(_Float16, (unsigned short)(w & 0xffffu));
}

// ---------- K0: init stat buffers + per-block |w| partial max (no atomics) ----------
__global__ __launch_bounds__(256) void k_init_ws(
    const float* __restrict__ w1, const float* __restrict__ w2,
    const float* __restrict__ fw1, const float* __restrict__ fw2,
    int* __restrict__ s1, int* __restrict__ s2, int* __restrict__ sf, int* __restrict__ so,
    float* __restrict__ wsbuf /*[67]*/)
{
    int blk = blockIdx.x, t = threadIdx.x;
    if (blk < 26){
        int gt = blk*256 + t;
        if (gt < 2048){ int j = gt & 31; s1[gt] = (j < 16) ? INT_MAX : INT_MIN; }
        else if (gt < 6144){ int u = gt - 2048; int j = u & 63; s2[u] = (j < 32) ? INT_MAX : INT_MIN; }
        else if (gt < 6272){ int u = gt - 6144; sf[u] = ((u & 1) == 0) ? INT_MAX : INT_MIN; }
        else if (gt < 6400){ int u = gt - 6272; so[u] = ((u & 1) == 0) ? INT_MAX : INT_MIN; }
        return;
    }
    __shared__ float red[256];
    int b2 = blk - 26;   // 0..66
    const float* src; int n, base;
    if (b2 < 64){ src = fw1; base = b2*3136; n = 3136; }
    else if (b2 == 64){ src = w1;  base = 0; n = 144; }
    else if (b2 == 65){ src = w2;  base = 0; n = 4608; }
    else { src = fw2; base = 0; n = 1280; }
    float m = 0.f;
    for (int i = t; i < n; i += 256) m = fmaxf(m, fabsf(src[base + i]));
    red[t] = m; __syncthreads();
    for (int off = 128; off; off >>= 1){
        if (t < off) red[t] = fmaxf(red[t], red[t+off]);
        __syncthreads();
    }
    if (t == 0) wsbuf[b2] = red[0];
}

// ---------- K1: pack/quantize weights + pad/split x ----------
// wpk1h: f16 codes, slot-spread with hi/lo duplication:
//   entry (hi*16+col)*8 + j: hi<3 && j<3 -> code(w1[col][hi*3+j]);
//                            hi<3 && 3<=j<6 -> same code (for lo-parts); else 0.
__global__ __launch_bounds__(256) void k_pack_prep(
    const float* __restrict__ x,
    const float* __restrict__ w1, const float* __restrict__ w2,
    const float* __restrict__ fw1, const float* __restrict__ fw2,
    const float* __restrict__ wsbuf,
    _Float16* __restrict__ wpk1h, int8_t* __restrict__ wpk2,
    int8_t* __restrict__ bpk1, float* __restrict__ qfw2,
    float* __restrict__ wscales, uint32_t* __restrict__ xp)
{
    int blk = blockIdx.x, t = threadIdx.x;
    if (blk >= 786){
        int i = (blk - 786)*256 + t;        // 7,372,800 = 8192*900 exact
        int b = i / 900, r = i - b*900;
        int yy = r / 30, xx = r - yy*30;
        float val = 0.f;
        if (yy >= 1 && yy <= 28 && xx >= 1 && xx <= 28)
            val = x[(size_t)b*784 + (yy-1)*28 + (xx-1)];
        _Float16 h  = (_Float16)val;
        _Float16 lo = (_Float16)(val - (float)h);
        xp[i] = ((uint32_t)__builtin_bit_cast(unsigned short, h) << 16)
              |  (uint32_t)__builtin_bit_cast(unsigned short, lo);
        return;
    }
    if (blk < 784){
        float m = 0.f;
        #pragma unroll
        for (int i = 0; i < 64; i++) m = fmaxf(m, wsbuf[i]);
        float s = scale_of(m);
        int i = blk*256 + t;                      // 200704 exact
        int o = i / 1568, k = i - o*1568;
        int c = k / 49, r = k - c*49;
        int kp = r*32 + c;
        int kchunk = kp >> 6, rem = kp & 63, hi = rem >> 4, j = rem & 15;
        int code = (int)quant_k(fw1[i], s);
        bpk1[(o>>4)*25600 + (kchunk*4 + hi)*256 + (o&15)*16 + j] = (int8_t)code;
    } else if (blk == 784){
        float s0 = scale_of(wsbuf[64]), s3 = scale_of(wsbuf[66]);
        for (int i = t; i < 512; i += 256){
            int grp = i >> 3, j = i & 7;
            int hi = grp >> 4, col = grp & 15;
            _Float16 val = (_Float16)0.f;
            if (hi < 3){
                int jj = (j < 3) ? j : ((j < 6) ? (j - 3) : -1);
                if (jj >= 0) val = (_Float16)quant_k(w1[col*9 + hi*3 + jj], s0);  // exact int code
            }
            wpk1h[i] = val;
        }
        for (int i = t; i < 1280; i += 256) qfw2[i] = fq_apply(fw2[i], s3);
        for (int i = t; i < 4096; i += 256){
            int o = i >> 5, rem = (i & 31) + 32;  // kp 1568..1599 -> chunk24
            int hi = rem >> 4, j = rem & 15;
            bpk1[(o>>4)*25600 + (24*4 + hi)*256 + (o&15)*16 + j] = 0;
        }
        if (t == 0){
            float m = 0.f;
            for (int i = 0; i < 64; i++) m = fmaxf(m, wsbuf[i]);
            wscales[0] = scale_of(wsbuf[64]);
            wscales[1] = scale_of(wsbuf[65]);
            wscales[2] = scale_of(m);
            wscales[3] = scale_of(wsbuf[66]);
        }
    } else {
        float s1 = scale_of(wsbuf[65]);
        for (int i = t; i < 6144; i += 256) wpk2[i] = 0;
        __syncthreads();
        for (int i = t; i < 4608; i += 256){
            int co = i / 144, rr = i - co*144, ci = rr / 9, pix = rr - ci*9;
            wpk2[(co >> 4)*3072 + pix*256 + (co & 15)*16 + ci] = (int8_t)(int)quant_k(w2[i], s1);
        }
    }
}

// ---------- conv1 fragment: hi-parts at slots 0-2, lo-parts at 3-5 (one MFMA) ----------
__device__ __forceinline__ f16x8 conv1_fragHL(const uint32_t* __restrict__ base, bool valid)
{
    uint32_t w0 = valid ? base[0] : 0u;
    uint32_t w1 = valid ? base[1] : 0u;
    uint32_t w2 = valid ? base[2] : 0u;
    _Float16 z = (_Float16)0.f;
    return (f16x8){hpart(w0), hpart(w1), hpart(w2),
                   lpart(w0), lpart(w1), lpart(w2), z, z};
}

// ---------- K2: conv1 MFMA + per-channel min/max (paired tiles for ILP) ----------
__global__ __launch_bounds__(256) void k_conv1s_mfma(
    const uint32_t* __restrict__ xp, const _Float16* __restrict__ wpk1h,
    const float* __restrict__ b1, const float* __restrict__ wscales,
    int* __restrict__ stats1)
{
    int t = threadIdx.x, l = t & 63, wid = t >> 6;
    int hi = l >> 4, col = l & 15;
    f16x8 bv = *(const f16x8*)(wpk1h + (hi*16 + col)*8);
    float sb = b1[col];
    float s0 = wscales[0];
    int tile0 = blockIdx.x*4 + wid;                // 0..6271
    int p0 = tile0*16 + (l & 15);
    int b0 = p0 / 784, r = p0 - b0*784;
    int y = r / 28, xx = r - y*28;
    int rowo = (hi < 3) ? hi : 2;
    bool valid = hi < 3;
    const uint32_t* base = xp + (size_t)b0*900 + (y + rowo)*30 + xx;
    float mn = INFINITY, mx = -INFINITY;
    #pragma unroll 1
    for (int it = 0; it < 32; it++){               // 32 pairs = 64 tiles
        const uint32_t* base2 = base + (size_t)128*900;
        f16x8 a0 = conv1_fragHL(base,  valid);
        f16x8 a1 = conv1_fragHL(base2, valid);
        f32x4 c0 = {0.f,0.f,0.f,0.f}, c1 = {0.f,0.f,0.f,0.f};
        c0 = __builtin_amdgcn_mfma_f32_16x16x32_f16(a0, bv, c0, 0, 0, 0);
        c1 = __builtin_amdgcn_mfma_f32_16x16x32_f16(a1, bv, c1, 0, 0, 0);
        #pragma unroll
        for (int rg = 0; rg < 4; rg++){
            mn = fminf(mn, fminf(c0[rg], c1[rg]));
            mx = fmaxf(mx, fmaxf(c0[rg], c1[rg]));
        }
        base += (size_t)256*900;
    }
    // affine after (monotone single op: exact)
    mn = fmaf(s0, mn, sb);
    mx = fmaf(s0, mx, sb);
    mn = fminf(mn, __shfl_xor(mn, 16)); mn = fminf(mn, __shfl_xor(mn, 32));
    mx = fmaxf(mx, __shfl_xor(mx, 16)); mx = fmaxf(mx, __shfl_xor(mx, 32));
    if (l < 16){
        int* basep = stats1 + (blockIdx.x & (NCOPIES-1))*32;
        atomicMin(&basep[l],      f2ord(mn));
        atomicMax(&basep[16 + l], f2ord(mx));
    }
}

// ---------- scales for block1 + chain LUT build ----------
__global__ __launch_bounds__(256) void k_scales_block(
    const int* __restrict__ stats,
    const float* __restrict__ g, const float* __restrict__ be,
    const float* __restrict__ m, const float* __restrict__ v,
    float* __restrict__ s_out, int8_t* __restrict__ t1buf)
{
    __shared__ float cmn[16], cmx[16], invs[16], dds[16], sss[3];
    int t = threadIdx.x;
    if (t < 32){
        bool ismax = t >= 16; int c = t & 15;
        int acc = ismax ? INT_MIN : INT_MAX;
        for (int i = 0; i < NCOPIES; i++){
            int u = stats[i*32 + t];
            acc = ismax ? max(acc, u) : min(acc, u);
        }
        if (ismax) cmx[c] = ord2f(acc); else cmn[c] = ord2f(acc);
    }
    __syncthreads();
    if (t == 0){
        float am = 0.f;
        for (int c = 0; c < 16; c++) am = fmaxf(am, fmaxf(fabsf(cmn[c]), fabsf(cmx[c])));
        float sA_ = fmaxf(am / QMAXF, 1e-8f);
        float rmax = 0.f;
        float q1x[16], q1n[16];
        for (int c = 0; c < 16; c++){
            q1x[c] = fmaxf(fq_apply(cmx[c], sA_), 0.f);
            q1n[c] = fmaxf(fq_apply(cmn[c], sA_), 0.f);
            rmax = fmaxf(rmax, q1x[c]);
        }
        float sB_ = fmaxf(rmax / QMAXF, 1e-8f);
        float am3 = 0.f;
        for (int c = 0; c < 16; c++){
            float inv = g[c] / sqrtf(v[c] + BN_EPS);
            float dd  = be[c] - m[c]*inv;
            invs[c] = inv; dds[c] = dd;
            float ha = fmaf(fq_apply(q1x[c], sB_), inv, dd);
            float hb = fmaf(fq_apply(q1n[c], sB_), inv, dd);
            am3 = fmaxf(am3, fmaxf(fabsf(ha), fabsf(hb)));
        }
        float sC_ = fmaxf(am3 / QMAXF, 1e-8f);
        sss[0] = sA_; sss[1] = sB_; sss[2] = sC_;
        s_out[0] = sA_; s_out[1] = sB_; s_out[2] = sC_;
    }
    __syncthreads();
    float s1 = sss[0], s2 = sss[1], s3 = sss[2];
    for (int e = t; e < 2048; e += 256){
        int c = e >> 7, idx = e & 127;
        float hh = (float)idx * s1;             // = q1*s1 (relu'd)
        float q2 = quant_k(hh, s2);
        float h2 = q2 * s2;
        float hb = fmaf(h2, invs[c], dds[c]);
        t1buf[e] = (int8_t)(int)quant_k(hb, s3);
    }
}

// ---------- K4: block1 MFMA -> pool -> 1 div + LUT -> h1q (paired tiles) ----------
__global__ __launch_bounds__(256) void k_block1_mfma(
    const uint32_t* __restrict__ xp, const _Float16* __restrict__ wpk1h,
    const float* __restrict__ b1, const float* __restrict__ wscales,
    const float* __restrict__ scales, const int8_t* __restrict__ t1buf,
    int8_t* __restrict__ h1q)
{
    __shared__ int8_t T1l[16*132];
    int t = threadIdx.x, l = t & 63, wid = t >> 6;
    for (int e = t; e < 2048; e += 256)
        T1l[(e >> 7)*132 + (e & 127)] = t1buf[e];
    __syncthreads();
    int hi = l >> 4, col = l & 15;
    f16x8 bv = *(const f16x8*)(wpk1h + (hi*16 + col)*8);
    float sb = b1[col];
    float s0 = wscales[0], s1 = scales[0];
    int tile0 = blockIdx.x*4 + wid;                // 0..25087
    int grow = tile0*16 + (l & 15);
    int cell = grow >> 2, sub = grow & 3;
    int b0 = cell / 196, rc = cell - b0*196;
    int py = rc / 14, px = rc - py*14;
    int y = 2*py + (sub >> 1), xx = 2*px + (sub & 1);
    int rowo = (hi < 3) ? hi : 2;
    bool valid = hi < 3;
    const uint32_t* base = xp + (size_t)b0*900 + (y + rowo)*30 + xx;
    const int8_t* T1c = T1l + col*132;
    int8_t* h1o = h1q + (size_t)tile0*64 + l;
    #pragma unroll 1
    for (int it = 0; it < 8; it++){                // 8 pairs = 16 tiles
        const uint32_t* base2 = base + (size_t)512*900;
        f16x8 a0 = conv1_fragHL(base,  valid);
        f16x8 a1 = conv1_fragHL(base2, valid);
        f32x4 c0 = {0.f,0.f,0.f,0.f}, c1 = {0.f,0.f,0.f,0.f};
        c0 = __builtin_amdgcn_mfma_f32_16x16x32_f16(a0, bv, c0, 0, 0, 0);
        c1 = __builtin_amdgcn_mfma_f32_16x16x32_f16(a1, bv, c1, 0, 0, 0);
        float pool0 = fmaxf(fmaxf(c0[0], c0[1]), fmaxf(c0[2], c0[3]));
        float pool1 = fmaxf(fmaxf(c1[0], c1[1]), fmaxf(c1[2], c1[3]));
        float q0 = quant_k(fmaf(s0, pool0, sb), s1);
        float q1 = quant_k(fmaf(s0, pool1, sb), s1);
        h1o[0]                  = T1c[(int)fmaxf(q0, 0.f)];
        h1o[(size_t)100352*16]  = T1c[(int)fmaxf(q1, 0.f)];
        base += (size_t)1024*900;
        h1o  += (size_t)2*100352*16;
    }
}

// ---------- K6: conv2 int8 MFMA + per-channel code min/max (hoisted) ----------
__global__ __launch_bounds__(256) void k_conv2s_mfma(
    const int8_t* __restrict__ h1q, const int8_t* __restrict__ wpk2,
    int* __restrict__ stats2)
{
    __shared__ int smn[32], smx[32];
    int t = threadIdx.x, l = t & 63, wid = t >> 6;
    if (t < 32){ smn[t] = INT_MAX; smx[t] = INT_MIN; }
    __syncthreads();
    int hi = l >> 4;
    v4i bv[6];
    #pragma unroll
    for (int nt = 0; nt < 2; nt++)
        #pragma unroll
        for (int s = 0; s < 3; s++)
            bv[nt*3+s] = *(const v4i*)(wpk2 + nt*3072 + (4*s + hi)*256 + (l&15)*16);
    int tile0 = blockIdx.x*4 + wid;                // 0..6271
    int grow = tile0*16 + (l & 15);
    int cell_g = grow >> 2;
    int b0 = cell_g / 49, cell = cell_g - b0*49;
    int sub = grow & 3;
    int qy = cell / 7, qx = cell - qy*7;
    int y = 2*qy + (sub >> 1), x = 2*qx + (sub & 1);
    const int8_t* ip = h1q + (size_t)b0*196*16;
    int toff[3];
    #pragma unroll
    for (int s = 0; s < 3; s++){
        int tap = 4*s + hi;
        toff[s] = -1;
        if (tap < 9){
            int ky = tap / 3, kx = tap - ky*3;
            int yy = y + ky - 1, xc = x + kx - 1;
            if (yy >= 0 && yy < 14 && xc >= 0 && xc < 14)
                toff[s] = (yy*14 + xc)*16;
        }
    }
    int mn0 = INT_MAX, mx0 = INT_MIN, mn1 = INT_MAX, mx1 = INT_MIN;
    #pragma unroll 1
    for (int it = 0; it < 16; it++){            // 1568 blocks * 16 = 25088 tiles
        v4i acc0 = (v4i){0,0,0,0}, acc1 = (v4i){0,0,0,0};
        #pragma unroll
        for (int s = 0; s < 3; s++){
            v4i av = (toff[s] >= 0) ? *(const v4i*)(ip + toff[s]) : (v4i){0,0,0,0};
            acc0 = __builtin_amdgcn_mfma_i32_16x16x64_i8(av, bv[s],     acc0, 0, 0, 0);
            acc1 = __builtin_amdgcn_mfma_i32_16x16x64_i8(av, bv[3 + s], acc1, 0, 0, 0);
        }
        #pragma unroll
        for (int r = 0; r < 4; r++){
            mn0 = min(mn0, acc0[r]); mx0 = max(mx0, acc0[r]);
            mn1 = min(mn1, acc1[r]); mx1 = max(mx1, acc1[r]);
        }
        ip += (size_t)512*196*16;
    }
    mn0 = min(mn0, __shfl_xor(mn0, 16)); mn0 = min(mn0, __shfl_xor(mn0, 32));
    mx0 = max(mx0, __shfl_xor(mx0, 16)); mx0 = max(mx0, __shfl_xor(mx0, 32));
    mn1 = min(mn1, __shfl_xor(mn1, 16)); mn1 = min(mn1, __shfl_xor(mn1, 32));
    mx1 = max(mx1, __shfl_xor(mx1, 16)); mx1 = max(mx1, __shfl_xor(mx1, 32));
    if (l < 16){
        atomicMin(&smn[l], mn0);      atomicMax(&smx[l], mx0);
        atomicMin(&smn[16 + l], mn1); atomicMax(&smx[16 + l], mx1);
    }
    __syncthreads();
    if (t < 32){
        int* basep = stats2 + (blockIdx.x & (NCOPIES-1))*64;
        atomicMin(&basep[t],      smn[t]);
        atomicMax(&basep[t + 32], smx[t]);
    }
}

// ---------- scales for block2 + chain LUT build ----------
__global__ __launch_bounds__(256) void k_scales2(
    const int* __restrict__ stats,
    const float* __restrict__ g, const float* __restrict__ be,
    const float* __restrict__ m, const float* __restrict__ v,
    const float* __restrict__ b2,
    const float* __restrict__ scales, const float* __restrict__ wscales,
    float* __restrict__ s_out, int8_t* __restrict__ t2buf)
{
    __shared__ float cmn[32], cmx[32], invs[32], dds[32], sss[3];
    int t = threadIdx.x;
    float S = scales[2] * wscales[1];
    if (t < 64){
        bool ismax = t >= 32; int c = t & 31;
        int acc = ismax ? INT_MIN : INT_MAX;
        for (int i = 0; i < NCOPIES; i++){
            int u = stats[i*64 + t];
            acc = ismax ? max(acc, u) : min(acc, u);
        }
        float val = fmaf(S, (float)acc, b2[c]);
        if (ismax) cmx[c] = val; else cmn[c] = val;
    }
    __syncthreads();
    if (t == 0){
        float am = 0.f;
        for (int c = 0; c < 32; c++) am = fmaxf(am, fmaxf(fabsf(cmn[c]), fabsf(cmx[c])));
        float sA_ = fmaxf(am / QMAXF, 1e-8f);
        float rmax = 0.f;
        float q1x[32], q1n[32];
        for (int c = 0; c < 32; c++){
            q1x[c] = fmaxf(fq_apply(cmx[c], sA_), 0.f);
            q1n[c] = fmaxf(fq_apply(cmn[c], sA_), 0.f);
            rmax = fmaxf(rmax, q1x[c]);
        }
        float sB_ = fmaxf(rmax / QMAXF, 1e-8f);
        float am3 = 0.f;
        for (int c = 0; c < 32; c++){
            float inv = g[c] / sqrtf(v[c] + BN_EPS);
            float dd  = be[c] - m[c]*inv;
            invs[c] = inv; dds[c] = dd;
            float ha = fmaf(fq_apply(q1x[c], sB_), inv, dd);
            float hb = fmaf(fq_apply(q1n[c], sB_), inv, dd);
            am3 = fmaxf(am3, fmaxf(fabsf(ha), fabsf(hb)));
        }
        float sC_ = fmaxf(am3 / QMAXF, 1e-8f);
        sss[0] = sA_; sss[1] = sB_; sss[2] = sC_;
        s_out[0] = sA_; s_out[1] = sB_; s_out[2] = sC_;
    }
    __syncthreads();
    float s4 = sss[0], s5 = sss[1], s6 = sss[2];
    for (int e = t; e < 4096; e += 256){
        int c = e >> 7, idx = e & 127;
        float hh = (float)idx * s4;
        float q5 = quant_k(hh, s5);
        float h2 = q5 * s5;
        float hb = fmaf(h2, invs[c], dds[c]);
        t2buf[e] = (int8_t)(int)quant_k(hb, s6);
    }
}

// ---------- K8: block2 MFMA -> pool -> 1 div + LUT -> h2q ----------
__global__ __launch_bounds__(256) void k_block2_mfma(
    const int8_t* __restrict__ h1q, const int8_t* __restrict__ wpk2,
    const float* __restrict__ b2, const float* __restrict__ scales,
    const float* __restrict__ wscales, const int8_t* __restrict__ t2buf,
    int8_t* __restrict__ h2q)
{
    __shared__ int8_t T2l[32*132];
    int t = threadIdx.x, l = t & 63, wid = t >> 6;
    for (int e = t; e < 4096; e += 256)
        T2l[(e >> 7)*132 + (e & 127)] = t2buf[e];
    __syncthreads();
    int hi = l >> 4, cl = l & 15;
    float S = scales[2] * wscales[1];
    float s4 = scales[3];
    float sb0 = b2[cl], sb1 = b2[16 + cl];
    const int8_t* T2a = T2l + cl*132;
    const int8_t* T2b = T2l + (16 + cl)*132;
    v4i bv[6];
    #pragma unroll
    for (int nt = 0; nt < 2; nt++)
        #pragma unroll
        for (int s = 0; s < 3; s++)
            bv[nt*3+s] = *(const v4i*)(wpk2 + nt*3072 + (4*s + hi)*256 + cl*16);
    int tile0 = blockIdx.x*4 + wid;                // 0..25087
    int grow = tile0*16 + (l & 15);
    int cell_g = grow >> 2;
    int b0 = cell_g / 49, cell = cell_g - b0*49;
    int sub = grow & 3;
    int qy = cell / 7, qx = cell - qy*7;
    int y = 2*qy + (sub >> 1), x = 2*qx + (sub & 1);
    const int8_t* ip = h1q + (size_t)b0*196*16;
    int toff[3];
    #pragma unroll
    for (int s = 0; s < 3; s++){
        int tap = 4*s + hi;
        toff[s] = -1;
        if (tap < 9){
            int ky = tap / 3, kx = tap - ky*3;
            int yy = y + ky - 1, xc = x + kx - 1;
            if (yy >= 0 && yy < 14 && xc >= 0 && xc < 14)
                toff[s] = (yy*14 + xc)*16;
        }
    }
    int8_t* h2o = h2q + (size_t)(tile0*4 + hi)*32 + cl;   // +16 for nt=1
    #pragma unroll 1
    for (int it = 0; it < 4; it++){
        v4i acc0 = (v4i){0,0,0,0}, acc1 = (v4i){0,0,0,0};
        #pragma unroll
        for (int s = 0; s < 3; s++){
            v4i av = (toff[s] >= 0) ? *(const v4i*)(ip + toff[s]) : (v4i){0,0,0,0};
            acc0 = __builtin_amdgcn_mfma_i32_16x16x64_i8(av, bv[s],     acc0, 0, 0, 0);
            acc1 = __builtin_amdgcn_mfma_i32_16x16x64_i8(av, bv[3 + s], acc1, 0, 0, 0);
        }
        int pool0 = max(max(acc0[0], acc0[1]), max(acc0[2], acc0[3]));
        int pool1 = max(max(acc1[0], acc1[1]), max(acc1[2], acc1[3]));
        float q0 = quant_k(fmaf(S, (float)pool0, sb0), s4);
        float q1 = quant_k(fmaf(S, (float)pool1, sb1), s4);
        h2o[0]  = T2a[(int)fmaxf(q0, 0.f)];
        h2o[16] = T2b[(int)fmaxf(q1, 0.f)];
        ip  += (size_t)2048*196*16;
        h2o += (size_t)100352*32;
    }
}

// ---------- K9: fc1 int8 MFMA, quarter-split: 2048 waves ----------
__global__ __launch_bounds__(256) void k_fc1(
    const int8_t* __restrict__ h2q, const int8_t* __restrict__ bpk1,
    const float* __restrict__ fb1, const float* __restrict__ scales,
    const float* __restrict__ wscales,
    float* __restrict__ fc1o, int* __restrict__ statsFc)
{
    __shared__ int smn, smx;
    int t = threadIdx.x, l = t & 63, wid = t >> 6;
    if (t == 0){ smn = INT_MAX; smx = INT_MIN; }
    __syncthreads();
    int wave_id = blockIdx.x*4 + wid;     // 2048 waves (512 blocks)
    int mtile = wave_id >> 2;             // 0..511
    int quarter = wave_id & 3;            // 2 o-groups each
    int hi = l >> 4, lo = l & 15;
    const int8_t* arow = h2q + (size_t)(mtile*16 + lo)*1568;
    v4i acc[2];
    #pragma unroll
    for (int g = 0; g < 2; g++) acc[g] = (v4i){0,0,0,0};
    #pragma unroll 1
    for (int kc = 0; kc < 25; kc++){
        int koff = kc*64 + hi*16;
        v4i av = (v4i){0,0,0,0};
        if (koff < 1568) av = *(const v4i*)(arow + koff);
        #pragma unroll
        for (int g = 0; g < 2; g++){
            v4i bvv = *(const v4i*)(bpk1 + (quarter*2 + g)*25600 + (kc*4 + hi)*256 + lo*16);
            acc[g] = __builtin_amdgcn_mfma_i32_16x16x64_i8(av, bvv, acc[g], 0, 0, 0);
        }
    }
    float Sfc = scales[5] * wscales[2];
    float lmn = INFINITY, lmx = -INFINITY;
    #pragma unroll
    for (int g = 0; g < 2; g++){
        int o = (quarter*2 + g)*16 + lo;
        float bias = fb1[o];
        #pragma unroll
        for (int r = 0; r < 4; r++){
            int m = mtile*16 + hi*4 + r;
            float val = fmaf(Sfc, (float)acc[g][r], bias);
            fc1o[(size_t)m*128 + o] = val;
            lmn = fminf(lmn, val); lmx = fmaxf(lmx, val);
        }
    }
    #pragma unroll
    for (int d = 1; d < 64; d <<= 1){
        lmn = fminf(lmn, __shfl_xor(lmn, d));
        lmx = fmaxf(lmx, __shfl_xor(lmx, d));
    }
    if (l == 0){
        atomicMin(&smn, f2ord(lmn));
        atomicMax(&smx, f2ord(lmx));
    }
    __syncthreads();
    if (t == 0){
        int* basep = statsFc + (blockIdx.x & (NCOPIES-1))*2;
        atomicMin(&basep[0], smn); atomicMax(&basep[1], smx);
    }
}

// ---------- K12: fc2 with LUT'd h3 quantization ----------
__global__ __launch_bounds__(256) void k_fc2(
    const float* __restrict__ fc1o, const float* __restrict__ qfw2, const float* __restrict__ fb2,
    const int* __restrict__ statsFc, float* __restrict__ out, int* __restrict__ statsOut)
{
    __shared__ float sw[1280], sb2[10], Tf[128];
    __shared__ float s7sh, s8sh;
    __shared__ int smn, smx;
    int t = threadIdx.x;
    for (int i = t; i < 1280; i += 256) sw[i] = qfw2[i];
    if (t < 10) sb2[t] = fb2[t];
    if (t == 0){
        smn = INT_MAX; smx = INT_MIN;
        int mni = INT_MAX, mxi = INT_MIN;
        for (int i = 0; i < NCOPIES; i++){ mni = min(mni, statsFc[i*2]); mxi = max(mxi, statsFc[i*2+1]); }
        float mn = ord2f(mni), mx = ord2f(mxi);
        float am = fmaxf(fabsf(mn), fabsf(mx));
        float s7 = fmaxf(am / QMAXF, 1e-8f);
        float rmx = fmaxf(fq_apply(mx, s7), 0.f);
        s7sh = s7; s8sh = fmaxf(rmx / QMAXF, 1e-8f);
    }
    __syncthreads();
    float s7 = s7sh, s8 = s8sh;
    if (t < 128) Tf[t] = s8 * quant_k((float)t * s7, s8);
    __syncthreads();
    int b = blockIdx.x*256 + t;   // 8192 exact (32 blocks)
    float acc[10];
    #pragma unroll
    for (int j = 0; j < 10; j++) acc[j] = sb2[j];
    const float* fp = fc1o + (size_t)b*128;
    for (int k = 0; k < 128; k += 4){
        float4 f = *(const float4*)(fp + k);
        float v0 = Tf[(int)fmaxf(quant_k(f.x, s7), 0.f)];
        float v1 = Tf[(int)fmaxf(quant_k(f.y, s7), 0.f)];
        float v2 = Tf[(int)fmaxf(quant_k(f.z, s7), 0.f)];
        float v3 = Tf[(int)fmaxf(quant_k(f.w, s7), 0.f)];
        #pragma unroll
        for (int j = 0; j < 10; j++){
            float a = acc[j];
            a = fmaf(v0, sw[j*128 + k],     a);
            a = fmaf(v1, sw[j*128 + k + 1], a);
            a = fmaf(v2, sw[j*128 + k + 2], a);
            a = fmaf(v3, sw[j*128 + k + 3], a);
            acc[j] = a;
        }
    }
    float lmn = INFINITY, lmx = -INFINITY;
    #pragma unroll
    for (int j = 0; j < 10; j++){
        out[(size_t)b*10 + j] = acc[j];
        lmn = fminf(lmn, acc[j]); lmx = fmaxf(lmx, acc[j]);
    }
    atomicMin(&smn, f2ord(lmn)); atomicMax(&smx, f2ord(lmx));
    __syncthreads();
    if (t == 0){
        int* basep = statsOut + (blockIdx.x & (NCOPIES-1))*2;
        atomicMin(&basep[0], smn); atomicMax(&basep[1], smx);
    }
}

// ---------- K14: final fake-quant of d_out ----------
__global__ void k_quant_out(float* __restrict__ out, const int* __restrict__ statsOut, int n){
    __shared__ float s9s;
    if (threadIdx.x == 0){
        int mni = INT_MAX, mxi = INT_MIN;
        for (int i = 0; i < NCOPIES; i++){ mni = min(mni, statsOut[i*2]); mxi = max(mxi, statsOut[i*2+1]); }
        float am = fmaxf(fabsf(ord2f(mni)), fabsf(ord2f(mxi)));
        s9s = fmaxf(am / QMAXF, 1e-8f);
    }
    __syncthreads();
    int i = blockIdx.x*256 + threadIdx.x;
    if (i < n) out[i] = fq_apply(out[i], s9s);
}

// =================== host ===================
extern "C" void kernel_launch(void* const* d_in, const int* in_sizes, int n_in,
                              void* d_out, int out_size, void* d_ws, size_t ws_size,
                              hipStream_t stream)
{
    const float* x   = (const float*)d_in[0];
    const float* w1  = (const float*)d_in[1];
    const float* b1  = (const float*)d_in[2];
    const float* g1  = (const float*)d_in[3];
    const float* be1 = (const float*)d_in[4];
    const float* m1  = (const float*)d_in[5];
    const float* v1  = (const float*)d_in[6];
    const float* w2  = (const float*)d_in[7];
    const float* b2  = (const float*)d_in[8];
    const float* g2  = (const float*)d_in[9];
    const float* be2 = (const float*)d_in[10];
    const float* m2  = (const float*)d_in[11];
    const float* v2  = (const float*)d_in[12];
    const float* fw1 = (const float*)d_in[13];
    const float* fb1 = (const float*)d_in[14];
    const float* fw2 = (const float*)d_in[15];
    const float* fb2 = (const float*)d_in[16];
    float* out = (float*)d_out;

    char* ws = (char*)d_ws;
    size_t off = 0;
    auto alloc = [&](size_t bytes)->char*{
        char* p = ws + off;
        off = (off + bytes + 255) & ~(size_t)255;
        return p;
    };
    _Float16* wpk1h = (_Float16*)alloc(512*2);
    int8_t* wpk2  = (int8_t*)alloc(6144);
    int8_t* bpk1  = (int8_t*)alloc(204800);
    float* qfw2   = (float*)alloc(1280*4);
    float* scales = (float*)alloc(16*4);
    float* wscales= (float*)alloc(4*4);
    float* wsbuf  = (float*)alloc(67*4);
    int8_t* t1buf = (int8_t*)alloc(2048);
    int8_t* t2buf = (int8_t*)alloc(4096);
    int* stats1   = (int*)alloc(64*32*4);
    int* stats2   = (int*)alloc(64*64*4);
    int* statsFc  = (int*)alloc(64*2*4);
    int* statsOut = (int*)alloc(64*2*4);
    uint32_t* xp  = (uint32_t*)alloc((size_t)8192*900*4);
    int8_t* h1q   = (int8_t*)alloc((size_t)8192*196*16);
    int8_t* h2q   = (int8_t*)alloc((size_t)8192*49*32);
    float* fc1o   = (float*)alloc((size_t)8192*128*4);
    (void)ws_size;

    k_init_ws<<<93, 256, 0, stream>>>(w1, w2, fw1, fw2, stats1, stats2, statsFc, statsOut, wsbuf);
    k_pack_prep<<<29586, 256, 0, stream>>>(x, w1, w2, fw1, fw2, wsbuf, wpk1h, wpk2, bpk1, qfw2, wscales, xp);
    k_conv1s_mfma<<<1568, 256, 0, stream>>>(xp, wpk1h, b1, wscales, stats1);
    k_scales_block<<<1, 256, 0, stream>>>(stats1, g1, be1, m1, v1, scales + 0, t1buf);
    k_block1_mfma<<<6272, 256, 0, stream>>>(xp, wpk1h, b1, wscales, scales, t1buf, h1q);
    k_conv2s_mfma<<<1568, 256, 0, stream>>>(h1q, wpk2, stats2);
    k_scales2<<<1, 256, 0, stream>>>(stats2, g2, be2, m2, v2, b2, scales, wscales, scales + 3, t2buf);
    k_block2_mfma<<<6272, 256, 0, stream>>>(h1q, wpk2, b2, scales, wscales, t2buf, h2q);
    k_fc1<<<512, 256, 0, stream>>>(h2q, bpk1, fb1, scales, wscales, fc1o, statsFc);
    k_fc2<<<32, 256, 0, stream>>>(fc1o, qfw2, fb2, statsFc, out, statsOut);
    k_quant_out<<<320, 256, 0, stream>>>(out, statsOut, out_size);
}

// Round 15
// 188.433 us; speedup vs baseline: 1.9586x; 1.0499x over previous
//
#include <hip/hip_runtime.h>
#include <math.h>
#include <limits.h>
#include <stdint.h>

#define QMAXF 127.0f
#define BN_EPS 1e-5f
#define NCOPIES 64

typedef int v4i __attribute__((ext_vector_type(4)));
typedef float f32x4 __attribute__((ext_vector_type(4)));
typedef _Float16 f16x8 __attribute__((ext_vector_type(8)));

// ---------- helpers ----------
__device__ __forceinline__ int f2ord(float f){
    int i = __float_as_int(f);
    return i ^ ((i >> 31) & 0x7fffffff);
}
__device__ __forceinline__ float ord2f(int i){
    return __int_as_float(i ^ ((i >> 31) & 0x7fffffff));
}
__device__ __forceinline__ float scale_of(float m){
    return fmaxf(m / QMAXF, 1e-8f);
}
// fake-quant forward: clip(round(x/s))*s  (round = half-to-even, matches jnp.round)
__device__ __forceinline__ float fq_apply(float x, float s){
    float q = rintf(x / s);
    q = fminf(fmaxf(q, -QMAXF), QMAXF);
    return q * s;
}
// return clipped integer level as float
__device__ __forceinline__ float quant_k(float x, float s){
    float q = rintf(x / s);
    return fminf(fmaxf(q, -QMAXF), QMAXF);
}
__device__ __forceinline__ _Float16 hpart(uint32_t w){
    return __builtin_bit_cast(_Float16, (unsigned short)(w >> 16));
}
__device__ __forceinline__ _Float16 lpart(uint32_t w){
    return __builtin_bit_cast(_Float16, (unsigned short)(w & 0xffffu));
}

// ---------- K0: init stat buffers + per-block |w| partial max ----------
__global__ __launch_bounds__(256) void k_init_ws(
    const float* __restrict__ w1, const float* __restrict__ w2,
    const float* __restrict__ fw1, const float* __restrict__ fw2,
    int* __restrict__ s1, int* __restrict__ s2, int* __restrict__ sf, int* __restrict__ so,
    float* __restrict__ wsbuf /*[67]*/)
{
    int blk = blockIdx.x, t = threadIdx.x;
    if (blk < 26){
        int gt = blk*256 + t;
        if (gt < 2048){ int j = gt & 31; s1[gt] = (j < 16) ? INT_MAX : INT_MIN; }
        else if (gt < 6144){ int u = gt - 2048; int j = u & 63; s2[u] = (j < 32) ? INT_MAX : INT_MIN; }
        else if (gt < 6272){ int u = gt - 6144; sf[u] = ((u & 1) == 0) ? INT_MAX : INT_MIN; }
        else if (gt < 6400){ int u = gt - 6272; so[u] = ((u & 1) == 0) ? INT_MAX : INT_MIN; }
        return;
    }
    __shared__ float red[256];
    int b2 = blk - 26;   // 0..66
    const float* src; int n, base;
    if (b2 < 64){ src = fw1; base = b2*3136; n = 3136; }
    else if (b2 == 64){ src = w1;  base = 0; n = 144; }
    else if (b2 == 65){ src = w2;  base = 0; n = 4608; }
    else { src = fw2; base = 0; n = 1280; }
    float m = 0.f;
    for (int i = t; i < n; i += 256) m = fmaxf(m, fabsf(src[base + i]));
    red[t] = m; __syncthreads();
    for (int off = 128; off; off >>= 1){
        if (t < off) red[t] = fmaxf(red[t], red[t+off]);
        __syncthreads();
    }
    if (t == 0) wsbuf[b2] = red[0];
}

// ---------- K1: pack/quantize weights + pad/split x ----------
__global__ __launch_bounds__(256) void k_pack_prep(
    const float* __restrict__ x,
    const float* __restrict__ w1, const float* __restrict__ w2,
    const float* __restrict__ fw1, const float* __restrict__ fw2,
    const float* __restrict__ wsbuf,
    _Float16* __restrict__ wpk1h, int8_t* __restrict__ wpk2,
    int8_t* __restrict__ bpk1, float* __restrict__ qfw2,
    float* __restrict__ wscales, uint32_t* __restrict__ xp)
{
    int blk = blockIdx.x, t = threadIdx.x;
    if (blk >= 786){
        int i = (blk - 786)*256 + t;        // 7,372,800 = 8192*900 exact
        int b = i / 900, r = i - b*900;
        int yy = r / 30, xx = r - yy*30;
        float val = 0.f;
        if (yy >= 1 && yy <= 28 && xx >= 1 && xx <= 28)
            val = x[(size_t)b*784 + (yy-1)*28 + (xx-1)];
        _Float16 h  = (_Float16)val;
        _Float16 lo = (_Float16)(val - (float)h);
        xp[i] = ((uint32_t)__builtin_bit_cast(unsigned short, h) << 16)
              |  (uint32_t)__builtin_bit_cast(unsigned short, lo);
        return;
    }
    if (blk < 784){
        float m = 0.f;
        #pragma unroll
        for (int i = 0; i < 64; i++) m = fmaxf(m, wsbuf[i]);
        float s = scale_of(m);
        int i = blk*256 + t;                      // 200704 exact
        int o = i / 1568, k = i - o*1568;
        int c = k / 49, r = k - c*49;
        int kp = r*32 + c;
        int kchunk = kp >> 6, rem = kp & 63, hi = rem >> 4, j = rem & 15;
        int code = (int)quant_k(fw1[i], s);
        bpk1[(o>>4)*25600 + (kchunk*4 + hi)*256 + (o&15)*16 + j] = (int8_t)code;
    } else if (blk == 784){
        float s0 = scale_of(wsbuf[64]), s3 = scale_of(wsbuf[66]);
        for (int i = t; i < 512; i += 256){
            int grp = i >> 3, j = i & 7;
            int hi = grp >> 4, col = grp & 15;
            _Float16 val = (_Float16)0.f;
            if (hi < 3){
                int jj = (j < 3) ? j : ((j < 6) ? (j - 3) : -1);
                if (jj >= 0) val = (_Float16)quant_k(w1[col*9 + hi*3 + jj], s0);  // exact int code
            }
            wpk1h[i] = val;
        }
        for (int i = t; i < 1280; i += 256) qfw2[i] = fq_apply(fw2[i], s3);
        for (int i = t; i < 4096; i += 256){
            int o = i >> 5, rem = (i & 31) + 32;  // kp 1568..1599 -> chunk24
            int hi = rem >> 4, j = rem & 15;
            bpk1[(o>>4)*25600 + (24*4 + hi)*256 + (o&15)*16 + j] = 0;
        }
        if (t == 0){
            float m = 0.f;
            for (int i = 0; i < 64; i++) m = fmaxf(m, wsbuf[i]);
            wscales[0] = scale_of(wsbuf[64]);
            wscales[1] = scale_of(wsbuf[65]);
            wscales[2] = scale_of(m);
            wscales[3] = scale_of(wsbuf[66]);
        }
    } else {
        float s1 = scale_of(wsbuf[65]);
        for (int i = t; i < 6144; i += 256) wpk2[i] = 0;
        __syncthreads();
        for (int i = t; i < 4608; i += 256){
            int co = i / 144, rr = i - co*144, ci = rr / 9, pix = rr - ci*9;
            wpk2[(co >> 4)*3072 + pix*256 + (co & 15)*16 + ci] = (int8_t)(int)quant_k(w2[i], s1);
        }
    }
}

// ---------- conv1 fragment from 3 preloaded dwords: hi at slots 0-2, lo at 3-5 ----------
__device__ __forceinline__ f16x8 conv1_fragW(uint32_t w0, uint32_t w1, uint32_t w2)
{
    _Float16 z = (_Float16)0.f;
    return (f16x8){hpart(w0), hpart(w1), hpart(w2),
                   lpart(w0), lpart(w1), lpart(w2), z, z};
}

// ---------- K2: conv1 MFMA + per-channel min/max (manual prefetch pipeline) ----------
__global__ __launch_bounds__(256) void k_conv1s_mfma(
    const uint32_t* __restrict__ xp, const _Float16* __restrict__ wpk1h,
    const float* __restrict__ b1, const float* __restrict__ wscales,
    int* __restrict__ stats1)
{
    int t = threadIdx.x, l = t & 63, wid = t >> 6;
    int hi = l >> 4, col = l & 15;
    f16x8 bv = *(const f16x8*)(wpk1h + (hi*16 + col)*8);
    float sb = b1[col];
    float s0 = wscales[0];
    int tile0 = blockIdx.x*4 + wid;                // 0..6271
    int p0 = tile0*16 + (l & 15);
    int b0 = p0 / 784, r = p0 - b0*784;
    int y = r / 28, xx = r - y*28;
    int rowo = (hi < 3) ? hi : 2;
    bool valid = hi < 3;
    const uint32_t* base  = xp + (size_t)b0*900 + (y + rowo)*30 + xx;
    const uint32_t* base2 = base + (size_t)128*900;
    uint32_t n00, n01, n02, n10, n11, n12;
    if (valid){ n00 = base[0];  n01 = base[1];  n02 = base[2];
                n10 = base2[0]; n11 = base2[1]; n12 = base2[2]; }
    else { n00 = n01 = n02 = n10 = n11 = n12 = 0u; }
    float mn = INFINITY, mx = -INFINITY;
    #pragma unroll 1
    for (int it = 0; it < 32; it++){               // 32 pairs = 64 tiles
        uint32_t w00 = n00, w01 = n01, w02 = n02;
        uint32_t w10 = n10, w11 = n11, w12 = n12;
        base  += (size_t)256*900;
        base2 += (size_t)256*900;
        if (it < 31 && valid){
            n00 = base[0];  n01 = base[1];  n02 = base[2];
            n10 = base2[0]; n11 = base2[1]; n12 = base2[2];
        }
        f16x8 a0 = conv1_fragW(w00, w01, w02);
        f16x8 a1 = conv1_fragW(w10, w11, w12);
        f32x4 c0 = {0.f,0.f,0.f,0.f}, c1 = {0.f,0.f,0.f,0.f};
        c0 = __builtin_amdgcn_mfma_f32_16x16x32_f16(a0, bv, c0, 0, 0, 0);
        c1 = __builtin_amdgcn_mfma_f32_16x16x32_f16(a1, bv, c1, 0, 0, 0);
        #pragma unroll
        for (int rg = 0; rg < 4; rg++){
            mn = fminf(mn, fminf(c0[rg], c1[rg]));
            mx = fmaxf(mx, fmaxf(c0[rg], c1[rg]));
        }
    }
    mn = fmaf(s0, mn, sb);
    mx = fmaf(s0, mx, sb);
    mn = fminf(mn, __shfl_xor(mn, 16)); mn = fminf(mn, __shfl_xor(mn, 32));
    mx = fmaxf(mx, __shfl_xor(mx, 16)); mx = fmaxf(mx, __shfl_xor(mx, 32));
    if (l < 16){
        int* basep = stats1 + (blockIdx.x & (NCOPIES-1))*32;
        atomicMin(&basep[l],      f2ord(mn));
        atomicMax(&basep[16 + l], f2ord(mx));
    }
}

// ---------- scales for block1 + chain LUT build ----------
__global__ __launch_bounds__(256) void k_scales_block(
    const int* __restrict__ stats,
    const float* __restrict__ g, const float* __restrict__ be,
    const float* __restrict__ m, const float* __restrict__ v,
    float* __restrict__ s_out, int8_t* __restrict__ t1buf)
{
    __shared__ float cmn[16], cmx[16], invs[16], dds[16], sss[3];
    int t = threadIdx.x;
    if (t < 32){
        bool ismax = t >= 16; int c = t & 15;
        int acc = ismax ? INT_MIN : INT_MAX;
        for (int i = 0; i < NCOPIES; i++){
            int u = stats[i*32 + t];
            acc = ismax ? max(acc, u) : min(acc, u);
        }
        if (ismax) cmx[c] = ord2f(acc); else cmn[c] = ord2f(acc);
    }
    __syncthreads();
    if (t == 0){
        float am = 0.f;
        for (int c = 0; c < 16; c++) am = fmaxf(am, fmaxf(fabsf(cmn[c]), fabsf(cmx[c])));
        float sA_ = fmaxf(am / QMAXF, 1e-8f);
        float rmax = 0.f;
        float q1x[16], q1n[16];
        for (int c = 0; c < 16; c++){
            q1x[c] = fmaxf(fq_apply(cmx[c], sA_), 0.f);
            q1n[c] = fmaxf(fq_apply(cmn[c], sA_), 0.f);
            rmax = fmaxf(rmax, q1x[c]);
        }
        float sB_ = fmaxf(rmax / QMAXF, 1e-8f);
        float am3 = 0.f;
        for (int c = 0; c < 16; c++){
            float inv = g[c] / sqrtf(v[c] + BN_EPS);
            float dd  = be[c] - m[c]*inv;
            invs[c] = inv; dds[c] = dd;
            float ha = fmaf(fq_apply(q1x[c], sB_), inv, dd);
            float hb = fmaf(fq_apply(q1n[c], sB_), inv, dd);
            am3 = fmaxf(am3, fmaxf(fabsf(ha), fabsf(hb)));
        }
        float sC_ = fmaxf(am3 / QMAXF, 1e-8f);
        sss[0] = sA_; sss[1] = sB_; sss[2] = sC_;
        s_out[0] = sA_; s_out[1] = sB_; s_out[2] = sC_;
    }
    __syncthreads();
    float s1 = sss[0], s2 = sss[1], s3 = sss[2];
    for (int e = t; e < 2048; e += 256){
        int c = e >> 7, idx = e & 127;
        float hh = (float)idx * s1;             // = q1*s1 (relu'd)
        float q2 = quant_k(hh, s2);
        float h2 = q2 * s2;
        float hb = fmaf(h2, invs[c], dds[c]);
        t1buf[e] = (int8_t)(int)quant_k(hb, s3);
    }
}

// ---------- K4: block1 MFMA -> pool -> 1 div + LUT -> h1q (manual prefetch) ----------
__global__ __launch_bounds__(256) void k_block1_mfma(
    const uint32_t* __restrict__ xp, const _Float16* __restrict__ wpk1h,
    const float* __restrict__ b1, const float* __restrict__ wscales,
    const float* __restrict__ scales, const int8_t* __restrict__ t1buf,
    int8_t* __restrict__ h1q)
{
    __shared__ int8_t T1l[16*132];
    int t = threadIdx.x, l = t & 63, wid = t >> 6;
    for (int e = t; e < 2048; e += 256)
        T1l[(e >> 7)*132 + (e & 127)] = t1buf[e];
    __syncthreads();
    int hi = l >> 4, col = l & 15;
    f16x8 bv = *(const f16x8*)(wpk1h + (hi*16 + col)*8);
    float sb = b1[col];
    float s0 = wscales[0], s1 = scales[0];
    int tile0 = blockIdx.x*4 + wid;                // 0..25087
    int grow = tile0*16 + (l & 15);
    int cell = grow >> 2, sub = grow & 3;
    int b0 = cell / 196, rc = cell - b0*196;
    int py = rc / 14, px = rc - py*14;
    int y = 2*py + (sub >> 1), xx = 2*px + (sub & 1);
    int rowo = (hi < 3) ? hi : 2;
    bool valid = hi < 3;
    const uint32_t* base  = xp + (size_t)b0*900 + (y + rowo)*30 + xx;
    const uint32_t* base2 = base + (size_t)512*900;
    const int8_t* T1c = T1l + col*132;
    int8_t* h1o = h1q + (size_t)tile0*64 + l;
    uint32_t n00, n01, n02, n10, n11, n12;
    if (valid){ n00 = base[0];  n01 = base[1];  n02 = base[2];
                n10 = base2[0]; n11 = base2[1]; n12 = base2[2]; }
    else { n00 = n01 = n02 = n10 = n11 = n12 = 0u; }
    #pragma unroll 1
    for (int it = 0; it < 8; it++){                // 8 pairs = 16 tiles
        uint32_t w00 = n00, w01 = n01, w02 = n02;
        uint32_t w10 = n10, w11 = n11, w12 = n12;
        base  += (size_t)1024*900;
        base2 += (size_t)1024*900;
        if (it < 7 && valid){
            n00 = base[0];  n01 = base[1];  n02 = base[2];
            n10 = base2[0]; n11 = base2[1]; n12 = base2[2];
        }
        f16x8 a0 = conv1_fragW(w00, w01, w02);
        f16x8 a1 = conv1_fragW(w10, w11, w12);
        f32x4 c0 = {0.f,0.f,0.f,0.f}, c1 = {0.f,0.f,0.f,0.f};
        c0 = __builtin_amdgcn_mfma_f32_16x16x32_f16(a0, bv, c0, 0, 0, 0);
        c1 = __builtin_amdgcn_mfma_f32_16x16x32_f16(a1, bv, c1, 0, 0, 0);
        float pool0 = fmaxf(fmaxf(c0[0], c0[1]), fmaxf(c0[2], c0[3]));
        float pool1 = fmaxf(fmaxf(c1[0], c1[1]), fmaxf(c1[2], c1[3]));
        float q0 = quant_k(fmaf(s0, pool0, sb), s1);
        float q1 = quant_k(fmaf(s0, pool1, sb), s1);
        h1o[0]                  = T1c[(int)fmaxf(q0, 0.f)];
        h1o[(size_t)100352*16]  = T1c[(int)fmaxf(q1, 0.f)];
        h1o += (size_t)2*100352*16;
    }
}

// ---------- K6: conv2 int8 MFMA + per-channel code min/max (manual prefetch) ----------
__global__ __launch_bounds__(256) void k_conv2s_mfma(
    const int8_t* __restrict__ h1q, const int8_t* __restrict__ wpk2,
    int* __restrict__ stats2)
{
    __shared__ int smn[32], smx[32];
    int t = threadIdx.x, l = t & 63, wid = t >> 6;
    if (t < 32){ smn[t] = INT_MAX; smx[t] = INT_MIN; }
    __syncthreads();
    int hi = l >> 4;
    v4i bv[6];
    #pragma unroll
    for (int nt = 0; nt < 2; nt++)
        #pragma unroll
        for (int s = 0; s < 3; s++)
            bv[nt*3+s] = *(const v4i*)(wpk2 + nt*3072 + (4*s + hi)*256 + (l&15)*16);
    int tile0 = blockIdx.x*4 + wid;                // 0..6271
    int grow = tile0*16 + (l & 15);
    int cell_g = grow >> 2;
    int b0 = cell_g / 49, cell = cell_g - b0*49;
    int sub = grow & 3;
    int qy = cell / 7, qx = cell - qy*7;
    int y = 2*qy + (sub >> 1), x = 2*qx + (sub & 1);
    const int8_t* ip = h1q + (size_t)b0*196*16;
    int toff[3];
    #pragma unroll
    for (int s = 0; s < 3; s++){
        int tap = 4*s + hi;
        toff[s] = -1;
        if (tap < 9){
            int ky = tap / 3, kx = tap - ky*3;
            int yy = y + ky - 1, xc = x + kx - 1;
            if (yy >= 0 && yy < 14 && xc >= 0 && xc < 14)
                toff[s] = (yy*14 + xc)*16;
        }
    }
    v4i nav0 = (toff[0] >= 0) ? *(const v4i*)(ip + toff[0]) : (v4i){0,0,0,0};
    v4i nav1 = (toff[1] >= 0) ? *(const v4i*)(ip + toff[1]) : (v4i){0,0,0,0};
    v4i nav2 = (toff[2] >= 0) ? *(const v4i*)(ip + toff[2]) : (v4i){0,0,0,0};
    int mn0 = INT_MAX, mx0 = INT_MIN, mn1 = INT_MAX, mx1 = INT_MIN;
    #pragma unroll 1
    for (int it = 0; it < 16; it++){            // 1568 blocks * 16 = 25088 tiles
        v4i av0 = nav0, av1 = nav1, av2 = nav2;
        ip += (size_t)512*196*16;
        if (it < 15){
            nav0 = (toff[0] >= 0) ? *(const v4i*)(ip + toff[0]) : (v4i){0,0,0,0};
            nav1 = (toff[1] >= 0) ? *(const v4i*)(ip + toff[1]) : (v4i){0,0,0,0};
            nav2 = (toff[2] >= 0) ? *(const v4i*)(ip + toff[2]) : (v4i){0,0,0,0};
        }
        v4i acc0 = (v4i){0,0,0,0}, acc1 = (v4i){0,0,0,0};
        acc0 = __builtin_amdgcn_mfma_i32_16x16x64_i8(av0, bv[0], acc0, 0, 0, 0);
        acc1 = __builtin_amdgcn_mfma_i32_16x16x64_i8(av0, bv[3], acc1, 0, 0, 0);
        acc0 = __builtin_amdgcn_mfma_i32_16x16x64_i8(av1, bv[1], acc0, 0, 0, 0);
        acc1 = __builtin_amdgcn_mfma_i32_16x16x64_i8(av1, bv[4], acc1, 0, 0, 0);
        acc0 = __builtin_amdgcn_mfma_i32_16x16x64_i8(av2, bv[2], acc0, 0, 0, 0);
        acc1 = __builtin_amdgcn_mfma_i32_16x16x64_i8(av2, bv[5], acc1, 0, 0, 0);
        #pragma unroll
        for (int r = 0; r < 4; r++){
            mn0 = min(mn0, acc0[r]); mx0 = max(mx0, acc0[r]);
            mn1 = min(mn1, acc1[r]); mx1 = max(mx1, acc1[r]);
        }
    }
    mn0 = min(mn0, __shfl_xor(mn0, 16)); mn0 = min(mn0, __shfl_xor(mn0, 32));
    mx0 = max(mx0, __shfl_xor(mx0, 16)); mx0 = max(mx0, __shfl_xor(mx0, 32));
    mn1 = min(mn1, __shfl_xor(mn1, 16)); mn1 = min(mn1, __shfl_xor(mn1, 32));
    mx1 = max(mx1, __shfl_xor(mx1, 16)); mx1 = max(mx1, __shfl_xor(mx1, 32));
    if (l < 16){
        atomicMin(&smn[l], mn0);      atomicMax(&smx[l], mx0);
        atomicMin(&smn[16 + l], mn1); atomicMax(&smx[16 + l], mx1);
    }
    __syncthreads();
    if (t < 32){
        int* basep = stats2 + (blockIdx.x & (NCOPIES-1))*64;
        atomicMin(&basep[t],      smn[t]);
        atomicMax(&basep[t + 32], smx[t]);
    }
}

// ---------- scales for block2 + chain LUT build ----------
__global__ __launch_bounds__(256) void k_scales2(
    const int* __restrict__ stats,
    const float* __restrict__ g, const float* __restrict__ be,
    const float* __restrict__ m, const float* __restrict__ v,
    const float* __restrict__ b2,
    const float* __restrict__ scales, const float* __restrict__ wscales,
    float* __restrict__ s_out, int8_t* __restrict__ t2buf)
{
    __shared__ float cmn[32], cmx[32], invs[32], dds[32], sss[3];
    int t = threadIdx.x;
    float S = scales[2] * wscales[1];
    if (t < 64){
        bool ismax = t >= 32; int c = t & 31;
        int acc = ismax ? INT_MIN : INT_MAX;
        for (int i = 0; i < NCOPIES; i++){
            int u = stats[i*64 + t];
            acc = ismax ? max(acc, u) : min(acc, u);
        }
        float val = fmaf(S, (float)acc, b2[c]);
        if (ismax) cmx[c] = val; else cmn[c] = val;
    }
    __syncthreads();
    if (t == 0){
        float am = 0.f;
        for (int c = 0; c < 32; c++) am = fmaxf(am, fmaxf(fabsf(cmn[c]), fabsf(cmx[c])));
        float sA_ = fmaxf(am / QMAXF, 1e-8f);
        float rmax = 0.f;
        float q1x[32], q1n[32];
        for (int c = 0; c < 32; c++){
            q1x[c] = fmaxf(fq_apply(cmx[c], sA_), 0.f);
            q1n[c] = fmaxf(fq_apply(cmn[c], sA_), 0.f);
            rmax = fmaxf(rmax, q1x[c]);
        }
        float sB_ = fmaxf(rmax / QMAXF, 1e-8f);
        float am3 = 0.f;
        for (int c = 0; c < 32; c++){
            float inv = g[c] / sqrtf(v[c] + BN_EPS);
            float dd  = be[c] - m[c]*inv;
            invs[c] = inv; dds[c] = dd;
            float ha = fmaf(fq_apply(q1x[c], sB_), inv, dd);
            float hb = fmaf(fq_apply(q1n[c], sB_), inv, dd);
            am3 = fmaxf(am3, fmaxf(fabsf(ha), fabsf(hb)));
        }
        float sC_ = fmaxf(am3 / QMAXF, 1e-8f);
        sss[0] = sA_; sss[1] = sB_; sss[2] = sC_;
        s_out[0] = sA_; s_out[1] = sB_; s_out[2] = sC_;
    }
    __syncthreads();
    float s4 = sss[0], s5 = sss[1], s6 = sss[2];
    for (int e = t; e < 4096; e += 256){
        int c = e >> 7, idx = e & 127;
        float hh = (float)idx * s4;
        float q5 = quant_k(hh, s5);
        float h2 = q5 * s5;
        float hb = fmaf(h2, invs[c], dds[c]);
        t2buf[e] = (int8_t)(int)quant_k(hb, s6);
    }
}

// ---------- K8: block2 MFMA -> pool -> 1 div + LUT -> h2q (manual prefetch) ----------
__global__ __launch_bounds__(256) void k_block2_mfma(
    const int8_t* __restrict__ h1q, const int8_t* __restrict__ wpk2,
    const float* __restrict__ b2, const float* __restrict__ scales,
    const float* __restrict__ wscales, const int8_t* __restrict__ t2buf,
    int8_t* __restrict__ h2q)
{
    __shared__ int8_t T2l[32*132];
    int t = threadIdx.x, l = t & 63, wid = t >> 6;
    for (int e = t; e < 4096; e += 256)
        T2l[(e >> 7)*132 + (e & 127)] = t2buf[e];
    __syncthreads();
    int hi = l >> 4, cl = l & 15;
    float S = scales[2] * wscales[1];
    float s4 = scales[3];
    float sb0 = b2[cl], sb1 = b2[16 + cl];
    const int8_t* T2a = T2l + cl*132;
    const int8_t* T2b = T2l + (16 + cl)*132;
    v4i bv[6];
    #pragma unroll
    for (int nt = 0; nt < 2; nt++)
        #pragma unroll
        for (int s = 0; s < 3; s++)
            bv[nt*3+s] = *(const v4i*)(wpk2 + nt*3072 + (4*s + hi)*256 + cl*16);
    int tile0 = blockIdx.x*4 + wid;                // 0..25087
    int grow = tile0*16 + (l & 15);
    int cell_g = grow >> 2;
    int b0 = cell_g / 49, cell = cell_g - b0*49;
    int sub = grow & 3;
    int qy = cell / 7, qx = cell - qy*7;
    int y = 2*qy + (sub >> 1), x = 2*qx + (sub & 1);
    const int8_t* ip = h1q + (size_t)b0*196*16;
    int toff[3];
    #pragma unroll
    for (int s = 0; s < 3; s++){
        int tap = 4*s + hi;
        toff[s] = -1;
        if (tap < 9){
            int ky = tap / 3, kx = tap - ky*3;
            int yy = y + ky - 1, xc = x + kx - 1;
            if (yy >= 0 && yy < 14 && xc >= 0 && xc < 14)
                toff[s] = (yy*14 + xc)*16;
        }
    }
    v4i nav0 = (toff[0] >= 0) ? *(const v4i*)(ip + toff[0]) : (v4i){0,0,0,0};
    v4i nav1 = (toff[1] >= 0) ? *(const v4i*)(ip + toff[1]) : (v4i){0,0,0,0};
    v4i nav2 = (toff[2] >= 0) ? *(const v4i*)(ip + toff[2]) : (v4i){0,0,0,0};
    int8_t* h2o = h2q + (size_t)(tile0*4 + hi)*32 + cl;   // +16 for nt=1
    #pragma unroll 1
    for (int it = 0; it < 4; it++){
        v4i av0 = nav0, av1 = nav1, av2 = nav2;
        ip += (size_t)2048*196*16;
        if (it < 3){
            nav0 = (toff[0] >= 0) ? *(const v4i*)(ip + toff[0]) : (v4i){0,0,0,0};
            nav1 = (toff[1] >= 0) ? *(const v4i*)(ip + toff[1]) : (v4i){0,0,0,0};
            nav2 = (toff[2] >= 0) ? *(const v4i*)(ip + toff[2]) : (v4i){0,0,0,0};
        }
        v4i acc0 = (v4i){0,0,0,0}, acc1 = (v4i){0,0,0,0};
        acc0 = __builtin_amdgcn_mfma_i32_16x16x64_i8(av0, bv[0], acc0, 0, 0, 0);
        acc1 = __builtin_amdgcn_mfma_i32_16x16x64_i8(av0, bv[3], acc1, 0, 0, 0);
        acc0 = __builtin_amdgcn_mfma_i32_16x16x64_i8(av1, bv[1], acc0, 0, 0, 0);
        acc1 = __builtin_amdgcn_mfma_i32_16x16x64_i8(av1, bv[4], acc1, 0, 0, 0);
        acc0 = __builtin_amdgcn_mfma_i32_16x16x64_i8(av2, bv[2], acc0, 0, 0, 0);
        acc1 = __builtin_amdgcn_mfma_i32_16x16x64_i8(av2, bv[5], acc1, 0, 0, 0);
        int pool0 = max(max(acc0[0], acc0[1]), max(acc0[2], acc0[3]));
        int pool1 = max(max(acc1[0], acc1[1]), max(acc1[2], acc1[3]));
        float q0 = quant_k(fmaf(S, (float)pool0, sb0), s4);
        float q1 = quant_k(fmaf(S, (float)pool1, sb1), s4);
        h2o[0]  = T2a[(int)fmaxf(q0, 0.f)];
        h2o[16] = T2b[(int)fmaxf(q1, 0.f)];
        h2o += (size_t)100352*32;
    }
}

// ---------- K9: fc1 int8 MFMA, quarter-split: 2048 waves ----------
__global__ __launch_bounds__(256) void k_fc1(
    const int8_t* __restrict__ h2q, const int8_t* __restrict__ bpk1,
    const float* __restrict__ fb1, const float* __restrict__ scales,
    const float* __restrict__ wscales,
    float* __restrict__ fc1o, int* __restrict__ statsFc)
{
    __shared__ int smn, smx;
    int t = threadIdx.x, l = t & 63, wid = t >> 6;
    if (t == 0){ smn = INT_MAX; smx = INT_MIN; }
    __syncthreads();
    int wave_id = blockIdx.x*4 + wid;     // 2048 waves (512 blocks)
    int mtile = wave_id >> 2;             // 0..511
    int quarter = wave_id & 3;            // 2 o-groups each
    int hi = l >> 4, lo = l & 15;
    const int8_t* arow = h2q + (size_t)(mtile*16 + lo)*1568;
    v4i acc[2];
    #pragma unroll
    for (int g = 0; g < 2; g++) acc[g] = (v4i){0,0,0,0};
    #pragma unroll 1
    for (int kc = 0; kc < 25; kc++){
        int koff = kc*64 + hi*16;
        v4i av = (v4i){0,0,0,0};
        if (koff < 1568) av = *(const v4i*)(arow + koff);
        #pragma unroll
        for (int g = 0; g < 2; g++){
            v4i bvv = *(const v4i*)(bpk1 + (quarter*2 + g)*25600 + (kc*4 + hi)*256 + lo*16);
            acc[g] = __builtin_amdgcn_mfma_i32_16x16x64_i8(av, bvv, acc[g], 0, 0, 0);
        }
    }
    float Sfc = scales[5] * wscales[2];
    float lmn = INFINITY, lmx = -INFINITY;
    #pragma unroll
    for (int g = 0; g < 2; g++){
        int o = (quarter*2 + g)*16 + lo;
        float bias = fb1[o];
        #pragma unroll
        for (int r = 0; r < 4; r++){
            int m = mtile*16 + hi*4 + r;
            float val = fmaf(Sfc, (float)acc[g][r], bias);
            fc1o[(size_t)m*128 + o] = val;
            lmn = fminf(lmn, val); lmx = fmaxf(lmx, val);
        }
    }
    #pragma unroll
    for (int d = 1; d < 64; d <<= 1){
        lmn = fminf(lmn, __shfl_xor(lmn, d));
        lmx = fmaxf(lmx, __shfl_xor(lmx, d));
    }
    if (l == 0){
        atomicMin(&smn, f2ord(lmn));
        atomicMax(&smx, f2ord(lmx));
    }
    __syncthreads();
    if (t == 0){
        int* basep = statsFc + (blockIdx.x & (NCOPIES-1))*2;
        atomicMin(&basep[0], smn); atomicMax(&basep[1], smx);
    }
}

// ---------- K12: fc2 with LUT'd h3 quantization ----------
__global__ __launch_bounds__(256) void k_fc2(
    const float* __restrict__ fc1o, const float* __restrict__ qfw2, const float* __restrict__ fb2,
    const int* __restrict__ statsFc, float* __restrict__ out, int* __restrict__ statsOut)
{
    __shared__ float sw[1280], sb2[10], Tf[128];
    __shared__ float s7sh, s8sh;
    __shared__ int smn, smx;
    int t = threadIdx.x;
    for (int i = t; i < 1280; i += 256) sw[i] = qfw2[i];
    if (t < 10) sb2[t] = fb2[t];
    if (t == 0){
        smn = INT_MAX; smx = INT_MIN;
        int mni = INT_MAX, mxi = INT_MIN;
        for (int i = 0; i < NCOPIES; i++){ mni = min(mni, statsFc[i*2]); mxi = max(mxi, statsFc[i*2+1]); }
        float mn = ord2f(mni), mx = ord2f(mxi);
        float am = fmaxf(fabsf(mn), fabsf(mx));
        float s7 = fmaxf(am / QMAXF, 1e-8f);
        float rmx = fmaxf(fq_apply(mx, s7), 0.f);
        s7sh = s7; s8sh = fmaxf(rmx / QMAXF, 1e-8f);
    }
    __syncthreads();
    float s7 = s7sh, s8 = s8sh;
    if (t < 128) Tf[t] = s8 * quant_k((float)t * s7, s8);
    __syncthreads();
    int b = blockIdx.x*256 + t;   // 8192 exact (32 blocks)
    float acc[10];
    #pragma unroll
    for (int j = 0; j < 10; j++) acc[j] = sb2[j];
    const float* fp = fc1o + (size_t)b*128;
    for (int k = 0; k < 128; k += 4){
        float4 f = *(const float4*)(fp + k);
        float v0 = Tf[(int)fmaxf(quant_k(f.x, s7), 0.f)];
        float v1 = Tf[(int)fmaxf(quant_k(f.y, s7), 0.f)];
        float v2 = Tf[(int)fmaxf(quant_k(f.z, s7), 0.f)];
        float v3 = Tf[(int)fmaxf(quant_k(f.w, s7), 0.f)];
        #pragma unroll
        for (int j = 0; j < 10; j++){
            float a = acc[j];
            a = fmaf(v0, sw[j*128 + k],     a);
            a = fmaf(v1, sw[j*128 + k + 1], a);
            a = fmaf(v2, sw[j*128 + k + 2], a);
            a = fmaf(v3, sw[j*128 + k + 3], a);
            acc[j] = a;
        }
    }
    float lmn = INFINITY, lmx = -INFINITY;
    #pragma unroll
    for (int j = 0; j < 10; j++){
        out[(size_t)b*10 + j] = acc[j];
        lmn = fminf(lmn, acc[j]); lmx = fmaxf(lmx, acc[j]);
    }
    atomicMin(&smn, f2ord(lmn)); atomicMax(&smx, f2ord(lmx));
    __syncthreads();
    if (t == 0){
        int* basep = statsOut + (blockIdx.x & (NCOPIES-1))*2;
        atomicMin(&basep[0], smn); atomicMax(&basep[1], smx);
    }
}

// ---------- K14: final fake-quant of d_out ----------
__global__ void k_quant_out(float* __restrict__ out, const int* __restrict__ statsOut, int n){
    __shared__ float s9s;
    if (threadIdx.x == 0){
        int mni = INT_MAX, mxi = INT_MIN;
        for (int i = 0; i < NCOPIES; i++){ mni = min(mni, statsOut[i*2]); mxi = max(mxi, statsOut[i*2+1]); }
        float am = fmaxf(fabsf(ord2f(mni)), fabsf(ord2f(mxi)));
        s9s = fmaxf(am / QMAXF, 1e-8f);
    }
    __syncthreads();
    int i = blockIdx.x*256 + threadIdx.x;
    if (i < n) out[i] = fq_apply(out[i], s9s);
}

// =================== host ===================
extern "C" void kernel_launch(void* const* d_in, const int* in_sizes, int n_in,
                              void* d_out, int out_size, void* d_ws, size_t ws_size,
                              hipStream_t stream)
{
    const float* x   = (const float*)d_in[0];
    const float* w1  = (const float*)d_in[1];
    const float* b1  = (const float*)d_in[2];
    const float* g1  = (const float*)d_in[3];
    const float* be1 = (const float*)d_in[4];
    const float* m1  = (const float*)d_in[5];
    const float* v1  = (const float*)d_in[6];
    const float* w2  = (const float*)d_in[7];
    const float* b2  = (const float*)d_in[8];
    const float* g2  = (const float*)d_in[9];
    const float* be2 = (const float*)d_in[10];
    const float* m2  = (const float*)d_in[11];
    const float* v2  = (const float*)d_in[12];
    const float* fw1 = (const float*)d_in[13];
    const float* fb1 = (const float*)d_in[14];
    const float* fw2 = (const float*)d_in[15];
    const float* fb2 = (const float*)d_in[16];
    float* out = (float*)d_out;

    char* ws = (char*)d_ws;
    size_t off = 0;
    auto alloc = [&](size_t bytes)->char*{
        char* p = ws + off;
        off = (off + bytes + 255) & ~(size_t)255;
        return p;
    };
    _Float16* wpk1h = (_Float16*)alloc(512*2);
    int8_t* wpk2  = (int8_t*)alloc(6144);
    int8_t* bpk1  = (int8_t*)alloc(204800);
    float* qfw2   = (float*)alloc(1280*4);
    float* scales = (float*)alloc(16*4);
    float* wscales= (float*)alloc(4*4);
    float* wsbuf  = (float*)alloc(67*4);
    int8_t* t1buf = (int8_t*)alloc(2048);
    int8_t* t2buf = (int8_t*)alloc(4096);
    int* stats1   = (int*)alloc(64*32*4);
    int* stats2   = (int*)alloc(64*64*4);
    int* statsFc  = (int*)alloc(64*2*4);
    int* statsOut = (int*)alloc(64*2*4);
    uint32_t* xp  = (uint32_t*)alloc((size_t)8192*900*4);
    int8_t* h1q   = (int8_t*)alloc((size_t)8192*196*16);
    int8_t* h2q   = (int8_t*)alloc((size_t)8192*49*32);
    float* fc1o   = (float*)alloc((size_t)8192*128*4);
    (void)ws_size;

    k_init_ws<<<93, 256, 0, stream>>>(w1, w2, fw1, fw2, stats1, stats2, statsFc, statsOut, wsbuf);
    k_pack_prep<<<29586, 256, 0, stream>>>(x, w1, w2, fw1, fw2, wsbuf, wpk1h, wpk2, bpk1, qfw2, wscales, xp);
    k_conv1s_mfma<<<1568, 256, 0, stream>>>(xp, wpk1h, b1, wscales, stats1);
    k_scales_block<<<1, 256, 0, stream>>>(stats1, g1, be1, m1, v1, scales + 0, t1buf);
    k_block1_mfma<<<6272, 256, 0, stream>>>(xp, wpk1h, b1, wscales, scales, t1buf, h1q);
    k_conv2s_mfma<<<1568, 256, 0, stream>>>(h1q, wpk2, stats2);
    k_scales2<<<1, 256, 0, stream>>>(stats2, g2, be2, m2, v2, b2, scales, wscales, scales + 3, t2buf);
    k_block2_mfma<<<6272, 256, 0, stream>>>(h1q, wpk2, b2, scales, wscales, t2buf, h2q);
    k_fc1<<<512, 256, 0, stream>>>(h2q, bpk1, fb1, scales, wscales, fc1o, statsFc);
    k_fc2<<<32, 256, 0, stream>>>(fc1o, qfw2, fb2, statsFc, out, statsOut);
    k_quant_out<<<320, 256, 0, stream>>>(out, statsOut, out_size);
}

// Round 16
// 181.770 us; speedup vs baseline: 2.0304x; 1.0367x over previous
//
#include <hip/hip_runtime.h>
#include <math.h>
#include <limits.h>
#include <stdint.h>

#define QMAXF 127.0f
#define BN_EPS 1e-5f
#define NCOPIES 64

typedef int v4i __attribute__((ext_vector_type(4)));
typedef float f32x4 __attribute__((ext_vector_type(4)));
typedef _Float16 f16x8 __attribute__((ext_vector_type(8)));

// ---------- helpers ----------
__device__ __forceinline__ int f2ord(float f){
    int i = __float_as_int(f);
    return i ^ ((i >> 31) & 0x7fffffff);
}
__device__ __forceinline__ float ord2f(int i){
    return __int_as_float(i ^ ((i >> 31) & 0x7fffffff));
}
__device__ __forceinline__ float scale_of(float m){
    return fmaxf(m / QMAXF, 1e-8f);
}
// fake-quant forward: clip(round(x/s))*s  (round = half-to-even, matches jnp.round)
__device__ __forceinline__ float fq_apply(float x, float s){
    float q = rintf(x / s);
    q = fminf(fmaxf(q, -QMAXF), QMAXF);
    return q * s;
}
// return clipped integer level as float
__device__ __forceinline__ float quant_k(float x, float s){
    float q = rintf(x / s);
    return fminf(fmaxf(q, -QMAXF), QMAXF);
}
__device__ __forceinline__ _Float16 hpart(uint32_t w){
    return __builtin_bit_cast(_Float16, (unsigned short)(w >> 16));
}
__device__ __forceinline__ _Float16 lpart(uint32_t w){
    return __builtin_bit_cast(_Float16, (unsigned short)(w & 0xffffu));
}

// ---------- K0: init stat buffers + per-block |w| partial max ----------
__global__ __launch_bounds__(256) void k_init_ws(
    const float* __restrict__ w1, const float* __restrict__ w2,
    const float* __restrict__ fw1, const float* __restrict__ fw2,
    int* __restrict__ s1, int* __restrict__ s2, int* __restrict__ sf, int* __restrict__ so,
    float* __restrict__ wsbuf /*[67]*/)
{
    int blk = blockIdx.x, t = threadIdx.x;
    if (blk < 26){
        int gt = blk*256 + t;
        if (gt < 2048){ int j = gt & 31; s1[gt] = (j < 16) ? INT_MAX : INT_MIN; }
        else if (gt < 6144){ int u = gt - 2048; int j = u & 63; s2[u] = (j < 32) ? INT_MAX : INT_MIN; }
        else if (gt < 6272){ int u = gt - 6144; sf[u] = ((u & 1) == 0) ? INT_MAX : INT_MIN; }
        else if (gt < 6400){ int u = gt - 6272; so[u] = ((u & 1) == 0) ? INT_MAX : INT_MIN; }
        return;
    }
    __shared__ float red[256];
    int b2 = blk - 26;   // 0..66
    const float* src; int n, base;
    if (b2 < 64){ src = fw1; base = b2*3136; n = 3136; }
    else if (b2 == 64){ src = w1;  base = 0; n = 144; }
    else if (b2 == 65){ src = w2;  base = 0; n = 4608; }
    else { src = fw2; base = 0; n = 1280; }
    float m = 0.f;
    for (int i = t; i < n; i += 256) m = fmaxf(m, fabsf(src[base + i]));
    red[t] = m; __syncthreads();
    for (int off = 128; off; off >>= 1){
        if (t < off) red[t] = fmaxf(red[t], red[t+off]);
        __syncthreads();
    }
    if (t == 0) wsbuf[b2] = red[0];
}

// ---------- K1: pack/quantize weights + pad/split x ----------
__global__ __launch_bounds__(256) void k_pack_prep(
    const float* __restrict__ x,
    const float* __restrict__ w1, const float* __restrict__ w2,
    const float* __restrict__ fw1, const float* __restrict__ fw2,
    const float* __restrict__ wsbuf,
    _Float16* __restrict__ wpk1h, int8_t* __restrict__ wpk2,
    int8_t* __restrict__ bpk1, float* __restrict__ qfw2,
    float* __restrict__ wscales, uint32_t* __restrict__ xp)
{
    int blk = blockIdx.x, t = threadIdx.x;
    if (blk >= 786){
        int i = (blk - 786)*256 + t;        // 7,372,800 = 8192*900 exact
        int b = i / 900, r = i - b*900;
        int yy = r / 30, xx = r - yy*30;
        float val = 0.f;
        if (yy >= 1 && yy <= 28 && xx >= 1 && xx <= 28)
            val = x[(size_t)b*784 + (yy-1)*28 + (xx-1)];
        _Float16 h  = (_Float16)val;
        _Float16 lo = (_Float16)(val - (float)h);
        xp[i] = ((uint32_t)__builtin_bit_cast(unsigned short, h) << 16)
              |  (uint32_t)__builtin_bit_cast(unsigned short, lo);
        return;
    }
    if (blk < 784){
        float m = 0.f;
        #pragma unroll
        for (int i = 0; i < 64; i++) m = fmaxf(m, wsbuf[i]);
        float s = scale_of(m);
        int i = blk*256 + t;                      // 200704 exact
        int o = i / 1568, k = i - o*1568;
        int c = k / 49, r = k - c*49;
        int kp = r*32 + c;
        int kchunk = kp >> 6, rem = kp & 63, hi = rem >> 4, j = rem & 15;
        int code = (int)quant_k(fw1[i], s);
        bpk1[(o>>4)*25600 + (kchunk*4 + hi)*256 + (o&15)*16 + j] = (int8_t)code;
    } else if (blk == 784){
        float s0 = scale_of(wsbuf[64]), s3 = scale_of(wsbuf[66]);
        for (int i = t; i < 512; i += 256){
            int grp = i >> 3, j = i & 7;
            int hi = grp >> 4, col = grp & 15;
            _Float16 val = (_Float16)0.f;
            if (hi < 3){
                int jj = (j < 3) ? j : ((j < 6) ? (j - 3) : -1);
                if (jj >= 0) val = (_Float16)quant_k(w1[col*9 + hi*3 + jj], s0);  // exact int code
            }
            wpk1h[i] = val;
        }
        for (int i = t; i < 1280; i += 256) qfw2[i] = fq_apply(fw2[i], s3);
        for (int i = t; i < 4096; i += 256){
            int o = i >> 5, rem = (i & 31) + 32;  // kp 1568..1599 -> chunk24
            int hi = rem >> 4, j = rem & 15;
            bpk1[(o>>4)*25600 + (24*4 + hi)*256 + (o&15)*16 + j] = 0;
        }
        if (t == 0){
            float m = 0.f;
            for (int i = 0; i < 64; i++) m = fmaxf(m, wsbuf[i]);
            wscales[0] = scale_of(wsbuf[64]);
            wscales[1] = scale_of(wsbuf[65]);
            wscales[2] = scale_of(m);
            wscales[3] = scale_of(wsbuf[66]);
        }
    } else {
        float s1 = scale_of(wsbuf[65]);
        for (int i = t; i < 6144; i += 256) wpk2[i] = 0;
        __syncthreads();
        for (int i = t; i < 4608; i += 256){
            int co = i / 144, rr = i - co*144, ci = rr / 9, pix = rr - ci*9;
            wpk2[(co >> 4)*3072 + pix*256 + (co & 15)*16 + ci] = (int8_t)(int)quant_k(w2[i], s1);
        }
    }
}

// ---------- conv1 fragment from 3 preloaded dwords: hi at slots 0-2, lo at 3-5 ----------
__device__ __forceinline__ f16x8 conv1_fragW(uint32_t w0, uint32_t w1, uint32_t w2)
{
    _Float16 z = (_Float16)0.f;
    return (f16x8){hpart(w0), hpart(w1), hpart(w2),
                   lpart(w0), lpart(w1), lpart(w2), z, z};
}

// ---------- K2: conv1 MFMA + per-channel min/max (4-deep prefetch pipeline) ----------
__global__ __launch_bounds__(256) void k_conv1s_mfma(
    const uint32_t* __restrict__ xp, const _Float16* __restrict__ wpk1h,
    const float* __restrict__ b1, const float* __restrict__ wscales,
    int* __restrict__ stats1)
{
    int t = threadIdx.x, l = t & 63, wid = t >> 6;
    int hi = l >> 4, col = l & 15;
    f16x8 bv = *(const f16x8*)(wpk1h + (hi*16 + col)*8);
    float sb = b1[col];
    float s0 = wscales[0];
    int tile0 = blockIdx.x*4 + wid;                // 0..6271
    int p0 = tile0*16 + (l & 15);
    int b0 = p0 / 784, r = p0 - b0*784;
    int y = r / 28, xx = r - y*28;
    int rowo = (hi < 3) ? hi : 2;
    bool valid = hi < 3;
    const uint32_t* base = xp + (size_t)b0*900 + (y + rowo)*30 + xx;
    const size_t TS = (size_t)128*900;   // 128 images per tile step
    uint32_t n0[3], n1[3], n2[3], n3[3];
    if (valid){
        #pragma unroll
        for (int j = 0; j < 3; j++){
            n0[j] = base[j];           n1[j] = base[TS + j];
            n2[j] = base[2*TS + j];    n3[j] = base[3*TS + j];
        }
    } else {
        #pragma unroll
        for (int j = 0; j < 3; j++){ n0[j]=n1[j]=n2[j]=n3[j]=0u; }
    }
    float mn = INFINITY, mx = -INFINITY;
    #pragma unroll 1
    for (int it = 0; it < 16; it++){               // 16 quads = 64 tiles
        uint32_t w0[3], w1[3], w2[3], w3[3];
        #pragma unroll
        for (int j = 0; j < 3; j++){ w0[j]=n0[j]; w1[j]=n1[j]; w2[j]=n2[j]; w3[j]=n3[j]; }
        base += 4*TS;
        if (it < 15 && valid){
            #pragma unroll
            for (int j = 0; j < 3; j++){
                n0[j] = base[j];           n1[j] = base[TS + j];
                n2[j] = base[2*TS + j];    n3[j] = base[3*TS + j];
            }
        }
        f16x8 a0 = conv1_fragW(w0[0], w0[1], w0[2]);
        f16x8 a1 = conv1_fragW(w1[0], w1[1], w1[2]);
        f16x8 a2 = conv1_fragW(w2[0], w2[1], w2[2]);
        f16x8 a3 = conv1_fragW(w3[0], w3[1], w3[2]);
        f32x4 c0 = {0.f,0.f,0.f,0.f}, c1 = {0.f,0.f,0.f,0.f};
        f32x4 c2 = {0.f,0.f,0.f,0.f}, c3 = {0.f,0.f,0.f,0.f};
        c0 = __builtin_amdgcn_mfma_f32_16x16x32_f16(a0, bv, c0, 0, 0, 0);
        c1 = __builtin_amdgcn_mfma_f32_16x16x32_f16(a1, bv, c1, 0, 0, 0);
        c2 = __builtin_amdgcn_mfma_f32_16x16x32_f16(a2, bv, c2, 0, 0, 0);
        c3 = __builtin_amdgcn_mfma_f32_16x16x32_f16(a3, bv, c3, 0, 0, 0);
        #pragma unroll
        for (int rg = 0; rg < 4; rg++){
            mn = fminf(mn, fminf(fminf(c0[rg], c1[rg]), fminf(c2[rg], c3[rg])));
            mx = fmaxf(mx, fmaxf(fmaxf(c0[rg], c1[rg]), fmaxf(c2[rg], c3[rg])));
        }
    }
    mn = fmaf(s0, mn, sb);
    mx = fmaf(s0, mx, sb);
    mn = fminf(mn, __shfl_xor(mn, 16)); mn = fminf(mn, __shfl_xor(mn, 32));
    mx = fmaxf(mx, __shfl_xor(mx, 16)); mx = fmaxf(mx, __shfl_xor(mx, 32));
    if (l < 16){
        int* basep = stats1 + (blockIdx.x & (NCOPIES-1))*32;
        atomicMin(&basep[l],      f2ord(mn));
        atomicMax(&basep[16 + l], f2ord(mx));
    }
}

// ---------- scales for block1 + chain LUT build ----------
__global__ __launch_bounds__(256) void k_scales_block(
    const int* __restrict__ stats,
    const float* __restrict__ g, const float* __restrict__ be,
    const float* __restrict__ m, const float* __restrict__ v,
    float* __restrict__ s_out, int8_t* __restrict__ t1buf)
{
    __shared__ float cmn[16], cmx[16], invs[16], dds[16], sss[3];
    int t = threadIdx.x;
    if (t < 32){
        bool ismax = t >= 16; int c = t & 15;
        int acc = ismax ? INT_MIN : INT_MAX;
        for (int i = 0; i < NCOPIES; i++){
            int u = stats[i*32 + t];
            acc = ismax ? max(acc, u) : min(acc, u);
        }
        if (ismax) cmx[c] = ord2f(acc); else cmn[c] = ord2f(acc);
    }
    __syncthreads();
    if (t == 0){
        float am = 0.f;
        for (int c = 0; c < 16; c++) am = fmaxf(am, fmaxf(fabsf(cmn[c]), fabsf(cmx[c])));
        float sA_ = fmaxf(am / QMAXF, 1e-8f);
        float rmax = 0.f;
        float q1x[16], q1n[16];
        for (int c = 0; c < 16; c++){
            q1x[c] = fmaxf(fq_apply(cmx[c], sA_), 0.f);
            q1n[c] = fmaxf(fq_apply(cmn[c], sA_), 0.f);
            rmax = fmaxf(rmax, q1x[c]);
        }
        float sB_ = fmaxf(rmax / QMAXF, 1e-8f);
        float am3 = 0.f;
        for (int c = 0; c < 16; c++){
            float inv = g[c] / sqrtf(v[c] + BN_EPS);
            float dd  = be[c] - m[c]*inv;
            invs[c] = inv; dds[c] = dd;
            float ha = fmaf(fq_apply(q1x[c], sB_), inv, dd);
            float hb = fmaf(fq_apply(q1n[c], sB_), inv, dd);
            am3 = fmaxf(am3, fmaxf(fabsf(ha), fabsf(hb)));
        }
        float sC_ = fmaxf(am3 / QMAXF, 1e-8f);
        sss[0] = sA_; sss[1] = sB_; sss[2] = sC_;
        s_out[0] = sA_; s_out[1] = sB_; s_out[2] = sC_;
    }
    __syncthreads();
    float s1 = sss[0], s2 = sss[1], s3 = sss[2];
    for (int e = t; e < 2048; e += 256){
        int c = e >> 7, idx = e & 127;
        float hh = (float)idx * s1;             // = q1*s1 (relu'd)
        float q2 = quant_k(hh, s2);
        float h2 = q2 * s2;
        float hb = fmaf(h2, invs[c], dds[c]);
        t1buf[e] = (int8_t)(int)quant_k(hb, s3);
    }
}

// ---------- K4: block1 MFMA -> pool -> 1 div + LUT -> h1q (4-deep prefetch) ----------
__global__ __launch_bounds__(256) void k_block1_mfma(
    const uint32_t* __restrict__ xp, const _Float16* __restrict__ wpk1h,
    const float* __restrict__ b1, const float* __restrict__ wscales,
    const float* __restrict__ scales, const int8_t* __restrict__ t1buf,
    int8_t* __restrict__ h1q)
{
    __shared__ int8_t T1l[16*132];
    int t = threadIdx.x, l = t & 63, wid = t >> 6;
    for (int e = t; e < 2048; e += 256)
        T1l[(e >> 7)*132 + (e & 127)] = t1buf[e];
    __syncthreads();
    int hi = l >> 4, col = l & 15;
    f16x8 bv = *(const f16x8*)(wpk1h + (hi*16 + col)*8);
    float sb = b1[col];
    float s0 = wscales[0], s1 = scales[0];
    int tile0 = blockIdx.x*4 + wid;                // 0..25087
    int grow = tile0*16 + (l & 15);
    int cell = grow >> 2, sub = grow & 3;
    int b0 = cell / 196, rc = cell - b0*196;
    int py = rc / 14, px = rc - py*14;
    int y = 2*py + (sub >> 1), xx = 2*px + (sub & 1);
    int rowo = (hi < 3) ? hi : 2;
    bool valid = hi < 3;
    const uint32_t* base = xp + (size_t)b0*900 + (y + rowo)*30 + xx;
    const size_t TS = (size_t)512*900;   // 512 images per tile step
    const int8_t* T1c = T1l + col*132;
    int8_t* h1o = h1q + (size_t)tile0*64 + l;
    uint32_t n0[3], n1[3], n2[3], n3[3];
    if (valid){
        #pragma unroll
        for (int j = 0; j < 3; j++){
            n0[j] = base[j];           n1[j] = base[TS + j];
            n2[j] = base[2*TS + j];    n3[j] = base[3*TS + j];
        }
    } else {
        #pragma unroll
        for (int j = 0; j < 3; j++){ n0[j]=n1[j]=n2[j]=n3[j]=0u; }
    }
    #pragma unroll 1
    for (int it = 0; it < 4; it++){                // 4 quads = 16 tiles
        uint32_t w0[3], w1[3], w2[3], w3[3];
        #pragma unroll
        for (int j = 0; j < 3; j++){ w0[j]=n0[j]; w1[j]=n1[j]; w2[j]=n2[j]; w3[j]=n3[j]; }
        base += 4*TS;
        if (it < 3 && valid){
            #pragma unroll
            for (int j = 0; j < 3; j++){
                n0[j] = base[j];           n1[j] = base[TS + j];
                n2[j] = base[2*TS + j];    n3[j] = base[3*TS + j];
            }
        }
        f16x8 a0 = conv1_fragW(w0[0], w0[1], w0[2]);
        f16x8 a1 = conv1_fragW(w1[0], w1[1], w1[2]);
        f16x8 a2 = conv1_fragW(w2[0], w2[1], w2[2]);
        f16x8 a3 = conv1_fragW(w3[0], w3[1], w3[2]);
        f32x4 c0 = {0.f,0.f,0.f,0.f}, c1 = {0.f,0.f,0.f,0.f};
        f32x4 c2 = {0.f,0.f,0.f,0.f}, c3 = {0.f,0.f,0.f,0.f};
        c0 = __builtin_amdgcn_mfma_f32_16x16x32_f16(a0, bv, c0, 0, 0, 0);
        c1 = __builtin_amdgcn_mfma_f32_16x16x32_f16(a1, bv, c1, 0, 0, 0);
        c2 = __builtin_amdgcn_mfma_f32_16x16x32_f16(a2, bv, c2, 0, 0, 0);
        c3 = __builtin_amdgcn_mfma_f32_16x16x32_f16(a3, bv, c3, 0, 0, 0);
        float pool0 = fmaxf(fmaxf(c0[0], c0[1]), fmaxf(c0[2], c0[3]));
        float pool1 = fmaxf(fmaxf(c1[0], c1[1]), fmaxf(c1[2], c1[3]));
        float pool2 = fmaxf(fmaxf(c2[0], c2[1]), fmaxf(c2[2], c2[3]));
        float pool3 = fmaxf(fmaxf(c3[0], c3[1]), fmaxf(c3[2], c3[3]));
        float q0 = quant_k(fmaf(s0, pool0, sb), s1);
        float q1 = quant_k(fmaf(s0, pool1, sb), s1);
        float q2 = quant_k(fmaf(s0, pool2, sb), s1);
        float q3 = quant_k(fmaf(s0, pool3, sb), s1);
        h1o[0]                    = T1c[(int)fmaxf(q0, 0.f)];
        h1o[(size_t)100352*16]    = T1c[(int)fmaxf(q1, 0.f)];
        h1o[(size_t)2*100352*16]  = T1c[(int)fmaxf(q2, 0.f)];
        h1o[(size_t)3*100352*16]  = T1c[(int)fmaxf(q3, 0.f)];
        h1o += (size_t)4*100352*16;
    }
}

// ---------- K6: conv2 int8 MFMA + per-channel code min/max (manual prefetch) ----------
__global__ __launch_bounds__(256) void k_conv2s_mfma(
    const int8_t* __restrict__ h1q, const int8_t* __restrict__ wpk2,
    int* __restrict__ stats2)
{
    __shared__ int smn[32], smx[32];
    int t = threadIdx.x, l = t & 63, wid = t >> 6;
    if (t < 32){ smn[t] = INT_MAX; smx[t] = INT_MIN; }
    __syncthreads();
    int hi = l >> 4;
    v4i bv[6];
    #pragma unroll
    for (int nt = 0; nt < 2; nt++)
        #pragma unroll
        for (int s = 0; s < 3; s++)
            bv[nt*3+s] = *(const v4i*)(wpk2 + nt*3072 + (4*s + hi)*256 + (l&15)*16);
    int tile0 = blockIdx.x*4 + wid;                // 0..6271
    int grow = tile0*16 + (l & 15);
    int cell_g = grow >> 2;
    int b0 = cell_g / 49, cell = cell_g - b0*49;
    int sub = grow & 3;
    int qy = cell / 7, qx = cell - qy*7;
    int y = 2*qy + (sub >> 1), x = 2*qx + (sub & 1);
    const int8_t* ip = h1q + (size_t)b0*196*16;
    int toff[3];
    #pragma unroll
    for (int s = 0; s < 3; s++){
        int tap = 4*s + hi;
        toff[s] = -1;
        if (tap < 9){
            int ky = tap / 3, kx = tap - ky*3;
            int yy = y + ky - 1, xc = x + kx - 1;
            if (yy >= 0 && yy < 14 && xc >= 0 && xc < 14)
                toff[s] = (yy*14 + xc)*16;
        }
    }
    v4i nav0 = (toff[0] >= 0) ? *(const v4i*)(ip + toff[0]) : (v4i){0,0,0,0};
    v4i nav1 = (toff[1] >= 0) ? *(const v4i*)(ip + toff[1]) : (v4i){0,0,0,0};
    v4i nav2 = (toff[2] >= 0) ? *(const v4i*)(ip + toff[2]) : (v4i){0,0,0,0};
    int mn0 = INT_MAX, mx0 = INT_MIN, mn1 = INT_MAX, mx1 = INT_MIN;
    #pragma unroll 1
    for (int it = 0; it < 16; it++){            // 1568 blocks * 16 = 25088 tiles
        v4i av0 = nav0, av1 = nav1, av2 = nav2;
        ip += (size_t)512*196*16;
        if (it < 15){
            nav0 = (toff[0] >= 0) ? *(const v4i*)(ip + toff[0]) : (v4i){0,0,0,0};
            nav1 = (toff[1] >= 0) ? *(const v4i*)(ip + toff[1]) : (v4i){0,0,0,0};
            nav2 = (toff[2] >= 0) ? *(const v4i*)(ip + toff[2]) : (v4i){0,0,0,0};
        }
        v4i acc0 = (v4i){0,0,0,0}, acc1 = (v4i){0,0,0,0};
        acc0 = __builtin_amdgcn_mfma_i32_16x16x64_i8(av0, bv[0], acc0, 0, 0, 0);
        acc1 = __builtin_amdgcn_mfma_i32_16x16x64_i8(av0, bv[3], acc1, 0, 0, 0);
        acc0 = __builtin_amdgcn_mfma_i32_16x16x64_i8(av1, bv[1], acc0, 0, 0, 0);
        acc1 = __builtin_amdgcn_mfma_i32_16x16x64_i8(av1, bv[4], acc1, 0, 0, 0);
        acc0 = __builtin_amdgcn_mfma_i32_16x16x64_i8(av2, bv[2], acc0, 0, 0, 0);
        acc1 = __builtin_amdgcn_mfma_i32_16x16x64_i8(av2, bv[5], acc1, 0, 0, 0);
        #pragma unroll
        for (int r = 0; r < 4; r++){
            mn0 = min(mn0, acc0[r]); mx0 = max(mx0, acc0[r]);
            mn1 = min(mn1, acc1[r]); mx1 = max(mx1, acc1[r]);
        }
    }
    mn0 = min(mn0, __shfl_xor(mn0, 16)); mn0 = min(mn0, __shfl_xor(mn0, 32));
    mx0 = max(mx0, __shfl_xor(mx0, 16)); mx0 = max(mx0, __shfl_xor(mx0, 32));
    mn1 = min(mn1, __shfl_xor(mn1, 16)); mn1 = min(mn1, __shfl_xor(mn1, 32));
    mx1 = max(mx1, __shfl_xor(mx1, 16)); mx1 = max(mx1, __shfl_xor(mx1, 32));
    if (l < 16){
        atomicMin(&smn[l], mn0);      atomicMax(&smx[l], mx0);
        atomicMin(&smn[16 + l], mn1); atomicMax(&smx[16 + l], mx1);
    }
    __syncthreads();
    if (t < 32){
        int* basep = stats2 + (blockIdx.x & (NCOPIES-1))*64;
        atomicMin(&basep[t],      smn[t]);
        atomicMax(&basep[t + 32], smx[t]);
    }
}

// ---------- scales for block2 + chain LUT build ----------
__global__ __launch_bounds__(256) void k_scales2(
    const int* __restrict__ stats,
    const float* __restrict__ g, const float* __restrict__ be,
    const float* __restrict__ m, const float* __restrict__ v,
    const float* __restrict__ b2,
    const float* __restrict__ scales, const float* __restrict__ wscales,
    float* __restrict__ s_out, int8_t* __restrict__ t2buf)
{
    __shared__ float cmn[32], cmx[32], invs[32], dds[32], sss[3];
    int t = threadIdx.x;
    float S = scales[2] * wscales[1];
    if (t < 64){
        bool ismax = t >= 32; int c = t & 31;
        int acc = ismax ? INT_MIN : INT_MAX;
        for (int i = 0; i < NCOPIES; i++){
            int u = stats[i*64 + t];
            acc = ismax ? max(acc, u) : min(acc, u);
        }
        float val = fmaf(S, (float)acc, b2[c]);
        if (ismax) cmx[c] = val; else cmn[c] = val;
    }
    __syncthreads();
    if (t == 0){
        float am = 0.f;
        for (int c = 0; c < 32; c++) am = fmaxf(am, fmaxf(fabsf(cmn[c]), fabsf(cmx[c])));
        float sA_ = fmaxf(am / QMAXF, 1e-8f);
        float rmax = 0.f;
        float q1x[32], q1n[32];
        for (int c = 0; c < 32; c++){
            q1x[c] = fmaxf(fq_apply(cmx[c], sA_), 0.f);
            q1n[c] = fmaxf(fq_apply(cmn[c], sA_), 0.f);
            rmax = fmaxf(rmax, q1x[c]);
        }
        float sB_ = fmaxf(rmax / QMAXF, 1e-8f);
        float am3 = 0.f;
        for (int c = 0; c < 32; c++){
            float inv = g[c] / sqrtf(v[c] + BN_EPS);
            float dd  = be[c] - m[c]*inv;
            invs[c] = inv; dds[c] = dd;
            float ha = fmaf(fq_apply(q1x[c], sB_), inv, dd);
            float hb = fmaf(fq_apply(q1n[c], sB_), inv, dd);
            am3 = fmaxf(am3, fmaxf(fabsf(ha), fabsf(hb)));
        }
        float sC_ = fmaxf(am3 / QMAXF, 1e-8f);
        sss[0] = sA_; sss[1] = sB_; sss[2] = sC_;
        s_out[0] = sA_; s_out[1] = sB_; s_out[2] = sC_;
    }
    __syncthreads();
    float s4 = sss[0], s5 = sss[1], s6 = sss[2];
    for (int e = t; e < 4096; e += 256){
        int c = e >> 7, idx = e & 127;
        float hh = (float)idx * s4;
        float q5 = quant_k(hh, s5);
        float h2 = q5 * s5;
        float hb = fmaf(h2, invs[c], dds[c]);
        t2buf[e] = (int8_t)(int)quant_k(hb, s6);
    }
}

// ---------- K8: block2 MFMA -> pool -> 1 div + LUT -> h2q (manual prefetch) ----------
__global__ __launch_bounds__(256) void k_block2_mfma(
    const int8_t* __restrict__ h1q, const int8_t* __restrict__ wpk2,
    const float* __restrict__ b2, const float* __restrict__ scales,
    const float* __restrict__ wscales, const int8_t* __restrict__ t2buf,
    int8_t* __restrict__ h2q)
{
    __shared__ int8_t T2l[32*132];
    int t = threadIdx.x, l = t & 63, wid = t >> 6;
    for (int e = t; e < 4096; e += 256)
        T2l[(e >> 7)*132 + (e & 127)] = t2buf[e];
    __syncthreads();
    int hi = l >> 4, cl = l & 15;
    float S = scales[2] * wscales[1];
    float s4 = scales[3];
    float sb0 = b2[cl], sb1 = b2[16 + cl];
    const int8_t* T2a = T2l + cl*132;
    const int8_t* T2b = T2l + (16 + cl)*132;
    v4i bv[6];
    #pragma unroll
    for (int nt = 0; nt < 2; nt++)
        #pragma unroll
        for (int s = 0; s < 3; s++)
            bv[nt*3+s] = *(const v4i*)(wpk2 + nt*3072 + (4*s + hi)*256 + cl*16);
    int tile0 = blockIdx.x*4 + wid;                // 0..25087
    int grow = tile0*16 + (l & 15);
    int cell_g = grow >> 2;
    int b0 = cell_g / 49, cell = cell_g - b0*49;
    int sub = grow & 3;
    int qy = cell / 7, qx = cell - qy*7;
    int y = 2*qy + (sub >> 1), x = 2*qx + (sub & 1);
    const int8_t* ip = h1q + (size_t)b0*196*16;
    int toff[3];
    #pragma unroll
    for (int s = 0; s < 3; s++){
        int tap = 4*s + hi;
        toff[s] = -1;
        if (tap < 9){
            int ky = tap / 3, kx = tap - ky*3;
            int yy = y + ky - 1, xc = x + kx - 1;
            if (yy >= 0 && yy < 14 && xc >= 0 && xc < 14)
                toff[s] = (yy*14 + xc)*16;
        }
    }
    v4i nav0 = (toff[0] >= 0) ? *(const v4i*)(ip + toff[0]) : (v4i){0,0,0,0};
    v4i nav1 = (toff[1] >= 0) ? *(const v4i*)(ip + toff[1]) : (v4i){0,0,0,0};
    v4i nav2 = (toff[2] >= 0) ? *(const v4i*)(ip + toff[2]) : (v4i){0,0,0,0};
    int8_t* h2o = h2q + (size_t)(tile0*4 + hi)*32 + cl;   // +16 for nt=1
    #pragma unroll 1
    for (int it = 0; it < 4; it++){
        v4i av0 = nav0, av1 = nav1, av2 = nav2;
        ip += (size_t)2048*196*16;
        if (it < 3){
            nav0 = (toff[0] >= 0) ? *(const v4i*)(ip + toff[0]) : (v4i){0,0,0,0};
            nav1 = (toff[1] >= 0) ? *(const v4i*)(ip + toff[1]) : (v4i){0,0,0,0};
            nav2 = (toff[2] >= 0) ? *(const v4i*)(ip + toff[2]) : (v4i){0,0,0,0};
        }
        v4i acc0 = (v4i){0,0,0,0}, acc1 = (v4i){0,0,0,0};
        acc0 = __builtin_amdgcn_mfma_i32_16x16x64_i8(av0, bv[0], acc0, 0, 0, 0);
        acc1 = __builtin_amdgcn_mfma_i32_16x16x64_i8(av0, bv[3], acc1, 0, 0, 0);
        acc0 = __builtin_amdgcn_mfma_i32_16x16x64_i8(av1, bv[1], acc0, 0, 0, 0);
        acc1 = __builtin_amdgcn_mfma_i32_16x16x64_i8(av1, bv[4], acc1, 0, 0, 0);
        acc0 = __builtin_amdgcn_mfma_i32_16x16x64_i8(av2, bv[2], acc0, 0, 0, 0);
        acc1 = __builtin_amdgcn_mfma_i32_16x16x64_i8(av2, bv[5], acc1, 0, 0, 0);
        int pool0 = max(max(acc0[0], acc0[1]), max(acc0[2], acc0[3]));
        int pool1 = max(max(acc1[0], acc1[1]), max(acc1[2], acc1[3]));
        float q0 = quant_k(fmaf(S, (float)pool0, sb0), s4);
        float q1 = quant_k(fmaf(S, (float)pool1, sb1), s4);
        h2o[0]  = T2a[(int)fmaxf(q0, 0.f)];
        h2o[16] = T2b[(int)fmaxf(q1, 0.f)];
        h2o += (size_t)100352*32;
    }
}

// ---------- K9: fc1 int8 MFMA, quarter-split: 2048 waves ----------
__global__ __launch_bounds__(256) void k_fc1(
    const int8_t* __restrict__ h2q, const int8_t* __restrict__ bpk1,
    const float* __restrict__ fb1, const float* __restrict__ scales,
    const float* __restrict__ wscales,
    float* __restrict__ fc1o, int* __restrict__ statsFc)
{
    __shared__ int smn, smx;
    int t = threadIdx.x, l = t & 63, wid = t >> 6;
    if (t == 0){ smn = INT_MAX; smx = INT_MIN; }
    __syncthreads();
    int wave_id = blockIdx.x*4 + wid;     // 2048 waves (512 blocks)
    int mtile = wave_id >> 2;             // 0..511
    int quarter = wave_id & 3;            // 2 o-groups each
    int hi = l >> 4, lo = l & 15;
    const int8_t* arow = h2q + (size_t)(mtile*16 + lo)*1568;
    v4i acc[2];
    #pragma unroll
    for (int g = 0; g < 2; g++) acc[g] = (v4i){0,0,0,0};
    #pragma unroll 1
    for (int kc = 0; kc < 25; kc++){
        int koff = kc*64 + hi*16;
        v4i av = (v4i){0,0,0,0};
        if (koff < 1568) av = *(const v4i*)(arow + koff);
        #pragma unroll
        for (int g = 0; g < 2; g++){
            v4i bvv = *(const v4i*)(bpk1 + (quarter*2 + g)*25600 + (kc*4 + hi)*256 + lo*16);
            acc[g] = __builtin_amdgcn_mfma_i32_16x16x64_i8(av, bvv, acc[g], 0, 0, 0);
        }
    }
    float Sfc = scales[5] * wscales[2];
    float lmn = INFINITY, lmx = -INFINITY;
    #pragma unroll
    for (int g = 0; g < 2; g++){
        int o = (quarter*2 + g)*16 + lo;
        float bias = fb1[o];
        #pragma unroll
        for (int r = 0; r < 4; r++){
            int m = mtile*16 + hi*4 + r;
            float val = fmaf(Sfc, (float)acc[g][r], bias);
            fc1o[(size_t)m*128 + o] = val;
            lmn = fminf(lmn, val); lmx = fmaxf(lmx, val);
        }
    }
    #pragma unroll
    for (int d = 1; d < 64; d <<= 1){
        lmn = fminf(lmn, __shfl_xor(lmn, d));
        lmx = fmaxf(lmx, __shfl_xor(lmx, d));
    }
    if (l == 0){
        atomicMin(&smn, f2ord(lmn));
        atomicMax(&smx, f2ord(lmx));
    }
    __syncthreads();
    if (t == 0){
        int* basep = statsFc + (blockIdx.x & (NCOPIES-1))*2;
        atomicMin(&basep[0], smn); atomicMax(&basep[1], smx);
    }
}

// ---------- K12: fc2 with LUT'd h3 quantization ----------
__global__ __launch_bounds__(256) void k_fc2(
    const float* __restrict__ fc1o, const float* __restrict__ qfw2, const float* __restrict__ fb2,
    const int* __restrict__ statsFc, float* __restrict__ out, int* __restrict__ statsOut)
{
    __shared__ float sw[1280], sb2[10], Tf[128];
    __shared__ float s7sh, s8sh;
    __shared__ int smn, smx;
    int t = threadIdx.x;
    for (int i = t; i < 1280; i += 256) sw[i] = qfw2[i];
    if (t < 10) sb2[t] = fb2[t];
    if (t == 0){
        smn = INT_MAX; smx = INT_MIN;
        int mni = INT_MAX, mxi = INT_MIN;
        for (int i = 0; i < NCOPIES; i++){ mni = min(mni, statsFc[i*2]); mxi = max(mxi, statsFc[i*2+1]); }
        float mn = ord2f(mni), mx = ord2f(mxi);
        float am = fmaxf(fabsf(mn), fabsf(mx));
        float s7 = fmaxf(am / QMAXF, 1e-8f);
        float rmx = fmaxf(fq_apply(mx, s7), 0.f);
        s7sh = s7; s8sh = fmaxf(rmx / QMAXF, 1e-8f);
    }
    __syncthreads();
    float s7 = s7sh, s8 = s8sh;
    if (t < 128) Tf[t] = s8 * quant_k((float)t * s7, s8);
    __syncthreads();
    int b = blockIdx.x*256 + t;   // 8192 exact (32 blocks)
    float acc[10];
    #pragma unroll
    for (int j = 0; j < 10; j++) acc[j] = sb2[j];
    const float* fp = fc1o + (size_t)b*128;
    for (int k = 0; k < 128; k += 4){
        float4 f = *(const float4*)(fp + k);
        float v0 = Tf[(int)fmaxf(quant_k(f.x, s7), 0.f)];
        float v1 = Tf[(int)fmaxf(quant_k(f.y, s7), 0.f)];
        float v2 = Tf[(int)fmaxf(quant_k(f.z, s7), 0.f)];
        float v3 = Tf[(int)fmaxf(quant_k(f.w, s7), 0.f)];
        #pragma unroll
        for (int j = 0; j < 10; j++){
            float a = acc[j];
            a = fmaf(v0, sw[j*128 + k],     a);
            a = fmaf(v1, sw[j*128 + k + 1], a);
            a = fmaf(v2, sw[j*128 + k + 2], a);
            a = fmaf(v3, sw[j*128 + k + 3], a);
            acc[j] = a;
        }
    }
    float lmn = INFINITY, lmx = -INFINITY;
    #pragma unroll
    for (int j = 0; j < 10; j++){
        out[(size_t)b*10 + j] = acc[j];
        lmn = fminf(lmn, acc[j]); lmx = fmaxf(lmx, acc[j]);
    }
    atomicMin(&smn, f2ord(lmn)); atomicMax(&smx, f2ord(lmx));
    __syncthreads();
    if (t == 0){
        int* basep = statsOut + (blockIdx.x & (NCOPIES-1))*2;
        atomicMin(&basep[0], smn); atomicMax(&basep[1], smx);
    }
}

// ---------- K14: final fake-quant of d_out ----------
__global__ void k_quant_out(float* __restrict__ out, const int* __restrict__ statsOut, int n){
    __shared__ float s9s;
    if (threadIdx.x == 0){
        int mni = INT_MAX, mxi = INT_MIN;
        for (int i = 0; i < NCOPIES; i++){ mni = min(mni, statsOut[i*2]); mxi = max(mxi, statsOut[i*2+1]); }
        float am = fmaxf(fabsf(ord2f(mni)), fabsf(ord2f(mxi)));
        s9s = fmaxf(am / QMAXF, 1e-8f);
    }
    __syncthreads();
    int i = blockIdx.x*256 + threadIdx.x;
    if (i < n) out[i] = fq_apply(out[i], s9s);
}

// =================== host ===================
extern "C" void kernel_launch(void* const* d_in, const int* in_sizes, int n_in,
                              void* d_out, int out_size, void* d_ws, size_t ws_size,
                              hipStream_t stream)
{
    const float* x   = (const float*)d_in[0];
    const float* w1  = (const float*)d_in[1];
    const float* b1  = (const float*)d_in[2];
    const float* g1  = (const float*)d_in[3];
    const float* be1 = (const float*)d_in[4];
    const float* m1  = (const float*)d_in[5];
    const float* v1  = (const float*)d_in[6];
    const float* w2  = (const float*)d_in[7];
    const float* b2  = (const float*)d_in[8];
    const float* g2  = (const float*)d_in[9];
    const float* be2 = (const float*)d_in[10];
    const float* m2  = (const float*)d_in[11];
    const float* v2  = (const float*)d_in[12];
    const float* fw1 = (const float*)d_in[13];
    const float* fb1 = (const float*)d_in[14];
    const float* fw2 = (const float*)d_in[15];
    const float* fb2 = (const float*)d_in[16];
    float* out = (float*)d_out;

    char* ws = (char*)d_ws;
    size_t off = 0;
    auto alloc = [&](size_t bytes)->char*{
        char* p = ws + off;
        off = (off + bytes + 255) & ~(size_t)255;
        return p;
    };
    _Float16* wpk1h = (_Float16*)alloc(512*2);
    int8_t* wpk2  = (int8_t*)alloc(6144);
    int8_t* bpk1  = (int8_t*)alloc(204800);
    float* qfw2   = (float*)alloc(1280*4);
    float* scales = (float*)alloc(16*4);
    float* wscales= (float*)alloc(4*4);
    float* wsbuf  = (float*)alloc(67*4);
    int8_t* t1buf = (int8_t*)alloc(2048);
    int8_t* t2buf = (int8_t*)alloc(4096);
    int* stats1   = (int*)alloc(64*32*4);
    int* stats2   = (int*)alloc(64*64*4);
    int* statsFc  = (int*)alloc(64*2*4);
    int* statsOut = (int*)alloc(64*2*4);
    uint32_t* xp  = (uint32_t*)alloc((size_t)8192*900*4);
    int8_t* h1q   = (int8_t*)alloc((size_t)8192*196*16);
    int8_t* h2q   = (int8_t*)alloc((size_t)8192*49*32);
    float* fc1o   = (float*)alloc((size_t)8192*128*4);
    (void)ws_size;

    k_init_ws<<<93, 256, 0, stream>>>(w1, w2, fw1, fw2, stats1, stats2, statsFc, statsOut, wsbuf);
    k_pack_prep<<<29586, 256, 0, stream>>>(x, w1, w2, fw1, fw2, wsbuf, wpk1h, wpk2, bpk1, qfw2, wscales, xp);
    k_conv1s_mfma<<<1568, 256, 0, stream>>>(xp, wpk1h, b1, wscales, stats1);
    k_scales_block<<<1, 256, 0, stream>>>(stats1, g1, be1, m1, v1, scales + 0, t1buf);
    k_block1_mfma<<<6272, 256, 0, stream>>>(xp, wpk1h, b1, wscales, scales, t1buf, h1q);
    k_conv2s_mfma<<<1568, 256, 0, stream>>>(h1q, wpk2, stats2);
    k_scales2<<<1, 256, 0, stream>>>(stats2, g2, be2, m2, v2, b2, scales, wscales, scales + 3, t2buf);
    k_block2_mfma<<<6272, 256, 0, stream>>>(h1q, wpk2, b2, scales, wscales, t2buf, h2q);
    k_fc1<<<512, 256, 0, stream>>>(h2q, bpk1, fb1, scales, wscales, fc1o, statsFc);
    k_fc2<<<32, 256, 0, stream>>>(fc1o, qfw2, fb2, statsFc, out, statsOut);
    k_quant_out<<<320, 256, 0, stream>>>(out, statsOut, out_size);
}